// Round 19
// baseline (260.836 us; speedup 1.0000x reference)
//
#include <hip/hip_runtime.h>
#include <hip/hip_fp16.h>
#include <math.h>

#define N_NODES   50000
#define N_EDGES   1600000
#define E_TOT     (N_EDGES + N_NODES)
#define N_FEAT    128
#define HIDDEN    64
#define N_GRAPHS  128
#define NEG_SLOPE 0.2f
#define NSUB      256                      // sub-buckets over dst space
#define SUB_NODES 196                      // nodes per sub
#define SUB_CAP   8192                     // per-sub global capacity (mean 6250)
#define BUCKET_B  640
#define BCHUNK    2500                     // N_EDGES / BUCKET_B
#define SB_CAP2   17                       // LDS cap/sub (19.5KB -> 8 blocks/CU)
#define EMB_B     ((N_NODES + 31) / 32)    // 1563 embed blocks (8 nodes/wave)
#define AGG_B     (N_NODES / 4)            // agg blocks (1 dst/wave)

// ---- monotone float<->uint encoding for atomicMax on floats ----
__device__ __forceinline__ unsigned fenc(float f) {
    unsigned u = __float_as_uint(f);
    return (u & 0x80000000u) ? ~u : (u | 0x80000000u);
}
__device__ __forceinline__ float fdec(unsigned k) {
    unsigned u = (k & 0x80000000u) ? (k & 0x7FFFFFFFu) : ~k;
    return __uint_as_float(u);
}
__device__ __forceinline__ float lrelu(float e) {
    return (e >= 0.f) ? e : NEG_SLOPE * e;
}
__device__ __forceinline__ int rli(int v, int l) {
    return __builtin_amdgcn_readlane(v, l);
}
__device__ __forceinline__ float rlf(float v, int l) {
    return __int_as_float(__builtin_amdgcn_readlane(__float_as_int(v), l));
}
// ---- fp16-pair pack + v_dot2_f32_f16 (fp16 mul, fp32 accumulate) ----
typedef _Float16 h2v __attribute__((ext_vector_type(2)));
__device__ __forceinline__ unsigned pkh2(float a, float b) {
    h2v v; v.x = (_Float16)a; v.y = (_Float16)b;
    return __builtin_bit_cast(unsigned, v);
}
__device__ __forceinline__ float fdot2u(unsigned a, unsigned b, float c) {
    return __builtin_amdgcn_fdot2(__builtin_bit_cast(h2v, a),
                                  __builtin_bit_cast(h2v, b), c, false);
}
// ---- packed edge record: low32 = src, high32 = el bits ----
__device__ __forceinline__ unsigned long long pke(int src, float el) {
    return ((unsigned long long)(unsigned)__float_as_int(el) << 32) |
           (unsigned long long)(unsigned)src;
}

// ---- fold: W2C1=w2@c1w; pack nw1, w2c1, c2w; init g_enc + sub_tail ----
__global__ __launch_bounds__(256) void fold_w(
    const float* __restrict__ nw1,
    const float* __restrict__ w2, const float* __restrict__ b2,
    const float* __restrict__ c1w, const float* __restrict__ c2w,
    unsigned* __restrict__ nw1_pk, unsigned* __restrict__ w2c1_pk,
    unsigned* __restrict__ c2w_pk,
    float* __restrict__ b2c1, unsigned* __restrict__ g_enc,
    unsigned* __restrict__ sub_tail)
{
    __shared__ float c1s[4096];
    __shared__ float w2c1s[4096];
    int tid = threadIdx.x;
    for (int i = tid; i < 4096; i += 256) c1s[i] = c1w[i];
    for (int i = tid; i < N_GRAPHS * HIDDEN; i += 256) g_enc[i] = fenc(-INFINITY);
    sub_tail[tid] = 0u;
    __syncthreads();
    int j = tid & 63, i0 = tid >> 6;
    for (int ii = 0; ii < 16; ++ii) {
        int i = i0 * 16 + ii;
        float a = 0.f;
#pragma unroll 8
        for (int k = 0; k < 64; ++k) a = fmaf(w2[i * 64 + k], c1s[k * 64 + j], a);
        w2c1s[i * 64 + j] = a;
    }
    if (tid < 64) {
        float a = 0.f;
#pragma unroll 8
        for (int k = 0; k < 64; ++k) a = fmaf(b2[k], c1s[k * 64 + tid], a);
        b2c1[tid] = a;
    }
    __syncthreads();
    for (int idx = tid; idx < 64 * 64; idx += 256) {
        int kk = idx >> 6, jj = idx & 63;
        nw1_pk[idx] = pkh2(nw1[(2 * kk) * 64 + jj], nw1[(2 * kk + 1) * 64 + jj]);
    }
    for (int idx = tid; idx < 32 * 64; idx += 256) {
        int kk = idx >> 6, jj = idx & 63;
        w2c1_pk[idx] = pkh2(w2c1s[(2 * kk) * 64 + jj], w2c1s[(2 * kk + 1) * 64 + jj]);
        c2w_pk[idx]  = pkh2(c2w[(2 * kk) * 64 + jj],  c2w[(2 * kk + 1) * 64 + jj]);
    }
}

// ---- FUSED: bucket blocks [0,BUCKET_B) + embed blocks [BUCKET_B, +EMB_B) ----
__global__ __launch_bounds__(256) void embed_bucket(
    const float* __restrict__ x,
    const unsigned* __restrict__ nw1_pk, const float* __restrict__ n_b1,
    const unsigned* __restrict__ w2c1_pk, const float* __restrict__ b2c1,
    const float* __restrict__ a1s, const float* __restrict__ a1d,
    __half* __restrict__ hlin,
    float* __restrict__ asrc, float* __restrict__ adst,
    float* __restrict__ blkmax,
    const int* __restrict__ ei,
    unsigned* __restrict__ sub_tail, unsigned* __restrict__ sub_buf)
{
    __shared__ unsigned st[NSUB][SB_CAP2];    // 17.4 KB, odd stride: conflict-free
    __shared__ unsigned scnt[NSUB];
    __shared__ unsigned sbase[NSUB];
    __shared__ float wred[4];
    int tid = threadIdx.x;
    int lane = tid & 63, wid = tid >> 6;

    if (blockIdx.x < BUCKET_B) {
        // ---------- bucket path ----------
        scnt[tid] = 0u;
        __syncthreads();
        int beg = blockIdx.x * BCHUNK;
        int end = min(beg + BCHUNK, N_EDGES);
        for (int base = beg; base < end; base += 256) {
            int e = base + tid;
            if (e < end) {
                unsigned src = (unsigned)__builtin_nontemporal_load(ei + e);
                unsigned dst = (unsigned)__builtin_nontemporal_load(ei + N_EDGES + e);
                unsigned sub = dst / SUB_NODES;
                unsigned pay = ((dst - sub * SUB_NODES) << 16) | src;
                unsigned p = atomicAdd(&scnt[sub], 1u);
                if (p < SB_CAP2) st[sub][p] = pay;
                else {                           // ~1% overflow: direct write
                    unsigned gp = atomicAdd(&sub_tail[sub], 1u);
                    if (gp < SUB_CAP)
                        __builtin_nontemporal_store(pay, sub_buf + (size_t)sub * SUB_CAP + gp);
                }
            }
        }
        __syncthreads();
        unsigned c = min(scnt[tid], (unsigned)SB_CAP2);
        scnt[tid] = c;
        sbase[tid] = atomicAdd(&sub_tail[tid], c);
        __syncthreads();
        // wave-coalesced flush: wave handles subs wid, wid+4, ...; lanes 0..c-1
        for (int o = wid; o < NSUB; o += 4) {
            unsigned c_o = scnt[o];
            if ((unsigned)lane < c_o) {
                unsigned pos = sbase[o] + lane;
                if (pos < SUB_CAP)
                    __builtin_nontemporal_store(st[o][lane],
                        sub_buf + (size_t)o * SUB_CAP + pos);
            }
        }
    } else {
        // ---------- embed path: MLP + folded linear via packed dot2 ----------
        int eb = blockIdx.x - BUCKET_B;
        int n0 = eb * 32 + wid * 8;
        if (n0 < N_NODES) {
            unsigned xpk[8];
#pragma unroll
            for (int nn = 0; nn < 8; ++nn) {
                float2 v = ((const float2*)(x + (size_t)(n0 + nn) * N_FEAT))[lane];
                xpk[nn] = pkh2(v.x, v.y);
            }
            float acc[8];
            float b1v = n_b1[lane];
#pragma unroll
            for (int nn = 0; nn < 8; ++nn) acc[nn] = b1v;
#pragma unroll 4
            for (int kk = 0; kk < 64; ++kk) {
                unsigned wp = nw1_pk[kk * 64 + lane];
#pragma unroll
                for (int nn = 0; nn < 8; ++nn)
                    acc[nn] = fdot2u((unsigned)rli((int)xpk[nn], kk), wp, acc[nn]);
            }
#pragma unroll
            for (int nn = 0; nn < 8; ++nn) acc[nn] = fmaxf(acc[nn], 0.f);
            unsigned hpk[8];
#pragma unroll
            for (int nn = 0; nn < 8; ++nn) {
                float ha = __shfl(acc[nn], (2 * lane) & 63, 64);
                float hb = __shfl(acc[nn], (2 * lane + 1) & 63, 64);
                hpk[nn] = pkh2(ha, hb);
            }
            float hl[8];
            float bcv = b2c1[lane];
#pragma unroll
            for (int nn = 0; nn < 8; ++nn) hl[nn] = bcv;
#pragma unroll 4
            for (int kk = 0; kk < 32; ++kk) {
                unsigned wp = w2c1_pk[kk * 64 + lane];
#pragma unroll
                for (int nn = 0; nn < 8; ++nn)
                    hl[nn] = fdot2u((unsigned)rli((int)hpk[nn], kk), wp, hl[nn]);
            }
            float s1v = a1s[lane], d1v = a1d[lane];
            float wmax = -INFINITY;
#pragma unroll
            for (int nn = 0; nn < 8; ++nn) {
                int n = n0 + nn;
                hlin[(size_t)n * 64 + lane] = __float2half(hl[nn]);
                float ps = hl[nn] * s1v, pd = hl[nn] * d1v;
#pragma unroll
                for (int off = 32; off; off >>= 1) {
                    ps += __shfl_xor(ps, off, 64);
                    pd += __shfl_xor(pd, off, 64);
                }
                if (lane == 0) { asrc[n] = ps; adst[n] = pd; wmax = fmaxf(wmax, ps); }
            }
            if (lane == 0) wred[wid] = wmax;
        } else if (lane == 0) wred[wid] = -INFINITY;
        __syncthreads();
        if (tid == 0)
            blkmax[eb] = fmaxf(fmaxf(wred[0], wred[1]), fmaxf(wred[2], wred[3]));
    }
}

// ---- CSR build (256 per-sub blocks, zero global atomics) -> epk + As1 ----
__global__ __launch_bounds__(256) void csr_as1(
    const unsigned* __restrict__ sub_buf, const unsigned* __restrict__ sub_tail,
    const float* __restrict__ asrc1, const float* __restrict__ adst1,
    unsigned* __restrict__ row_ptr, unsigned long long* __restrict__ epk,
    const float* __restrict__ blkmax1, float* __restrict__ As1)
{
    __shared__ unsigned hist[SUB_NODES];
    __shared__ unsigned wt4[4], wo4[4];
    __shared__ unsigned eb_s[2];
    __shared__ unsigned tot_s;
    int tid = threadIdx.x, lane = tid & 63, wid = tid >> 6;

    if (blockIdx.x == NSUB) {              // As1 reduction block
        float m = -INFINITY;
        for (int i = tid; i < EMB_B; i += 256) m = fmaxf(m, blkmax1[i]);
#pragma unroll
        for (int off = 32; off; off >>= 1) m = fmaxf(m, __shfl_xor(m, off, 64));
        float* sm = (float*)wt4;
        if (lane == 0) sm[wid] = m;
        __syncthreads();
        if (tid == 0)
            As1[0] = fmaxf(fmaxf(sm[0], sm[1]), fmaxf(sm[2], sm[3]));
        return;
    }
    int gs = blockIdx.x;                   // 0..255
    unsigned myc = min(sub_tail[tid], (unsigned)SUB_CAP);
    unsigned nn_t = (tid < NSUB - 1) ? SUB_NODES : (N_NODES - (NSUB - 1) * SUB_NODES);
    unsigned v = myc + nn_t;
    unsigned xs = v;
#pragma unroll
    for (int off = 1; off < 64; off <<= 1) {
        unsigned t = __shfl_up(xs, off, 64);
        if (lane >= off) xs += t;
    }
    if (lane == 63) wt4[wid] = xs;
    __syncthreads();
    if (tid == 0) {
        unsigned run = 0;
        for (int w = 0; w < 4; ++w) { wo4[w] = run; run += wt4[w]; }
        tot_s = run;
    }
    __syncthreads();
    unsigned excl = wo4[wid] + xs - v;
    if (tid == gs) { eb_s[0] = excl; eb_s[1] = myc; }
    if (gs == 0 && tid == 0) row_ptr[N_NODES] = tot_s;
    __syncthreads();
    unsigned ebase = eb_s[0], cnt = eb_s[1];
    int node_lo = gs * SUB_NODES;
    int nn = (gs < NSUB - 1) ? SUB_NODES : (N_NODES - (NSUB - 1) * SUB_NODES);
    for (int i = tid; i < nn; i += 256) hist[i] = 1u;
    __syncthreads();
    const unsigned* seg = sub_buf + (size_t)gs * SUB_CAP;
    for (unsigned i = tid; i < cnt; i += 256)
        atomicAdd(&hist[__builtin_nontemporal_load(seg + i) >> 16], 1u);
    __syncthreads();
    unsigned v2 = (tid < nn) ? hist[tid] : 0u;
    unsigned xs2 = v2;
#pragma unroll
    for (int off = 1; off < 64; off <<= 1) {
        unsigned t = __shfl_up(xs2, off, 64);
        if (lane >= off) xs2 += t;
    }
    __syncthreads();
    if (lane == 63) wt4[wid] = xs2;
    __syncthreads();
    if (tid == 0) {
        unsigned run = 0;
        for (int w = 0; w < 4; ++w) { wo4[w] = run; run += wt4[w]; }
    }
    __syncthreads();
    if (tid < nn) {
        unsigned ex2 = wo4[wid] + xs2 - v2;
        unsigned rp = ebase + ex2;
        int n = node_lo + tid;
        row_ptr[n] = rp;
        epk[rp] = pke(n, lrelu(asrc1[n] + adst1[n]));   // self-loop first slot
        hist[tid] = ex2 + 1u;
    }
    __syncthreads();
    // scatter + layer-1 edge logit packed with src
    for (unsigned i = tid; i < cnt; i += 256) {
        unsigned pay = __builtin_nontemporal_load(seg + i);
        unsigned dl = pay >> 16;
        int src = (int)(pay & 0xffffu);
        unsigned p = atomicAdd(&hist[dl], 1u);
        epk[ebase + p] = pke(src, lrelu(asrc1[src] + adst1[node_lo + (int)dl]));
    }
}

// ---- layer-2 edge logits (epk.el overwrite) + As2 reduce (extra block) ----
__global__ __launch_bounds__(256) void wfill2(
    const unsigned* __restrict__ row_ptr,
    const float* __restrict__ asrc2, const float* __restrict__ adst2,
    unsigned long long* __restrict__ epk,
    const float* __restrict__ blkmax2, float* __restrict__ As2)
{
    int lane = threadIdx.x & 63, w = threadIdx.x >> 6;
    if (blockIdx.x == AGG_B) {             // As2 reduction block
        __shared__ float sm[4];
        int tid = threadIdx.x;
        float m = -INFINITY;
        for (int i = tid; i < AGG_B; i += 256) m = fmaxf(m, blkmax2[i]);
#pragma unroll
        for (int off = 32; off; off >>= 1) m = fmaxf(m, __shfl_xor(m, off, 64));
        if (lane == 0) sm[w] = m;
        __syncthreads();
        if (tid == 0)
            As2[0] = fmaxf(fmaxf(sm[0], sm[1]), fmaxf(sm[2], sm[3]));
        return;
    }
    int d = blockIdx.x * 4 + w;
    int s0 = (int)row_ptr[d], s1 = (int)row_ptr[d + 1];
    float ad = adst2[d];
    for (int i = s0 + lane; i < s1; i += 64) {
        unsigned long long q = epk[i];
        int src = (int)(unsigned)(q & 0xffffffffu);
        epk[i] = pke(src, lrelu(asrc2[src] + ad));
    }
}

// ---- agg core: 8 lanes/edge, U=8 burst (64 edges in flight -> 1 round) ----
__device__ __forceinline__ float agg8e(
    const __half* __restrict__ hmat,      // [N][64] fp16 (128B rows)
    const unsigned long long* __restrict__ epk,
    int s0, int s1, float C, int lane, float acc[8])
{
    int slot = lane >> 3;
    int fb = (lane & 7) << 3;
    float sden = 0.f;
#pragma unroll
    for (int j = 0; j < 8; ++j) acc[j] = 0.f;
    for (int base = s0; base < s1; base += 64) {
        int e0 = base + slot,      e1 = e0 + 8,  e2 = e0 + 16, e3 = e0 + 24;
        int e4 = e0 + 32,          e5 = e0 + 40, e6 = e0 + 48, e7 = e0 + 56;
        // 8 independent packed-edge loads (NT: streamed once)
        unsigned long long q0 = (e0 < s1) ? __builtin_nontemporal_load(epk + e0) : 0ull;
        unsigned long long q1 = (e1 < s1) ? __builtin_nontemporal_load(epk + e1) : 0ull;
        unsigned long long q2 = (e2 < s1) ? __builtin_nontemporal_load(epk + e2) : 0ull;
        unsigned long long q3 = (e3 < s1) ? __builtin_nontemporal_load(epk + e3) : 0ull;
        unsigned long long q4 = (e4 < s1) ? __builtin_nontemporal_load(epk + e4) : 0ull;
        unsigned long long q5 = (e5 < s1) ? __builtin_nontemporal_load(epk + e5) : 0ull;
        unsigned long long q6 = (e6 < s1) ? __builtin_nontemporal_load(epk + e6) : 0ull;
        unsigned long long q7 = (e7 < s1) ? __builtin_nontemporal_load(epk + e7) : 0ull;
        int i0 = (int)(unsigned)q0, i1 = (int)(unsigned)q1;
        int i2 = (int)(unsigned)q2, i3 = (int)(unsigned)q3;
        int i4 = (int)(unsigned)q4, i5 = (int)(unsigned)q5;
        int i6 = (int)(unsigned)q6, i7 = (int)(unsigned)q7;
        // 8 independent 16B row loads (out-of-range -> row 0, weight 0, L1-hot)
        float4 hv0 = *(const float4*)(hmat + (size_t)i0 * 64 + fb);
        float4 hv1 = *(const float4*)(hmat + (size_t)i1 * 64 + fb);
        float4 hv2 = *(const float4*)(hmat + (size_t)i2 * 64 + fb);
        float4 hv3 = *(const float4*)(hmat + (size_t)i3 * 64 + fb);
        float4 hv4 = *(const float4*)(hmat + (size_t)i4 * 64 + fb);
        float4 hv5 = *(const float4*)(hmat + (size_t)i5 * 64 + fb);
        float4 hv6 = *(const float4*)(hmat + (size_t)i6 * 64 + fb);
        float4 hv7 = *(const float4*)(hmat + (size_t)i7 * 64 + fb);
        float w0 = (e0 < s1) ? __expf(__int_as_float((int)(q0 >> 32)) - C) : 0.f;
        float w1 = (e1 < s1) ? __expf(__int_as_float((int)(q1 >> 32)) - C) : 0.f;
        float w2 = (e2 < s1) ? __expf(__int_as_float((int)(q2 >> 32)) - C) : 0.f;
        float w3 = (e3 < s1) ? __expf(__int_as_float((int)(q3 >> 32)) - C) : 0.f;
        float w4 = (e4 < s1) ? __expf(__int_as_float((int)(q4 >> 32)) - C) : 0.f;
        float w5 = (e5 < s1) ? __expf(__int_as_float((int)(q5 >> 32)) - C) : 0.f;
        float w6 = (e6 < s1) ? __expf(__int_as_float((int)(q6 >> 32)) - C) : 0.f;
        float w7 = (e7 < s1) ? __expf(__int_as_float((int)(q7 >> 32)) - C) : 0.f;
        sden += ((w0 + w1) + (w2 + w3)) + ((w4 + w5) + (w6 + w7));
        float2 a, b, c, dd;
#define ACC8(HV, W) \
        a = __half22float2(__builtin_bit_cast(__half2, HV.x)); \
        b = __half22float2(__builtin_bit_cast(__half2, HV.y)); \
        c = __half22float2(__builtin_bit_cast(__half2, HV.z)); \
        dd = __half22float2(__builtin_bit_cast(__half2, HV.w)); \
        acc[0] = fmaf(W, a.x, acc[0]);  acc[1] = fmaf(W, a.y, acc[1]); \
        acc[2] = fmaf(W, b.x, acc[2]);  acc[3] = fmaf(W, b.y, acc[3]); \
        acc[4] = fmaf(W, c.x, acc[4]);  acc[5] = fmaf(W, c.y, acc[5]); \
        acc[6] = fmaf(W, dd.x, acc[6]); acc[7] = fmaf(W, dd.y, acc[7]);
        ACC8(hv0, w0)
        ACC8(hv1, w1)
        ACC8(hv2, w2)
        ACC8(hv3, w3)
        ACC8(hv4, w4)
        ACC8(hv5, w5)
        ACC8(hv6, w6)
        ACC8(hv7, w7)
#undef ACC8
    }
#pragma unroll
    for (int j = 0; j < 8; ++j) {
        acc[j] += __shfl_xor(acc[j], 8, 64);
        acc[j] += __shfl_xor(acc[j], 16, 64);
        acc[j] += __shfl_xor(acc[j], 32, 64);
    }
#pragma unroll
    for (int off = 32; off; off >>= 1) sden += __shfl_xor(sden, off, 64);
    return sden * 0.125f;
}

// ---- fused: GAT layer1 aggregate (+relu) + layer2 linear + alpha dots ----
__global__ __launch_bounds__(256) void agg1(
    const __half* __restrict__ hlin1,
    const float* __restrict__ adst,
    const unsigned* __restrict__ row_ptr,
    const unsigned long long* __restrict__ epk,
    const float* __restrict__ As1, const float* __restrict__ c1b,
    const unsigned* __restrict__ c2w_pk,
    const float* __restrict__ a2s, const float* __restrict__ a2d,
    __half* __restrict__ hlin2, float* __restrict__ asrc2, float* __restrict__ adst2,
    float* __restrict__ blkmax)
{
    __shared__ float vbuf[4][64];
    __shared__ float wred[4];
    int lane = threadIdx.x & 63, w = threadIdx.x >> 6;
    int d = blockIdx.x * 4 + w;
    int s0 = (int)row_ptr[d], s1 = (int)row_ptr[d + 1];
    float C = lrelu(As1[0] + adst[d]);
    float acc[8];
    float den = agg8e(hlin1, epk, s0, s1, C, lane, acc);
    if ((lane >> 3) == 0) {               // slot-0 lanes hold all 64 features
        int fb = (lane & 7) << 3;
#pragma unroll
        for (int j = 0; j < 8; ++j) vbuf[w][fb + j] = acc[j];
    }
    __syncthreads();
    float inv = 1.f / (den + 1e-30f);
    int l2 = (2 * lane) & 63;
    float va = fmaxf(vbuf[w][l2] * inv + c1b[l2], 0.f);
    float vb = fmaxf(vbuf[w][l2 + 1] * inv + c1b[l2 + 1], 0.f);
    unsigned vpk = pkh2(va, vb);
    float hl = 0.f;
#pragma unroll 8
    for (int kk = 0; kk < 32; ++kk)
        hl = fdot2u((unsigned)rli((int)vpk, kk), c2w_pk[kk * 64 + lane], hl);
    hlin2[(size_t)d * 64 + lane] = __float2half(hl);
    float ps = hl * a2s[lane], pd = hl * a2d[lane];
#pragma unroll
    for (int off = 32; off; off >>= 1) {
        ps += __shfl_xor(ps, off, 64);
        pd += __shfl_xor(pd, off, 64);
    }
    if (lane == 0) { asrc2[d] = ps; adst2[d] = pd; wred[w] = ps; }
    __syncthreads();
    if (threadIdx.x == 0)
        blkmax[blockIdx.x] = fmaxf(fmaxf(wred[0], wred[1]), fmaxf(wred[2], wred[3]));
}

// ---- fused: GAT layer2 aggregate + bias + global max pool ----
__global__ __launch_bounds__(256) void agg2_pool(
    const __half* __restrict__ hlin2,
    const float* __restrict__ adst2,
    const unsigned* __restrict__ row_ptr,
    const unsigned long long* __restrict__ epk,
    const float* __restrict__ As2, const float* __restrict__ c2b,
    const int* __restrict__ batch, unsigned* __restrict__ g_enc)
{
    __shared__ float vbuf[4][64];
    int lane = threadIdx.x & 63, w = threadIdx.x >> 6;
    int d = blockIdx.x * 4 + w;
    int s0 = (int)row_ptr[d], s1 = (int)row_ptr[d + 1];
    float C = lrelu(As2[0] + adst2[d]);
    float acc[8];
    float den = agg8e(hlin2, epk, s0, s1, C, lane, acc);
    if ((lane >> 3) == 0) {
        int fb = (lane & 7) << 3;
#pragma unroll
        for (int j = 0; j < 8; ++j) vbuf[w][fb + j] = acc[j];
    }
    __syncthreads();
    float v = vbuf[w][lane] / (den + 1e-30f) + c2b[lane];   // no relu
    atomicMax(&g_enc[batch[d] * 64 + lane], fenc(v));
}

// ---- readout MLP: wave per graph ----
__global__ __launch_bounds__(256) void readout(
    const unsigned* __restrict__ g_enc,
    const float* __restrict__ fc1w, const float* __restrict__ fc1b,
    const float* __restrict__ fc2w, const float* __restrict__ fc2b,
    float* __restrict__ out)
{
    int lane = threadIdx.x & 63;
    int gi = blockIdx.x * 4 + (threadIdx.x >> 6);
    float gv = fdec(g_enc[gi * 64 + lane]);
    float a = fc1b[lane];
#pragma unroll 8
    for (int k = 0; k < 64; ++k)
        a = fmaf(rlf(gv, k), fc1w[k * 64 + lane], a);
    a = fmaxf(a, 0.f) * fc2w[lane];
#pragma unroll
    for (int off = 32; off; off >>= 1) a += __shfl_xor(a, off, 64);
    if (lane == 0) out[gi] = a + fc2b[0];
}

extern "C" void kernel_launch(void* const* d_in, const int* in_sizes, int n_in,
                              void* d_out, int out_size, void* d_ws, size_t ws_size,
                              hipStream_t stream)
{
    const float* x      = (const float*)d_in[0];
    const int*   ei     = (const int*)d_in[1];
    // d_in[2] edge_attr: dead value in reference, never read
    const int*   batch  = (const int*)d_in[3];
    const float* n_w1   = (const float*)d_in[4];
    const float* n_b1   = (const float*)d_in[5];
    const float* n_w2   = (const float*)d_in[6];
    const float* n_b2   = (const float*)d_in[7];
    // d_in[8..11] edge MLP weights: dead
    const float* c1_w    = (const float*)d_in[12];
    const float* c1_asrc = (const float*)d_in[13];
    const float* c1_adst = (const float*)d_in[14];
    const float* c1_b    = (const float*)d_in[15];
    const float* c2_w    = (const float*)d_in[16];
    const float* c2_asrc = (const float*)d_in[17];
    const float* c2_adst = (const float*)d_in[18];
    const float* c2_b    = (const float*)d_in[19];
    const float* fc1_w   = (const float*)d_in[20];
    const float* fc1_b   = (const float*)d_in[21];
    const float* fc2_w   = (const float*)d_in[22];
    const float* fc2_b   = (const float*)d_in[23];
    float* out = (float*)d_out;

    // workspace carve (256B aligned)
    char* ws = (char*)d_ws;
    size_t off = 0;
    auto alloc = [&](size_t bytes) -> void* {
        off = (off + 255) & ~(size_t)255;
        void* p = ws + off;
        off += bytes;
        return p;
    };
    unsigned* sub_tail = (unsigned*)alloc(sizeof(unsigned) * NSUB);
    unsigned* sub_buf  = (unsigned*)alloc(sizeof(unsigned) * (size_t)NSUB * SUB_CAP);
    unsigned* row_ptr  = (unsigned*)alloc(sizeof(unsigned) * (N_NODES + 1));
    unsigned long long* epk =
        (unsigned long long*)alloc(sizeof(unsigned long long) * E_TOT);
    __half*   hlin1    = (__half*)alloc(sizeof(__half) * (size_t)N_NODES * 64);
    __half*   hlin2    = (__half*)alloc(sizeof(__half) * (size_t)N_NODES * 64);
    float*    asrc1    = (float*)alloc(sizeof(float) * N_NODES);
    float*    adst1    = (float*)alloc(sizeof(float) * N_NODES);
    float*    asrc2    = (float*)alloc(sizeof(float) * N_NODES);
    float*    adst2    = (float*)alloc(sizeof(float) * N_NODES);
    unsigned* g_enc    = (unsigned*)alloc(sizeof(unsigned) * N_GRAPHS * HIDDEN);
    unsigned* nw1_pk   = (unsigned*)alloc(sizeof(unsigned) * 64 * 64);
    unsigned* w2c1_pk  = (unsigned*)alloc(sizeof(unsigned) * 32 * 64);
    unsigned* c2w_pk   = (unsigned*)alloc(sizeof(unsigned) * 32 * 64);
    float*    b2c1     = (float*)alloc(sizeof(float) * 64);
    float*    blkmax1  = (float*)alloc(sizeof(float) * EMB_B);
    float*    blkmax2  = (float*)alloc(sizeof(float) * AGG_B);
    float*    As1      = (float*)alloc(sizeof(float) * 2);
    float*    As2      = (float*)alloc(sizeof(float) * 2);

    fold_w<<<1, 256, 0, stream>>>(n_w1, n_w2, n_b2, c1_w, c2_w,
                                  nw1_pk, w2c1_pk, c2w_pk, b2c1, g_enc, sub_tail);

    // bucket (640 blocks, overlaps embed) + embed (1563 blocks)
    embed_bucket<<<BUCKET_B + EMB_B, 256, 0, stream>>>(
        x, nw1_pk, n_b1, w2c1_pk, b2c1, c1_asrc, c1_adst,
        hlin1, asrc1, adst1, blkmax1,
        ei, sub_tail, sub_buf);

    // CSR build -> packed (src, el1) records + As1 reduce
    csr_as1<<<NSUB + 1, 256, 0, stream>>>(
        sub_buf, sub_tail, asrc1, adst1, row_ptr, epk, blkmax1, As1);

    agg1<<<AGG_B, 256, 0, stream>>>(
        hlin1, adst1, row_ptr, epk, As1,
        c1_b, c2w_pk, c2_asrc, c2_adst, hlin2, asrc2, adst2, blkmax2);

    // layer-2 edge logits (epk overwrite) + As2 reduce
    wfill2<<<AGG_B + 1, 256, 0, stream>>>(
        row_ptr, asrc2, adst2, epk, blkmax2, As2);

    agg2_pool<<<AGG_B, 256, 0, stream>>>(
        hlin2, adst2, row_ptr, epk, As2, c2_b, batch, g_enc);
    readout<<<N_GRAPHS / 4, 256, 0, stream>>>(g_enc, fc1_w, fc1_b, fc2_w, fc2_b, out);
}

// Round 20
// 247.526 us; speedup vs baseline: 1.0538x; 1.0538x over previous
//
#include <hip/hip_runtime.h>
#include <hip/hip_fp16.h>
#include <math.h>

#define N_NODES   50000
#define N_EDGES   1600000
#define E_TOT     (N_EDGES + N_NODES)
#define N_FEAT    128
#define HIDDEN    64
#define N_GRAPHS  128
#define NEG_SLOPE 0.2f
#define NSUB      256                      // sub-buckets over dst space
#define SUB_NODES 196                      // nodes per sub
#define SUB_CAP   8192                     // per-sub global capacity (mean 6250)
#define BUCKET_B  640
#define BCHUNK    2500                     // N_EDGES / BUCKET_B
#define SB_CAP2   17                       // LDS cap/sub (19.5KB -> 8 blocks/CU)
#define EMB_B     ((N_NODES + 31) / 32)    // 1563 embed blocks (8 nodes/wave)
#define AGG_B     (N_NODES / 4)            // agg blocks (1 dst/wave)

// ---- monotone float<->uint encoding for atomicMax on floats ----
__device__ __forceinline__ unsigned fenc(float f) {
    unsigned u = __float_as_uint(f);
    return (u & 0x80000000u) ? ~u : (u | 0x80000000u);
}
__device__ __forceinline__ float fdec(unsigned k) {
    unsigned u = (k & 0x80000000u) ? (k & 0x7FFFFFFFu) : ~k;
    return __uint_as_float(u);
}
__device__ __forceinline__ float lrelu(float e) {
    return (e >= 0.f) ? e : NEG_SLOPE * e;
}
__device__ __forceinline__ int rli(int v, int l) {
    return __builtin_amdgcn_readlane(v, l);
}
__device__ __forceinline__ float rlf(float v, int l) {
    return __int_as_float(__builtin_amdgcn_readlane(__float_as_int(v), l));
}
// ---- fp16-pair pack + v_dot2_f32_f16 (fp16 mul, fp32 accumulate) ----
typedef _Float16 h2v __attribute__((ext_vector_type(2)));
__device__ __forceinline__ unsigned pkh2(float a, float b) {
    h2v v; v.x = (_Float16)a; v.y = (_Float16)b;
    return __builtin_bit_cast(unsigned, v);
}
__device__ __forceinline__ float fdot2u(unsigned a, unsigned b, float c) {
    return __builtin_amdgcn_fdot2(__builtin_bit_cast(h2v, a),
                                  __builtin_bit_cast(h2v, b), c, false);
}
// ---- packed edge record: low32 = src, high32 = el bits ----
__device__ __forceinline__ unsigned long long pke(int src, float el) {
    return ((unsigned long long)(unsigned)__float_as_int(el) << 32) |
           (unsigned long long)(unsigned)src;
}

// ---- fold: W2C1=w2@c1w; pack nw1, w2c1, c2w; init g_enc + sub_tail ----
__global__ __launch_bounds__(256) void fold_w(
    const float* __restrict__ nw1,
    const float* __restrict__ w2, const float* __restrict__ b2,
    const float* __restrict__ c1w, const float* __restrict__ c2w,
    unsigned* __restrict__ nw1_pk, unsigned* __restrict__ w2c1_pk,
    unsigned* __restrict__ c2w_pk,
    float* __restrict__ b2c1, unsigned* __restrict__ g_enc,
    unsigned* __restrict__ sub_tail)
{
    __shared__ float c1s[4096];
    __shared__ float w2c1s[4096];
    int tid = threadIdx.x;
    for (int i = tid; i < 4096; i += 256) c1s[i] = c1w[i];
    for (int i = tid; i < N_GRAPHS * HIDDEN; i += 256) g_enc[i] = fenc(-INFINITY);
    sub_tail[tid] = 0u;
    __syncthreads();
    int j = tid & 63, i0 = tid >> 6;
    for (int ii = 0; ii < 16; ++ii) {
        int i = i0 * 16 + ii;
        float a = 0.f;
#pragma unroll 8
        for (int k = 0; k < 64; ++k) a = fmaf(w2[i * 64 + k], c1s[k * 64 + j], a);
        w2c1s[i * 64 + j] = a;
    }
    if (tid < 64) {
        float a = 0.f;
#pragma unroll 8
        for (int k = 0; k < 64; ++k) a = fmaf(b2[k], c1s[k * 64 + tid], a);
        b2c1[tid] = a;
    }
    __syncthreads();
    for (int idx = tid; idx < 64 * 64; idx += 256) {
        int kk = idx >> 6, jj = idx & 63;
        nw1_pk[idx] = pkh2(nw1[(2 * kk) * 64 + jj], nw1[(2 * kk + 1) * 64 + jj]);
    }
    for (int idx = tid; idx < 32 * 64; idx += 256) {
        int kk = idx >> 6, jj = idx & 63;
        w2c1_pk[idx] = pkh2(w2c1s[(2 * kk) * 64 + jj], w2c1s[(2 * kk + 1) * 64 + jj]);
        c2w_pk[idx]  = pkh2(c2w[(2 * kk) * 64 + jj],  c2w[(2 * kk + 1) * 64 + jj]);
    }
}

// ---- FUSED: bucket blocks [0,BUCKET_B) + embed blocks [BUCKET_B, +EMB_B) ----
__global__ __launch_bounds__(256) void embed_bucket(
    const float* __restrict__ x,
    const unsigned* __restrict__ nw1_pk, const float* __restrict__ n_b1,
    const unsigned* __restrict__ w2c1_pk, const float* __restrict__ b2c1,
    const float* __restrict__ a1s, const float* __restrict__ a1d,
    __half* __restrict__ hlin,
    float* __restrict__ asrc, float* __restrict__ adst,
    float* __restrict__ blkmax,
    const int* __restrict__ ei,
    unsigned* __restrict__ sub_tail, unsigned* __restrict__ sub_buf)
{
    __shared__ unsigned st[NSUB][SB_CAP2];    // 17.4 KB, odd stride: conflict-free
    __shared__ unsigned scnt[NSUB];
    __shared__ unsigned sbase[NSUB];
    __shared__ float wred[4];
    int tid = threadIdx.x;
    int lane = tid & 63, wid = tid >> 6;

    if (blockIdx.x < BUCKET_B) {
        // ---------- bucket path ----------
        scnt[tid] = 0u;
        __syncthreads();
        int beg = blockIdx.x * BCHUNK;
        int end = min(beg + BCHUNK, N_EDGES);
        for (int base = beg; base < end; base += 256) {
            int e = base + tid;
            if (e < end) {
                unsigned src = (unsigned)__builtin_nontemporal_load(ei + e);
                unsigned dst = (unsigned)__builtin_nontemporal_load(ei + N_EDGES + e);
                unsigned sub = dst / SUB_NODES;
                unsigned pay = ((dst - sub * SUB_NODES) << 16) | src;
                unsigned p = atomicAdd(&scnt[sub], 1u);
                if (p < SB_CAP2) st[sub][p] = pay;
                else {                           // ~1% overflow: direct write
                    unsigned gp = atomicAdd(&sub_tail[sub], 1u);
                    if (gp < SUB_CAP)
                        __builtin_nontemporal_store(pay, sub_buf + (size_t)sub * SUB_CAP + gp);
                }
            }
        }
        __syncthreads();
        unsigned c = min(scnt[tid], (unsigned)SB_CAP2);
        scnt[tid] = c;
        sbase[tid] = atomicAdd(&sub_tail[tid], c);
        __syncthreads();
        // wave-coalesced flush: wave handles subs wid, wid+4, ...; lanes 0..c-1
        for (int o = wid; o < NSUB; o += 4) {
            unsigned c_o = scnt[o];
            if ((unsigned)lane < c_o) {
                unsigned pos = sbase[o] + lane;
                if (pos < SUB_CAP)
                    __builtin_nontemporal_store(st[o][lane],
                        sub_buf + (size_t)o * SUB_CAP + pos);
            }
        }
    } else {
        // ---------- embed path: MLP + folded linear via packed dot2 ----------
        int eb = blockIdx.x - BUCKET_B;
        int n0 = eb * 32 + wid * 8;
        if (n0 < N_NODES) {
            unsigned xpk[8];
#pragma unroll
            for (int nn = 0; nn < 8; ++nn) {
                float2 v = ((const float2*)(x + (size_t)(n0 + nn) * N_FEAT))[lane];
                xpk[nn] = pkh2(v.x, v.y);
            }
            float acc[8];
            float b1v = n_b1[lane];
#pragma unroll
            for (int nn = 0; nn < 8; ++nn) acc[nn] = b1v;
#pragma unroll 4
            for (int kk = 0; kk < 64; ++kk) {
                unsigned wp = nw1_pk[kk * 64 + lane];
#pragma unroll
                for (int nn = 0; nn < 8; ++nn)
                    acc[nn] = fdot2u((unsigned)rli((int)xpk[nn], kk), wp, acc[nn]);
            }
#pragma unroll
            for (int nn = 0; nn < 8; ++nn) acc[nn] = fmaxf(acc[nn], 0.f);
            unsigned hpk[8];
#pragma unroll
            for (int nn = 0; nn < 8; ++nn) {
                float ha = __shfl(acc[nn], (2 * lane) & 63, 64);
                float hb = __shfl(acc[nn], (2 * lane + 1) & 63, 64);
                hpk[nn] = pkh2(ha, hb);
            }
            float hl[8];
            float bcv = b2c1[lane];
#pragma unroll
            for (int nn = 0; nn < 8; ++nn) hl[nn] = bcv;
#pragma unroll 4
            for (int kk = 0; kk < 32; ++kk) {
                unsigned wp = w2c1_pk[kk * 64 + lane];
#pragma unroll
                for (int nn = 0; nn < 8; ++nn)
                    hl[nn] = fdot2u((unsigned)rli((int)hpk[nn], kk), wp, hl[nn]);
            }
            float s1v = a1s[lane], d1v = a1d[lane];
            float wmax = -INFINITY;
#pragma unroll
            for (int nn = 0; nn < 8; ++nn) {
                int n = n0 + nn;
                hlin[(size_t)n * 64 + lane] = __float2half(hl[nn]);
                float ps = hl[nn] * s1v, pd = hl[nn] * d1v;
#pragma unroll
                for (int off = 32; off; off >>= 1) {
                    ps += __shfl_xor(ps, off, 64);
                    pd += __shfl_xor(pd, off, 64);
                }
                if (lane == 0) { asrc[n] = ps; adst[n] = pd; wmax = fmaxf(wmax, ps); }
            }
            if (lane == 0) wred[wid] = wmax;
        } else if (lane == 0) wred[wid] = -INFINITY;
        __syncthreads();
        if (tid == 0)
            blkmax[eb] = fmaxf(fmaxf(wred[0], wred[1]), fmaxf(wred[2], wred[3]));
    }
}

// ---- CSR build (256 per-sub blocks, zero global atomics) -> epk + As1 ----
__global__ __launch_bounds__(256) void csr_as1(
    const unsigned* __restrict__ sub_buf, const unsigned* __restrict__ sub_tail,
    const float* __restrict__ asrc1, const float* __restrict__ adst1,
    unsigned* __restrict__ row_ptr, unsigned long long* __restrict__ epk,
    const float* __restrict__ blkmax1, float* __restrict__ As1)
{
    __shared__ unsigned hist[SUB_NODES];
    __shared__ unsigned wt4[4], wo4[4];
    __shared__ unsigned eb_s[2];
    __shared__ unsigned tot_s;
    int tid = threadIdx.x, lane = tid & 63, wid = tid >> 6;

    if (blockIdx.x == NSUB) {              // As1 reduction block
        float m = -INFINITY;
        for (int i = tid; i < EMB_B; i += 256) m = fmaxf(m, blkmax1[i]);
#pragma unroll
        for (int off = 32; off; off >>= 1) m = fmaxf(m, __shfl_xor(m, off, 64));
        float* sm = (float*)wt4;
        if (lane == 0) sm[wid] = m;
        __syncthreads();
        if (tid == 0)
            As1[0] = fmaxf(fmaxf(sm[0], sm[1]), fmaxf(sm[2], sm[3]));
        return;
    }
    int gs = blockIdx.x;                   // 0..255
    unsigned myc = min(sub_tail[tid], (unsigned)SUB_CAP);
    unsigned nn_t = (tid < NSUB - 1) ? SUB_NODES : (N_NODES - (NSUB - 1) * SUB_NODES);
    unsigned v = myc + nn_t;
    unsigned xs = v;
#pragma unroll
    for (int off = 1; off < 64; off <<= 1) {
        unsigned t = __shfl_up(xs, off, 64);
        if (lane >= off) xs += t;
    }
    if (lane == 63) wt4[wid] = xs;
    __syncthreads();
    if (tid == 0) {
        unsigned run = 0;
        for (int w = 0; w < 4; ++w) { wo4[w] = run; run += wt4[w]; }
        tot_s = run;
    }
    __syncthreads();
    unsigned excl = wo4[wid] + xs - v;
    if (tid == gs) { eb_s[0] = excl; eb_s[1] = myc; }
    if (gs == 0 && tid == 0) row_ptr[N_NODES] = tot_s;
    __syncthreads();
    unsigned ebase = eb_s[0], cnt = eb_s[1];
    int node_lo = gs * SUB_NODES;
    int nn = (gs < NSUB - 1) ? SUB_NODES : (N_NODES - (NSUB - 1) * SUB_NODES);
    for (int i = tid; i < nn; i += 256) hist[i] = 1u;
    __syncthreads();
    const unsigned* seg = sub_buf + (size_t)gs * SUB_CAP;
    for (unsigned i = tid; i < cnt; i += 256)
        atomicAdd(&hist[__builtin_nontemporal_load(seg + i) >> 16], 1u);
    __syncthreads();
    unsigned v2 = (tid < nn) ? hist[tid] : 0u;
    unsigned xs2 = v2;
#pragma unroll
    for (int off = 1; off < 64; off <<= 1) {
        unsigned t = __shfl_up(xs2, off, 64);
        if (lane >= off) xs2 += t;
    }
    __syncthreads();
    if (lane == 63) wt4[wid] = xs2;
    __syncthreads();
    if (tid == 0) {
        unsigned run = 0;
        for (int w = 0; w < 4; ++w) { wo4[w] = run; run += wt4[w]; }
    }
    __syncthreads();
    if (tid < nn) {
        unsigned ex2 = wo4[wid] + xs2 - v2;
        unsigned rp = ebase + ex2;
        int n = node_lo + tid;
        row_ptr[n] = rp;
        epk[rp] = pke(n, lrelu(asrc1[n] + adst1[n]));   // self-loop first slot
        hist[tid] = ex2 + 1u;
    }
    __syncthreads();
    // scatter + layer-1 edge logit packed with src
    for (unsigned i = tid; i < cnt; i += 256) {
        unsigned pay = __builtin_nontemporal_load(seg + i);
        unsigned dl = pay >> 16;
        int src = (int)(pay & 0xffffu);
        unsigned p = atomicAdd(&hist[dl], 1u);
        epk[ebase + p] = pke(src, lrelu(asrc1[src] + adst1[node_lo + (int)dl]));
    }
}

// ---- layer-2 edge logits (epk.el overwrite) + As2 reduce (extra block) ----
__global__ __launch_bounds__(256) void wfill2(
    const unsigned* __restrict__ row_ptr,
    const float* __restrict__ asrc2, const float* __restrict__ adst2,
    unsigned long long* __restrict__ epk,
    const float* __restrict__ blkmax2, float* __restrict__ As2)
{
    int lane = threadIdx.x & 63, w = threadIdx.x >> 6;
    if (blockIdx.x == AGG_B) {             // As2 reduction block
        __shared__ float sm[4];
        int tid = threadIdx.x;
        float m = -INFINITY;
        for (int i = tid; i < AGG_B; i += 256) m = fmaxf(m, blkmax2[i]);
#pragma unroll
        for (int off = 32; off; off >>= 1) m = fmaxf(m, __shfl_xor(m, off, 64));
        if (lane == 0) sm[w] = m;
        __syncthreads();
        if (tid == 0)
            As2[0] = fmaxf(fmaxf(sm[0], sm[1]), fmaxf(sm[2], sm[3]));
        return;
    }
    int d = blockIdx.x * 4 + w;
    int s0 = (int)row_ptr[d], s1 = (int)row_ptr[d + 1];
    float ad = adst2[d];
    // 2 independent edge records in flight per lane
    for (int i = s0 + lane; i < s1; i += 128) {
        int i2 = i + 64;
        unsigned long long q0 = epk[i];
        unsigned long long q1 = (i2 < s1) ? epk[i2] : 0ull;
        int src0 = (int)(unsigned)(q0 & 0xffffffffu);
        int src1 = (int)(unsigned)(q1 & 0xffffffffu);
        epk[i] = pke(src0, lrelu(asrc2[src0] + ad));
        if (i2 < s1) epk[i2] = pke(src1, lrelu(asrc2[src1] + ad));
    }
}

// ---- agg core: 8 lanes/edge, U=4 burst; row loads issued before exp ----
__device__ __forceinline__ float agg8e(
    const __half* __restrict__ hmat,      // [N][64] fp16 (128B rows)
    const unsigned long long* __restrict__ epk,
    int s0, int s1, float C, int lane, float acc[8])
{
    int slot = lane >> 3;
    int fb = (lane & 7) << 3;
    float sden = 0.f;
#pragma unroll
    for (int j = 0; j < 8; ++j) acc[j] = 0.f;
    for (int base = s0; base < s1; base += 32) {
        int e0 = base + slot, e1 = e0 + 8, e2 = e0 + 16, e3 = e0 + 24;
        // phase 1: 4 independent packed-edge loads (NT: streamed once)
        unsigned long long q0 = (e0 < s1) ? __builtin_nontemporal_load(epk + e0) : 0ull;
        unsigned long long q1 = (e1 < s1) ? __builtin_nontemporal_load(epk + e1) : 0ull;
        unsigned long long q2 = (e2 < s1) ? __builtin_nontemporal_load(epk + e2) : 0ull;
        unsigned long long q3 = (e3 < s1) ? __builtin_nontemporal_load(epk + e3) : 0ull;
        int i0 = (int)(unsigned)q0, i1 = (int)(unsigned)q1;
        int i2 = (int)(unsigned)q2, i3 = (int)(unsigned)q3;
        // phase 2: issue 4 independent 16B row loads IMMEDIATELY (dep: idx only)
        float4 hv0 = *(const float4*)(hmat + (size_t)i0 * 64 + fb);
        float4 hv1 = *(const float4*)(hmat + (size_t)i1 * 64 + fb);
        float4 hv2 = *(const float4*)(hmat + (size_t)i2 * 64 + fb);
        float4 hv3 = *(const float4*)(hmat + (size_t)i3 * 64 + fb);
        // phase 3: exp chain overlaps row-load latency
        float w0 = (e0 < s1) ? __expf(__int_as_float((int)(q0 >> 32)) - C) : 0.f;
        float w1 = (e1 < s1) ? __expf(__int_as_float((int)(q1 >> 32)) - C) : 0.f;
        float w2 = (e2 < s1) ? __expf(__int_as_float((int)(q2 >> 32)) - C) : 0.f;
        float w3 = (e3 < s1) ? __expf(__int_as_float((int)(q3 >> 32)) - C) : 0.f;
        sden += (w0 + w1) + (w2 + w3);
        // phase 4: accumulate
        float2 a, b, c, dd;
#define ACC8(HV, W) \
        a = __half22float2(__builtin_bit_cast(__half2, HV.x)); \
        b = __half22float2(__builtin_bit_cast(__half2, HV.y)); \
        c = __half22float2(__builtin_bit_cast(__half2, HV.z)); \
        dd = __half22float2(__builtin_bit_cast(__half2, HV.w)); \
        acc[0] = fmaf(W, a.x, acc[0]);  acc[1] = fmaf(W, a.y, acc[1]); \
        acc[2] = fmaf(W, b.x, acc[2]);  acc[3] = fmaf(W, b.y, acc[3]); \
        acc[4] = fmaf(W, c.x, acc[4]);  acc[5] = fmaf(W, c.y, acc[5]); \
        acc[6] = fmaf(W, dd.x, acc[6]); acc[7] = fmaf(W, dd.y, acc[7]);
        ACC8(hv0, w0)
        ACC8(hv1, w1)
        ACC8(hv2, w2)
        ACC8(hv3, w3)
#undef ACC8
    }
#pragma unroll
    for (int j = 0; j < 8; ++j) {
        acc[j] += __shfl_xor(acc[j], 8, 64);
        acc[j] += __shfl_xor(acc[j], 16, 64);
        acc[j] += __shfl_xor(acc[j], 32, 64);
    }
#pragma unroll
    for (int off = 32; off; off >>= 1) sden += __shfl_xor(sden, off, 64);
    return sden * 0.125f;
}

// ---- fused: GAT layer1 aggregate (+relu) + layer2 linear + alpha dots ----
__global__ __launch_bounds__(256) void agg1(
    const __half* __restrict__ hlin1,
    const float* __restrict__ adst,
    const unsigned* __restrict__ row_ptr,
    const unsigned long long* __restrict__ epk,
    const float* __restrict__ As1, const float* __restrict__ c1b,
    const unsigned* __restrict__ c2w_pk,
    const float* __restrict__ a2s, const float* __restrict__ a2d,
    __half* __restrict__ hlin2, float* __restrict__ asrc2, float* __restrict__ adst2,
    float* __restrict__ blkmax)
{
    __shared__ float vbuf[4][64];
    __shared__ float wred[4];
    int lane = threadIdx.x & 63, w = threadIdx.x >> 6;
    int d = blockIdx.x * 4 + w;
    int s0 = (int)row_ptr[d], s1 = (int)row_ptr[d + 1];
    float C = lrelu(As1[0] + adst[d]);
    float acc[8];
    float den = agg8e(hlin1, epk, s0, s1, C, lane, acc);
    if ((lane >> 3) == 0) {               // slot-0 lanes hold all 64 features
        int fb = (lane & 7) << 3;
#pragma unroll
        for (int j = 0; j < 8; ++j) vbuf[w][fb + j] = acc[j];
    }
    __syncthreads();
    float inv = 1.f / (den + 1e-30f);
    int l2 = (2 * lane) & 63;
    float va = fmaxf(vbuf[w][l2] * inv + c1b[l2], 0.f);
    float vb = fmaxf(vbuf[w][l2 + 1] * inv + c1b[l2 + 1], 0.f);
    unsigned vpk = pkh2(va, vb);
    float hl = 0.f;
#pragma unroll 8
    for (int kk = 0; kk < 32; ++kk)
        hl = fdot2u((unsigned)rli((int)vpk, kk), c2w_pk[kk * 64 + lane], hl);
    hlin2[(size_t)d * 64 + lane] = __float2half(hl);
    float ps = hl * a2s[lane], pd = hl * a2d[lane];
#pragma unroll
    for (int off = 32; off; off >>= 1) {
        ps += __shfl_xor(ps, off, 64);
        pd += __shfl_xor(pd, off, 64);
    }
    if (lane == 0) { asrc2[d] = ps; adst2[d] = pd; wred[w] = ps; }
    __syncthreads();
    if (threadIdx.x == 0)
        blkmax[blockIdx.x] = fmaxf(fmaxf(wred[0], wred[1]), fmaxf(wred[2], wred[3]));
}

// ---- fused: GAT layer2 aggregate + bias + global max pool ----
__global__ __launch_bounds__(256) void agg2_pool(
    const __half* __restrict__ hlin2,
    const float* __restrict__ adst2,
    const unsigned* __restrict__ row_ptr,
    const unsigned long long* __restrict__ epk,
    const float* __restrict__ As2, const float* __restrict__ c2b,
    const int* __restrict__ batch, unsigned* __restrict__ g_enc)
{
    __shared__ float vbuf[4][64];
    int lane = threadIdx.x & 63, w = threadIdx.x >> 6;
    int d = blockIdx.x * 4 + w;
    int s0 = (int)row_ptr[d], s1 = (int)row_ptr[d + 1];
    float C = lrelu(As2[0] + adst2[d]);
    float acc[8];
    float den = agg8e(hlin2, epk, s0, s1, C, lane, acc);
    if ((lane >> 3) == 0) {
        int fb = (lane & 7) << 3;
#pragma unroll
        for (int j = 0; j < 8; ++j) vbuf[w][fb + j] = acc[j];
    }
    __syncthreads();
    float v = vbuf[w][lane] / (den + 1e-30f) + c2b[lane];   // no relu
    atomicMax(&g_enc[batch[d] * 64 + lane], fenc(v));
}

// ---- readout MLP: wave per graph ----
__global__ __launch_bounds__(256) void readout(
    const unsigned* __restrict__ g_enc,
    const float* __restrict__ fc1w, const float* __restrict__ fc1b,
    const float* __restrict__ fc2w, const float* __restrict__ fc2b,
    float* __restrict__ out)
{
    int lane = threadIdx.x & 63;
    int gi = blockIdx.x * 4 + (threadIdx.x >> 6);
    float gv = fdec(g_enc[gi * 64 + lane]);
    float a = fc1b[lane];
#pragma unroll 8
    for (int k = 0; k < 64; ++k)
        a = fmaf(rlf(gv, k), fc1w[k * 64 + lane], a);
    a = fmaxf(a, 0.f) * fc2w[lane];
#pragma unroll
    for (int off = 32; off; off >>= 1) a += __shfl_xor(a, off, 64);
    if (lane == 0) out[gi] = a + fc2b[0];
}

extern "C" void kernel_launch(void* const* d_in, const int* in_sizes, int n_in,
                              void* d_out, int out_size, void* d_ws, size_t ws_size,
                              hipStream_t stream)
{
    const float* x      = (const float*)d_in[0];
    const int*   ei     = (const int*)d_in[1];
    // d_in[2] edge_attr: dead value in reference, never read
    const int*   batch  = (const int*)d_in[3];
    const float* n_w1   = (const float*)d_in[4];
    const float* n_b1   = (const float*)d_in[5];
    const float* n_w2   = (const float*)d_in[6];
    const float* n_b2   = (const float*)d_in[7];
    // d_in[8..11] edge MLP weights: dead
    const float* c1_w    = (const float*)d_in[12];
    const float* c1_asrc = (const float*)d_in[13];
    const float* c1_adst = (const float*)d_in[14];
    const float* c1_b    = (const float*)d_in[15];
    const float* c2_w    = (const float*)d_in[16];
    const float* c2_asrc = (const float*)d_in[17];
    const float* c2_adst = (const float*)d_in[18];
    const float* c2_b    = (const float*)d_in[19];
    const float* fc1_w   = (const float*)d_in[20];
    const float* fc1_b   = (const float*)d_in[21];
    const float* fc2_w   = (const float*)d_in[22];
    const float* fc2_b   = (const float*)d_in[23];
    float* out = (float*)d_out;

    // workspace carve (256B aligned)
    char* ws = (char*)d_ws;
    size_t off = 0;
    auto alloc = [&](size_t bytes) -> void* {
        off = (off + 255) & ~(size_t)255;
        void* p = ws + off;
        off += bytes;
        return p;
    };
    unsigned* sub_tail = (unsigned*)alloc(sizeof(unsigned) * NSUB);
    unsigned* sub_buf  = (unsigned*)alloc(sizeof(unsigned) * (size_t)NSUB * SUB_CAP);
    unsigned* row_ptr  = (unsigned*)alloc(sizeof(unsigned) * (N_NODES + 1));
    unsigned long long* epk =
        (unsigned long long*)alloc(sizeof(unsigned long long) * E_TOT);
    __half*   hlin1    = (__half*)alloc(sizeof(__half) * (size_t)N_NODES * 64);
    __half*   hlin2    = (__half*)alloc(sizeof(__half) * (size_t)N_NODES * 64);
    float*    asrc1    = (float*)alloc(sizeof(float) * N_NODES);
    float*    adst1    = (float*)alloc(sizeof(float) * N_NODES);
    float*    asrc2    = (float*)alloc(sizeof(float) * N_NODES);
    float*    adst2    = (float*)alloc(sizeof(float) * N_NODES);
    unsigned* g_enc    = (unsigned*)alloc(sizeof(unsigned) * N_GRAPHS * HIDDEN);
    unsigned* nw1_pk   = (unsigned*)alloc(sizeof(unsigned) * 64 * 64);
    unsigned* w2c1_pk  = (unsigned*)alloc(sizeof(unsigned) * 32 * 64);
    unsigned* c2w_pk   = (unsigned*)alloc(sizeof(unsigned) * 32 * 64);
    float*    b2c1     = (float*)alloc(sizeof(float) * 64);
    float*    blkmax1  = (float*)alloc(sizeof(float) * EMB_B);
    float*    blkmax2  = (float*)alloc(sizeof(float) * AGG_B);
    float*    As1      = (float*)alloc(sizeof(float) * 2);
    float*    As2      = (float*)alloc(sizeof(float) * 2);

    fold_w<<<1, 256, 0, stream>>>(n_w1, n_w2, n_b2, c1_w, c2_w,
                                  nw1_pk, w2c1_pk, c2w_pk, b2c1, g_enc, sub_tail);

    // bucket (640 blocks, overlaps embed) + embed (1563 blocks)
    embed_bucket<<<BUCKET_B + EMB_B, 256, 0, stream>>>(
        x, nw1_pk, n_b1, w2c1_pk, b2c1, c1_asrc, c1_adst,
        hlin1, asrc1, adst1, blkmax1,
        ei, sub_tail, sub_buf);

    // CSR build -> packed (src, el1) records + As1 reduce
    csr_as1<<<NSUB + 1, 256, 0, stream>>>(
        sub_buf, sub_tail, asrc1, adst1, row_ptr, epk, blkmax1, As1);

    agg1<<<AGG_B, 256, 0, stream>>>(
        hlin1, adst1, row_ptr, epk, As1,
        c1_b, c2w_pk, c2_asrc, c2_adst, hlin2, asrc2, adst2, blkmax2);

    // layer-2 edge logits (epk overwrite) + As2 reduce
    wfill2<<<AGG_B + 1, 256, 0, stream>>>(
        row_ptr, asrc2, adst2, epk, blkmax2, As2);

    agg2_pool<<<AGG_B, 256, 0, stream>>>(
        hlin2, adst2, row_ptr, epk, As2, c2_b, batch, g_enc);
    readout<<<N_GRAPHS / 4, 256, 0, stream>>>(g_enc, fc1_w, fc1_b, fc2_w, fc2_b, out);
}

// Round 21
// 244.023 us; speedup vs baseline: 1.0689x; 1.0144x over previous
//
#include <hip/hip_runtime.h>
#include <hip/hip_fp16.h>
#include <math.h>

#define N_NODES   50000
#define N_EDGES   1600000
#define E_TOT     (N_EDGES + N_NODES)
#define N_FEAT    128
#define HIDDEN    64
#define N_GRAPHS  128
#define NEG_SLOPE 0.2f
#define NSUB      256                      // sub-buckets over dst space
#define SUB_NODES 196                      // nodes per sub
#define SUB_CAP   8192                     // per-sub global capacity (mean 6250)
#define BUCKET_B  640
#define BCHUNK    2500                     // N_EDGES / BUCKET_B
#define SB_CAP2   17                       // LDS cap/sub (19.5KB -> 8 blocks/CU)
#define EMB_B     ((N_NODES + 15) / 16)    // 3125 embed blocks (4 nodes/wave)
#define AGG_B     (N_NODES / 4)            // agg blocks (1 dst/wave)

// ---- monotone float<->uint encoding for atomicMax on floats ----
__device__ __forceinline__ unsigned fenc(float f) {
    unsigned u = __float_as_uint(f);
    return (u & 0x80000000u) ? ~u : (u | 0x80000000u);
}
__device__ __forceinline__ float fdec(unsigned k) {
    unsigned u = (k & 0x80000000u) ? (k & 0x7FFFFFFFu) : ~k;
    return __uint_as_float(u);
}
__device__ __forceinline__ float lrelu(float e) {
    return (e >= 0.f) ? e : NEG_SLOPE * e;
}
__device__ __forceinline__ int rli(int v, int l) {
    return __builtin_amdgcn_readlane(v, l);
}
__device__ __forceinline__ float rlf(float v, int l) {
    return __int_as_float(__builtin_amdgcn_readlane(__float_as_int(v), l));
}
// ---- fp16-pair pack + v_dot2_f32_f16 (fp16 mul, fp32 accumulate) ----
typedef _Float16 h2v __attribute__((ext_vector_type(2)));
__device__ __forceinline__ unsigned pkh2(float a, float b) {
    h2v v; v.x = (_Float16)a; v.y = (_Float16)b;
    return __builtin_bit_cast(unsigned, v);
}
__device__ __forceinline__ float fdot2u(unsigned a, unsigned b, float c) {
    return __builtin_amdgcn_fdot2(__builtin_bit_cast(h2v, a),
                                  __builtin_bit_cast(h2v, b), c, false);
}
// ---- packed edge record: low32 = src, high32 = el bits ----
__device__ __forceinline__ unsigned long long pke(int src, float el) {
    return ((unsigned long long)(unsigned)__float_as_int(el) << 32) |
           (unsigned long long)(unsigned)src;
}

// ---- fold: W2C1=w2@c1w; pack nw1, w2c1, c2w; init g_enc + sub_tail ----
__global__ __launch_bounds__(256) void fold_w(
    const float* __restrict__ nw1,
    const float* __restrict__ w2, const float* __restrict__ b2,
    const float* __restrict__ c1w, const float* __restrict__ c2w,
    unsigned* __restrict__ nw1_pk, unsigned* __restrict__ w2c1_pk,
    unsigned* __restrict__ c2w_pk,
    float* __restrict__ b2c1, unsigned* __restrict__ g_enc,
    unsigned* __restrict__ sub_tail)
{
    __shared__ float c1s[4096];
    __shared__ float w2c1s[4096];
    int tid = threadIdx.x;
    for (int i = tid; i < 4096; i += 256) c1s[i] = c1w[i];
    for (int i = tid; i < N_GRAPHS * HIDDEN; i += 256) g_enc[i] = fenc(-INFINITY);
    sub_tail[tid] = 0u;
    __syncthreads();
    int j = tid & 63, i0 = tid >> 6;
    for (int ii = 0; ii < 16; ++ii) {
        int i = i0 * 16 + ii;
        float a = 0.f;
#pragma unroll 8
        for (int k = 0; k < 64; ++k) a = fmaf(w2[i * 64 + k], c1s[k * 64 + j], a);
        w2c1s[i * 64 + j] = a;
    }
    if (tid < 64) {
        float a = 0.f;
#pragma unroll 8
        for (int k = 0; k < 64; ++k) a = fmaf(b2[k], c1s[k * 64 + tid], a);
        b2c1[tid] = a;
    }
    __syncthreads();
    for (int idx = tid; idx < 64 * 64; idx += 256) {
        int kk = idx >> 6, jj = idx & 63;
        nw1_pk[idx] = pkh2(nw1[(2 * kk) * 64 + jj], nw1[(2 * kk + 1) * 64 + jj]);
    }
    for (int idx = tid; idx < 32 * 64; idx += 256) {
        int kk = idx >> 6, jj = idx & 63;
        w2c1_pk[idx] = pkh2(w2c1s[(2 * kk) * 64 + jj], w2c1s[(2 * kk + 1) * 64 + jj]);
        c2w_pk[idx]  = pkh2(c2w[(2 * kk) * 64 + jj],  c2w[(2 * kk + 1) * 64 + jj]);
    }
}

// ---- FUSED: bucket blocks [0,BUCKET_B) + embed blocks [BUCKET_B, +EMB_B) ----
// embed: 4 nodes/wave (fine granularity -> 3765 blocks, good CU backfill)
__global__ __launch_bounds__(256) void embed_bucket(
    const float* __restrict__ x,
    const unsigned* __restrict__ nw1_pk, const float* __restrict__ n_b1,
    const unsigned* __restrict__ w2c1_pk, const float* __restrict__ b2c1,
    const float* __restrict__ a1s, const float* __restrict__ a1d,
    __half* __restrict__ hlin,
    float* __restrict__ asrc, float* __restrict__ adst,
    float* __restrict__ blkmax,
    const int* __restrict__ ei,
    unsigned* __restrict__ sub_tail, unsigned* __restrict__ sub_buf)
{
    __shared__ unsigned st[NSUB][SB_CAP2];    // 17.4 KB, odd stride: conflict-free
    __shared__ unsigned scnt[NSUB];
    __shared__ unsigned sbase[NSUB];
    __shared__ float wred[4];
    int tid = threadIdx.x;
    int lane = tid & 63, wid = tid >> 6;

    if (blockIdx.x < BUCKET_B) {
        // ---------- bucket path ----------
        scnt[tid] = 0u;
        __syncthreads();
        int beg = blockIdx.x * BCHUNK;
        int end = min(beg + BCHUNK, N_EDGES);
        for (int base = beg; base < end; base += 256) {
            int e = base + tid;
            if (e < end) {
                unsigned src = (unsigned)__builtin_nontemporal_load(ei + e);
                unsigned dst = (unsigned)__builtin_nontemporal_load(ei + N_EDGES + e);
                unsigned sub = dst / SUB_NODES;
                unsigned pay = ((dst - sub * SUB_NODES) << 16) | src;
                unsigned p = atomicAdd(&scnt[sub], 1u);
                if (p < SB_CAP2) st[sub][p] = pay;
                else {                           // ~1% overflow: direct write
                    unsigned gp = atomicAdd(&sub_tail[sub], 1u);
                    if (gp < SUB_CAP)
                        __builtin_nontemporal_store(pay, sub_buf + (size_t)sub * SUB_CAP + gp);
                }
            }
        }
        __syncthreads();
        unsigned c = min(scnt[tid], (unsigned)SB_CAP2);
        scnt[tid] = c;
        sbase[tid] = atomicAdd(&sub_tail[tid], c);
        __syncthreads();
        // wave-coalesced flush: wave handles subs wid, wid+4, ...; lanes 0..c-1
        for (int o = wid; o < NSUB; o += 4) {
            unsigned c_o = scnt[o];
            if ((unsigned)lane < c_o) {
                unsigned pos = sbase[o] + lane;
                if (pos < SUB_CAP)
                    __builtin_nontemporal_store(st[o][lane],
                        sub_buf + (size_t)o * SUB_CAP + pos);
            }
        }
    } else {
        // ---------- embed path: MLP + folded linear via packed dot2 ----------
        int eb = blockIdx.x - BUCKET_B;
        int n0 = eb * 16 + wid * 4;          // 4 nodes per wave (exact: 50000%16==0)
        if (n0 < N_NODES) {
            unsigned xpk[4];
#pragma unroll
            for (int nn = 0; nn < 4; ++nn) {
                float2 v = ((const float2*)(x + (size_t)(n0 + nn) * N_FEAT))[lane];
                xpk[nn] = pkh2(v.x, v.y);
            }
            float acc[4];
            float b1v = n_b1[lane];
#pragma unroll
            for (int nn = 0; nn < 4; ++nn) acc[nn] = b1v;
#pragma unroll 4
            for (int kk = 0; kk < 64; ++kk) {
                unsigned wp = nw1_pk[kk * 64 + lane];
#pragma unroll
                for (int nn = 0; nn < 4; ++nn)
                    acc[nn] = fdot2u((unsigned)rli((int)xpk[nn], kk), wp, acc[nn]);
            }
#pragma unroll
            for (int nn = 0; nn < 4; ++nn) acc[nn] = fmaxf(acc[nn], 0.f);
            unsigned hpk[4];
#pragma unroll
            for (int nn = 0; nn < 4; ++nn) {
                float ha = __shfl(acc[nn], (2 * lane) & 63, 64);
                float hb = __shfl(acc[nn], (2 * lane + 1) & 63, 64);
                hpk[nn] = pkh2(ha, hb);
            }
            float hl[4];
            float bcv = b2c1[lane];
#pragma unroll
            for (int nn = 0; nn < 4; ++nn) hl[nn] = bcv;
#pragma unroll 4
            for (int kk = 0; kk < 32; ++kk) {
                unsigned wp = w2c1_pk[kk * 64 + lane];
#pragma unroll
                for (int nn = 0; nn < 4; ++nn)
                    hl[nn] = fdot2u((unsigned)rli((int)hpk[nn], kk), wp, hl[nn]);
            }
            float s1v = a1s[lane], d1v = a1d[lane];
            float wmax = -INFINITY;
#pragma unroll
            for (int nn = 0; nn < 4; ++nn) {
                int n = n0 + nn;
                hlin[(size_t)n * 64 + lane] = __float2half(hl[nn]);
                float ps = hl[nn] * s1v, pd = hl[nn] * d1v;
#pragma unroll
                for (int off = 32; off; off >>= 1) {
                    ps += __shfl_xor(ps, off, 64);
                    pd += __shfl_xor(pd, off, 64);
                }
                if (lane == 0) { asrc[n] = ps; adst[n] = pd; wmax = fmaxf(wmax, ps); }
            }
            if (lane == 0) wred[wid] = wmax;
        } else if (lane == 0) wred[wid] = -INFINITY;
        __syncthreads();
        if (tid == 0)
            blkmax[eb] = fmaxf(fmaxf(wred[0], wred[1]), fmaxf(wred[2], wred[3]));
    }
}

// ---- CSR build (256 per-sub blocks, zero global atomics) -> epk + As1 ----
__global__ __launch_bounds__(256) void csr_as1(
    const unsigned* __restrict__ sub_buf, const unsigned* __restrict__ sub_tail,
    const float* __restrict__ asrc1, const float* __restrict__ adst1,
    unsigned* __restrict__ row_ptr, unsigned long long* __restrict__ epk,
    const float* __restrict__ blkmax1, float* __restrict__ As1)
{
    __shared__ unsigned hist[SUB_NODES];
    __shared__ unsigned wt4[4], wo4[4];
    __shared__ unsigned eb_s[2];
    __shared__ unsigned tot_s;
    int tid = threadIdx.x, lane = tid & 63, wid = tid >> 6;

    if (blockIdx.x == NSUB) {              // As1 reduction block
        float m = -INFINITY;
        for (int i = tid; i < EMB_B; i += 256) m = fmaxf(m, blkmax1[i]);
#pragma unroll
        for (int off = 32; off; off >>= 1) m = fmaxf(m, __shfl_xor(m, off, 64));
        float* sm = (float*)wt4;
        if (lane == 0) sm[wid] = m;
        __syncthreads();
        if (tid == 0)
            As1[0] = fmaxf(fmaxf(sm[0], sm[1]), fmaxf(sm[2], sm[3]));
        return;
    }
    int gs = blockIdx.x;                   // 0..255
    unsigned myc = min(sub_tail[tid], (unsigned)SUB_CAP);
    unsigned nn_t = (tid < NSUB - 1) ? SUB_NODES : (N_NODES - (NSUB - 1) * SUB_NODES);
    unsigned v = myc + nn_t;
    unsigned xs = v;
#pragma unroll
    for (int off = 1; off < 64; off <<= 1) {
        unsigned t = __shfl_up(xs, off, 64);
        if (lane >= off) xs += t;
    }
    if (lane == 63) wt4[wid] = xs;
    __syncthreads();
    if (tid == 0) {
        unsigned run = 0;
        for (int w = 0; w < 4; ++w) { wo4[w] = run; run += wt4[w]; }
        tot_s = run;
    }
    __syncthreads();
    unsigned excl = wo4[wid] + xs - v;
    if (tid == gs) { eb_s[0] = excl; eb_s[1] = myc; }
    if (gs == 0 && tid == 0) row_ptr[N_NODES] = tot_s;
    __syncthreads();
    unsigned ebase = eb_s[0], cnt = eb_s[1];
    int node_lo = gs * SUB_NODES;
    int nn = (gs < NSUB - 1) ? SUB_NODES : (N_NODES - (NSUB - 1) * SUB_NODES);
    for (int i = tid; i < nn; i += 256) hist[i] = 1u;
    __syncthreads();
    const unsigned* seg = sub_buf + (size_t)gs * SUB_CAP;
    for (unsigned i = tid; i < cnt; i += 256)
        atomicAdd(&hist[__builtin_nontemporal_load(seg + i) >> 16], 1u);
    __syncthreads();
    unsigned v2 = (tid < nn) ? hist[tid] : 0u;
    unsigned xs2 = v2;
#pragma unroll
    for (int off = 1; off < 64; off <<= 1) {
        unsigned t = __shfl_up(xs2, off, 64);
        if (lane >= off) xs2 += t;
    }
    __syncthreads();
    if (lane == 63) wt4[wid] = xs2;
    __syncthreads();
    if (tid == 0) {
        unsigned run = 0;
        for (int w = 0; w < 4; ++w) { wo4[w] = run; run += wt4[w]; }
    }
    __syncthreads();
    if (tid < nn) {
        unsigned ex2 = wo4[wid] + xs2 - v2;
        unsigned rp = ebase + ex2;
        int n = node_lo + tid;
        row_ptr[n] = rp;
        epk[rp] = pke(n, lrelu(asrc1[n] + adst1[n]));   // self-loop first slot
        hist[tid] = ex2 + 1u;
    }
    __syncthreads();
    // scatter + layer-1 edge logit packed with src
    for (unsigned i = tid; i < cnt; i += 256) {
        unsigned pay = __builtin_nontemporal_load(seg + i);
        unsigned dl = pay >> 16;
        int src = (int)(pay & 0xffffu);
        unsigned p = atomicAdd(&hist[dl], 1u);
        epk[ebase + p] = pke(src, lrelu(asrc1[src] + adst1[node_lo + (int)dl]));
    }
}

// ---- layer-2 edge logits (epk.el overwrite) + As2 reduce (extra block) ----
__global__ __launch_bounds__(256) void wfill2(
    const unsigned* __restrict__ row_ptr,
    const float* __restrict__ asrc2, const float* __restrict__ adst2,
    unsigned long long* __restrict__ epk,
    const float* __restrict__ blkmax2, float* __restrict__ As2)
{
    int lane = threadIdx.x & 63, w = threadIdx.x >> 6;
    if (blockIdx.x == AGG_B) {             // As2 reduction block
        __shared__ float sm[4];
        int tid = threadIdx.x;
        float m = -INFINITY;
        for (int i = tid; i < AGG_B; i += 256) m = fmaxf(m, blkmax2[i]);
#pragma unroll
        for (int off = 32; off; off >>= 1) m = fmaxf(m, __shfl_xor(m, off, 64));
        if (lane == 0) sm[w] = m;
        __syncthreads();
        if (tid == 0)
            As2[0] = fmaxf(fmaxf(sm[0], sm[1]), fmaxf(sm[2], sm[3]));
        return;
    }
    int d = blockIdx.x * 4 + w;
    int s0 = (int)row_ptr[d], s1 = (int)row_ptr[d + 1];
    float ad = adst2[d];
    for (int i = s0 + lane; i < s1; i += 64) {
        unsigned long long q = epk[i];
        int src = (int)(unsigned)(q & 0xffffffffu);
        epk[i] = pke(src, lrelu(asrc2[src] + ad));
    }
}

// ---- agg core: 8 lanes/edge, U=4 burst (32 edges, 4 rows in flight/lane) ----
__device__ __forceinline__ float agg8e(
    const __half* __restrict__ hmat,      // [N][64] fp16 (128B rows)
    const unsigned long long* __restrict__ epk,
    int s0, int s1, float C, int lane, float acc[8])
{
    int slot = lane >> 3;
    int fb = (lane & 7) << 3;
    float sden = 0.f;
#pragma unroll
    for (int j = 0; j < 8; ++j) acc[j] = 0.f;
    for (int base = s0; base < s1; base += 32) {
        int e0 = base + slot, e1 = e0 + 8, e2 = e0 + 16, e3 = e0 + 24;
        // phase 1: 4 independent packed-edge loads (NT: streamed once)
        unsigned long long q0 = (e0 < s1) ? __builtin_nontemporal_load(epk + e0) : 0ull;
        unsigned long long q1 = (e1 < s1) ? __builtin_nontemporal_load(epk + e1) : 0ull;
        unsigned long long q2 = (e2 < s1) ? __builtin_nontemporal_load(epk + e2) : 0ull;
        unsigned long long q3 = (e3 < s1) ? __builtin_nontemporal_load(epk + e3) : 0ull;
        int i0 = (int)(unsigned)q0, i1 = (int)(unsigned)q1;
        int i2 = (int)(unsigned)q2, i3 = (int)(unsigned)q3;
        float w0 = (e0 < s1) ? __expf(__int_as_float((int)(q0 >> 32)) - C) : 0.f;
        float w1 = (e1 < s1) ? __expf(__int_as_float((int)(q1 >> 32)) - C) : 0.f;
        float w2 = (e2 < s1) ? __expf(__int_as_float((int)(q2 >> 32)) - C) : 0.f;
        float w3 = (e3 < s1) ? __expf(__int_as_float((int)(q3 >> 32)) - C) : 0.f;
        sden += (w0 + w1) + (w2 + w3);
        // phase 2: 4 independent 16B row loads (cached; gather set stays in L2)
        float4 hv0 = *(const float4*)(hmat + (size_t)i0 * 64 + fb);
        float4 hv1 = *(const float4*)(hmat + (size_t)i1 * 64 + fb);
        float4 hv2 = *(const float4*)(hmat + (size_t)i2 * 64 + fb);
        float4 hv3 = *(const float4*)(hmat + (size_t)i3 * 64 + fb);
        // phase 3: accumulate
        float2 a, b, c, dd;
#define ACC8(HV, W) \
        a = __half22float2(__builtin_bit_cast(__half2, HV.x)); \
        b = __half22float2(__builtin_bit_cast(__half2, HV.y)); \
        c = __half22float2(__builtin_bit_cast(__half2, HV.z)); \
        dd = __half22float2(__builtin_bit_cast(__half2, HV.w)); \
        acc[0] = fmaf(W, a.x, acc[0]);  acc[1] = fmaf(W, a.y, acc[1]); \
        acc[2] = fmaf(W, b.x, acc[2]);  acc[3] = fmaf(W, b.y, acc[3]); \
        acc[4] = fmaf(W, c.x, acc[4]);  acc[5] = fmaf(W, c.y, acc[5]); \
        acc[6] = fmaf(W, dd.x, acc[6]); acc[7] = fmaf(W, dd.y, acc[7]);
        ACC8(hv0, w0)
        ACC8(hv1, w1)
        ACC8(hv2, w2)
        ACC8(hv3, w3)
#undef ACC8
    }
#pragma unroll
    for (int j = 0; j < 8; ++j) {
        acc[j] += __shfl_xor(acc[j], 8, 64);
        acc[j] += __shfl_xor(acc[j], 16, 64);
        acc[j] += __shfl_xor(acc[j], 32, 64);
    }
#pragma unroll
    for (int off = 32; off; off >>= 1) sden += __shfl_xor(sden, off, 64);
    return sden * 0.125f;
}

// ---- fused: GAT layer1 aggregate (+relu) + layer2 linear + alpha dots ----
__global__ __launch_bounds__(256) void agg1(
    const __half* __restrict__ hlin1,
    const float* __restrict__ adst,
    const unsigned* __restrict__ row_ptr,
    const unsigned long long* __restrict__ epk,
    const float* __restrict__ As1, const float* __restrict__ c1b,
    const unsigned* __restrict__ c2w_pk,
    const float* __restrict__ a2s, const float* __restrict__ a2d,
    __half* __restrict__ hlin2, float* __restrict__ asrc2, float* __restrict__ adst2,
    float* __restrict__ blkmax)
{
    __shared__ float vbuf[4][64];
    __shared__ float wred[4];
    int lane = threadIdx.x & 63, w = threadIdx.x >> 6;
    int d = blockIdx.x * 4 + w;
    int s0 = (int)row_ptr[d], s1 = (int)row_ptr[d + 1];
    float C = lrelu(As1[0] + adst[d]);
    float acc[8];
    float den = agg8e(hlin1, epk, s0, s1, C, lane, acc);
    if ((lane >> 3) == 0) {               // slot-0 lanes hold all 64 features
        int fb = (lane & 7) << 3;
#pragma unroll
        for (int j = 0; j < 8; ++j) vbuf[w][fb + j] = acc[j];
    }
    __syncthreads();
    float inv = 1.f / (den + 1e-30f);
    int l2 = (2 * lane) & 63;
    float va = fmaxf(vbuf[w][l2] * inv + c1b[l2], 0.f);
    float vb = fmaxf(vbuf[w][l2 + 1] * inv + c1b[l2 + 1], 0.f);
    unsigned vpk = pkh2(va, vb);
    float hl = 0.f;
#pragma unroll 8
    for (int kk = 0; kk < 32; ++kk)
        hl = fdot2u((unsigned)rli((int)vpk, kk), c2w_pk[kk * 64 + lane], hl);
    hlin2[(size_t)d * 64 + lane] = __float2half(hl);
    float ps = hl * a2s[lane], pd = hl * a2d[lane];
#pragma unroll
    for (int off = 32; off; off >>= 1) {
        ps += __shfl_xor(ps, off, 64);
        pd += __shfl_xor(pd, off, 64);
    }
    if (lane == 0) { asrc2[d] = ps; adst2[d] = pd; wred[w] = ps; }
    __syncthreads();
    if (threadIdx.x == 0)
        blkmax[blockIdx.x] = fmaxf(fmaxf(wred[0], wred[1]), fmaxf(wred[2], wred[3]));
}

// ---- fused: GAT layer2 aggregate + bias + global max pool ----
__global__ __launch_bounds__(256) void agg2_pool(
    const __half* __restrict__ hlin2,
    const float* __restrict__ adst2,
    const unsigned* __restrict__ row_ptr,
    const unsigned long long* __restrict__ epk,
    const float* __restrict__ As2, const float* __restrict__ c2b,
    const int* __restrict__ batch, unsigned* __restrict__ g_enc)
{
    __shared__ float vbuf[4][64];
    int lane = threadIdx.x & 63, w = threadIdx.x >> 6;
    int d = blockIdx.x * 4 + w;
    int s0 = (int)row_ptr[d], s1 = (int)row_ptr[d + 1];
    float C = lrelu(As2[0] + adst2[d]);
    float acc[8];
    float den = agg8e(hlin2, epk, s0, s1, C, lane, acc);
    if ((lane >> 3) == 0) {
        int fb = (lane & 7) << 3;
#pragma unroll
        for (int j = 0; j < 8; ++j) vbuf[w][fb + j] = acc[j];
    }
    __syncthreads();
    float v = vbuf[w][lane] / (den + 1e-30f) + c2b[lane];   // no relu
    atomicMax(&g_enc[batch[d] * 64 + lane], fenc(v));
}

// ---- readout MLP: wave per graph ----
__global__ __launch_bounds__(256) void readout(
    const unsigned* __restrict__ g_enc,
    const float* __restrict__ fc1w, const float* __restrict__ fc1b,
    const float* __restrict__ fc2w, const float* __restrict__ fc2b,
    float* __restrict__ out)
{
    int lane = threadIdx.x & 63;
    int gi = blockIdx.x * 4 + (threadIdx.x >> 6);
    float gv = fdec(g_enc[gi * 64 + lane]);
    float a = fc1b[lane];
#pragma unroll 8
    for (int k = 0; k < 64; ++k)
        a = fmaf(rlf(gv, k), fc1w[k * 64 + lane], a);
    a = fmaxf(a, 0.f) * fc2w[lane];
#pragma unroll
    for (int off = 32; off; off >>= 1) a += __shfl_xor(a, off, 64);
    if (lane == 0) out[gi] = a + fc2b[0];
}

extern "C" void kernel_launch(void* const* d_in, const int* in_sizes, int n_in,
                              void* d_out, int out_size, void* d_ws, size_t ws_size,
                              hipStream_t stream)
{
    const float* x      = (const float*)d_in[0];
    const int*   ei     = (const int*)d_in[1];
    // d_in[2] edge_attr: dead value in reference, never read
    const int*   batch  = (const int*)d_in[3];
    const float* n_w1   = (const float*)d_in[4];
    const float* n_b1   = (const float*)d_in[5];
    const float* n_w2   = (const float*)d_in[6];
    const float* n_b2   = (const float*)d_in[7];
    // d_in[8..11] edge MLP weights: dead
    const float* c1_w    = (const float*)d_in[12];
    const float* c1_asrc = (const float*)d_in[13];
    const float* c1_adst = (const float*)d_in[14];
    const float* c1_b    = (const float*)d_in[15];
    const float* c2_w    = (const float*)d_in[16];
    const float* c2_asrc = (const float*)d_in[17];
    const float* c2_adst = (const float*)d_in[18];
    const float* c2_b    = (const float*)d_in[19];
    const float* fc1_w   = (const float*)d_in[20];
    const float* fc1_b   = (const float*)d_in[21];
    const float* fc2_w   = (const float*)d_in[22];
    const float* fc2_b   = (const float*)d_in[23];
    float* out = (float*)d_out;

    // workspace carve (256B aligned)
    char* ws = (char*)d_ws;
    size_t off = 0;
    auto alloc = [&](size_t bytes) -> void* {
        off = (off + 255) & ~(size_t)255;
        void* p = ws + off;
        off += bytes;
        return p;
    };
    unsigned* sub_tail = (unsigned*)alloc(sizeof(unsigned) * NSUB);
    unsigned* sub_buf  = (unsigned*)alloc(sizeof(unsigned) * (size_t)NSUB * SUB_CAP);
    unsigned* row_ptr  = (unsigned*)alloc(sizeof(unsigned) * (N_NODES + 1));
    unsigned long long* epk =
        (unsigned long long*)alloc(sizeof(unsigned long long) * E_TOT);
    __half*   hlin1    = (__half*)alloc(sizeof(__half) * (size_t)N_NODES * 64);
    __half*   hlin2    = (__half*)alloc(sizeof(__half) * (size_t)N_NODES * 64);
    float*    asrc1    = (float*)alloc(sizeof(float) * N_NODES);
    float*    adst1    = (float*)alloc(sizeof(float) * N_NODES);
    float*    asrc2    = (float*)alloc(sizeof(float) * N_NODES);
    float*    adst2    = (float*)alloc(sizeof(float) * N_NODES);
    unsigned* g_enc    = (unsigned*)alloc(sizeof(unsigned) * N_GRAPHS * HIDDEN);
    unsigned* nw1_pk   = (unsigned*)alloc(sizeof(unsigned) * 64 * 64);
    unsigned* w2c1_pk  = (unsigned*)alloc(sizeof(unsigned) * 32 * 64);
    unsigned* c2w_pk   = (unsigned*)alloc(sizeof(unsigned) * 32 * 64);
    float*    b2c1     = (float*)alloc(sizeof(float) * 64);
    float*    blkmax1  = (float*)alloc(sizeof(float) * EMB_B);
    float*    blkmax2  = (float*)alloc(sizeof(float) * AGG_B);
    float*    As1      = (float*)alloc(sizeof(float) * 2);
    float*    As2      = (float*)alloc(sizeof(float) * 2);

    fold_w<<<1, 256, 0, stream>>>(n_w1, n_w2, n_b2, c1_w, c2_w,
                                  nw1_pk, w2c1_pk, c2w_pk, b2c1, g_enc, sub_tail);

    // bucket (640 blocks, overlaps embed) + embed (3125 blocks)
    embed_bucket<<<BUCKET_B + EMB_B, 256, 0, stream>>>(
        x, nw1_pk, n_b1, w2c1_pk, b2c1, c1_asrc, c1_adst,
        hlin1, asrc1, adst1, blkmax1,
        ei, sub_tail, sub_buf);

    // CSR build -> packed (src, el1) records + As1 reduce
    csr_as1<<<NSUB + 1, 256, 0, stream>>>(
        sub_buf, sub_tail, asrc1, adst1, row_ptr, epk, blkmax1, As1);

    agg1<<<AGG_B, 256, 0, stream>>>(
        hlin1, adst1, row_ptr, epk, As1,
        c1_b, c2w_pk, c2_asrc, c2_adst, hlin2, asrc2, adst2, blkmax2);

    // layer-2 edge logits (epk overwrite) + As2 reduce
    wfill2<<<AGG_B + 1, 256, 0, stream>>>(
        row_ptr, asrc2, adst2, epk, blkmax2, As2);

    agg2_pool<<<AGG_B, 256, 0, stream>>>(
        hlin2, adst2, row_ptr, epk, As2, c2_b, batch, g_enc);
    readout<<<N_GRAPHS / 4, 256, 0, stream>>>(g_enc, fc1_w, fc1_b, fc2_w, fc2_b, out);
}

// Round 22
// 225.019 us; speedup vs baseline: 1.1592x; 1.0845x over previous
//
#include <hip/hip_runtime.h>
#include <hip/hip_fp16.h>
#include <math.h>

#define N_NODES   50000
#define N_EDGES   1600000
#define E_TOT     (N_EDGES + N_NODES)
#define N_FEAT    128
#define HIDDEN    64
#define N_GRAPHS  128
#define NEG_SLOPE 0.2f
#define NSUB      256                      // sub-buckets over dst space
#define SUB_NODES 196                      // nodes per sub
#define SUB_CAP   8192                     // per-sub global capacity (mean 6250)
#define BUCKET_B  640
#define BCHUNK    2500                     // N_EDGES / BUCKET_B
#define SB_CAP2   17                       // LDS cap/sub (19.5KB -> 8 blocks/CU)
#define EMB_B     ((N_NODES + 15) / 16)    // 3125 embed blocks (4 nodes/wave)
#define AGG_B     (N_NODES / 4)            // agg blocks (1 dst/wave)

// ---- monotone float<->uint encoding for atomicMax on floats ----
__device__ __forceinline__ unsigned fenc(float f) {
    unsigned u = __float_as_uint(f);
    return (u & 0x80000000u) ? ~u : (u | 0x80000000u);
}
__device__ __forceinline__ float fdec(unsigned k) {
    unsigned u = (k & 0x80000000u) ? (k & 0x7FFFFFFFu) : ~k;
    return __uint_as_float(u);
}
__device__ __forceinline__ float lrelu(float e) {
    return (e >= 0.f) ? e : NEG_SLOPE * e;
}
__device__ __forceinline__ int rli(int v, int l) {
    return __builtin_amdgcn_readlane(v, l);
}
__device__ __forceinline__ float rlf(float v, int l) {
    return __int_as_float(__builtin_amdgcn_readlane(__float_as_int(v), l));
}
// ---- fp16-pair pack + v_dot2_f32_f16 (fp16 mul, fp32 accumulate) ----
typedef _Float16 h2v __attribute__((ext_vector_type(2)));
__device__ __forceinline__ unsigned pkh2(float a, float b) {
    h2v v; v.x = (_Float16)a; v.y = (_Float16)b;
    return __builtin_bit_cast(unsigned, v);
}
__device__ __forceinline__ float fdot2u(unsigned a, unsigned b, float c) {
    return __builtin_amdgcn_fdot2(__builtin_bit_cast(h2v, a),
                                  __builtin_bit_cast(h2v, b), c, false);
}
// ---- packed edge record: low32 = src, high32 = el bits ----
__device__ __forceinline__ unsigned long long pke(int src, float el) {
    return ((unsigned long long)(unsigned)__float_as_int(el) << 32) |
           (unsigned long long)(unsigned)src;
}

// ---- fold: W2C1=w2@c1w; pack nw1, w2c1, c2w; init g_enc + sub_tail ----
__global__ __launch_bounds__(256) void fold_w(
    const float* __restrict__ nw1,
    const float* __restrict__ w2, const float* __restrict__ b2,
    const float* __restrict__ c1w, const float* __restrict__ c2w,
    unsigned* __restrict__ nw1_pk, unsigned* __restrict__ w2c1_pk,
    unsigned* __restrict__ c2w_pk,
    float* __restrict__ b2c1, unsigned* __restrict__ g_enc,
    unsigned* __restrict__ sub_tail)
{
    __shared__ float c1s[4096];
    __shared__ float w2c1s[4096];
    int tid = threadIdx.x;
    for (int i = tid; i < 4096; i += 256) c1s[i] = c1w[i];
    for (int i = tid; i < N_GRAPHS * HIDDEN; i += 256) g_enc[i] = fenc(-INFINITY);
    sub_tail[tid] = 0u;
    __syncthreads();
    int j = tid & 63, i0 = tid >> 6;
    for (int ii = 0; ii < 16; ++ii) {
        int i = i0 * 16 + ii;
        float a = 0.f;
#pragma unroll 8
        for (int k = 0; k < 64; ++k) a = fmaf(w2[i * 64 + k], c1s[k * 64 + j], a);
        w2c1s[i * 64 + j] = a;
    }
    if (tid < 64) {
        float a = 0.f;
#pragma unroll 8
        for (int k = 0; k < 64; ++k) a = fmaf(b2[k], c1s[k * 64 + tid], a);
        b2c1[tid] = a;
    }
    __syncthreads();
    for (int idx = tid; idx < 64 * 64; idx += 256) {
        int kk = idx >> 6, jj = idx & 63;
        nw1_pk[idx] = pkh2(nw1[(2 * kk) * 64 + jj], nw1[(2 * kk + 1) * 64 + jj]);
    }
    for (int idx = tid; idx < 32 * 64; idx += 256) {
        int kk = idx >> 6, jj = idx & 63;
        w2c1_pk[idx] = pkh2(w2c1s[(2 * kk) * 64 + jj], w2c1s[(2 * kk + 1) * 64 + jj]);
        c2w_pk[idx]  = pkh2(c2w[(2 * kk) * 64 + jj],  c2w[(2 * kk + 1) * 64 + jj]);
    }
}

// ---- FUSED: bucket blocks [0,BUCKET_B) + embed blocks [BUCKET_B, +EMB_B) ----
__global__ __launch_bounds__(256) void embed_bucket(
    const float* __restrict__ x,
    const unsigned* __restrict__ nw1_pk, const float* __restrict__ n_b1,
    const unsigned* __restrict__ w2c1_pk, const float* __restrict__ b2c1,
    const float* __restrict__ a1s, const float* __restrict__ a1d,
    __half* __restrict__ hlin,
    float* __restrict__ asrc, float* __restrict__ adst,
    float* __restrict__ blkmax,
    const int* __restrict__ ei,
    unsigned* __restrict__ sub_tail, unsigned* __restrict__ sub_buf)
{
    __shared__ unsigned st[NSUB][SB_CAP2];    // 17.4 KB, odd stride: conflict-free
    __shared__ unsigned scnt[NSUB];
    __shared__ unsigned sbase[NSUB];
    __shared__ float wred[4];
    int tid = threadIdx.x;
    int lane = tid & 63, wid = tid >> 6;

    if (blockIdx.x < BUCKET_B) {
        // ---------- bucket path ----------
        scnt[tid] = 0u;
        __syncthreads();
        int beg = blockIdx.x * BCHUNK;
        int end = min(beg + BCHUNK, N_EDGES);
        for (int base = beg; base < end; base += 256) {
            int e = base + tid;
            if (e < end) {
                unsigned src = (unsigned)__builtin_nontemporal_load(ei + e);
                unsigned dst = (unsigned)__builtin_nontemporal_load(ei + N_EDGES + e);
                unsigned sub = dst / SUB_NODES;
                unsigned pay = ((dst - sub * SUB_NODES) << 16) | src;
                unsigned p = atomicAdd(&scnt[sub], 1u);
                if (p < SB_CAP2) st[sub][p] = pay;
                else {                           // ~1% overflow: direct write
                    unsigned gp = atomicAdd(&sub_tail[sub], 1u);
                    if (gp < SUB_CAP)
                        __builtin_nontemporal_store(pay, sub_buf + (size_t)sub * SUB_CAP + gp);
                }
            }
        }
        __syncthreads();
        unsigned c = min(scnt[tid], (unsigned)SB_CAP2);
        scnt[tid] = c;
        sbase[tid] = atomicAdd(&sub_tail[tid], c);
        __syncthreads();
        // wave-coalesced flush: wave handles subs wid, wid+4, ...; lanes 0..c-1
        for (int o = wid; o < NSUB; o += 4) {
            unsigned c_o = scnt[o];
            if ((unsigned)lane < c_o) {
                unsigned pos = sbase[o] + lane;
                if (pos < SUB_CAP)
                    __builtin_nontemporal_store(st[o][lane],
                        sub_buf + (size_t)o * SUB_CAP + pos);
            }
        }
    } else {
        // ---------- embed path: MLP + folded linear via packed dot2 ----------
        int eb = blockIdx.x - BUCKET_B;
        int n0 = eb * 16 + wid * 4;          // 4 nodes per wave
        if (n0 < N_NODES) {
            unsigned xpk[4];
#pragma unroll
            for (int nn = 0; nn < 4; ++nn) {
                float2 v = ((const float2*)(x + (size_t)(n0 + nn) * N_FEAT))[lane];
                xpk[nn] = pkh2(v.x, v.y);
            }
            float acc[4];
            float b1v = n_b1[lane];
#pragma unroll
            for (int nn = 0; nn < 4; ++nn) acc[nn] = b1v;
#pragma unroll 4
            for (int kk = 0; kk < 64; ++kk) {
                unsigned wp = nw1_pk[kk * 64 + lane];
#pragma unroll
                for (int nn = 0; nn < 4; ++nn)
                    acc[nn] = fdot2u((unsigned)rli((int)xpk[nn], kk), wp, acc[nn]);
            }
#pragma unroll
            for (int nn = 0; nn < 4; ++nn) acc[nn] = fmaxf(acc[nn], 0.f);
            unsigned hpk[4];
#pragma unroll
            for (int nn = 0; nn < 4; ++nn) {
                float ha = __shfl(acc[nn], (2 * lane) & 63, 64);
                float hb = __shfl(acc[nn], (2 * lane + 1) & 63, 64);
                hpk[nn] = pkh2(ha, hb);
            }
            float hl[4];
            float bcv = b2c1[lane];
#pragma unroll
            for (int nn = 0; nn < 4; ++nn) hl[nn] = bcv;
#pragma unroll 4
            for (int kk = 0; kk < 32; ++kk) {
                unsigned wp = w2c1_pk[kk * 64 + lane];
#pragma unroll
                for (int nn = 0; nn < 4; ++nn)
                    hl[nn] = fdot2u((unsigned)rli((int)hpk[nn], kk), wp, hl[nn]);
            }
            float s1v = a1s[lane], d1v = a1d[lane];
            float wmax = -INFINITY;
#pragma unroll
            for (int nn = 0; nn < 4; ++nn) {
                int n = n0 + nn;
                hlin[(size_t)n * 64 + lane] = __float2half(hl[nn]);
                float ps = hl[nn] * s1v, pd = hl[nn] * d1v;
#pragma unroll
                for (int off = 32; off; off >>= 1) {
                    ps += __shfl_xor(ps, off, 64);
                    pd += __shfl_xor(pd, off, 64);
                }
                if (lane == 0) { asrc[n] = ps; adst[n] = pd; wmax = fmaxf(wmax, ps); }
            }
            if (lane == 0) wred[wid] = wmax;
        } else if (lane == 0) wred[wid] = -INFINITY;
        __syncthreads();
        if (tid == 0)
            blkmax[eb] = fmaxf(fmaxf(wred[0], wred[1]), fmaxf(wred[2], wred[3]));
    }
}

// ---- CSR build (256 per-sub blocks, zero global atomics) -> epk + As1 ----
__global__ __launch_bounds__(256) void csr_as1(
    const unsigned* __restrict__ sub_buf, const unsigned* __restrict__ sub_tail,
    const float* __restrict__ asrc1, const float* __restrict__ adst1,
    unsigned* __restrict__ row_ptr, unsigned long long* __restrict__ epk,
    const float* __restrict__ blkmax1, float* __restrict__ As1)
{
    __shared__ unsigned hist[SUB_NODES];
    __shared__ unsigned wt4[4], wo4[4];
    __shared__ unsigned eb_s[2];
    __shared__ unsigned tot_s;
    int tid = threadIdx.x, lane = tid & 63, wid = tid >> 6;

    if (blockIdx.x == NSUB) {              // As1 reduction block
        float m = -INFINITY;
        for (int i = tid; i < EMB_B; i += 256) m = fmaxf(m, blkmax1[i]);
#pragma unroll
        for (int off = 32; off; off >>= 1) m = fmaxf(m, __shfl_xor(m, off, 64));
        float* sm = (float*)wt4;
        if (lane == 0) sm[wid] = m;
        __syncthreads();
        if (tid == 0)
            As1[0] = fmaxf(fmaxf(sm[0], sm[1]), fmaxf(sm[2], sm[3]));
        return;
    }
    int gs = blockIdx.x;                   // 0..255
    unsigned myc = min(sub_tail[tid], (unsigned)SUB_CAP);
    unsigned nn_t = (tid < NSUB - 1) ? SUB_NODES : (N_NODES - (NSUB - 1) * SUB_NODES);
    unsigned v = myc + nn_t;
    unsigned xs = v;
#pragma unroll
    for (int off = 1; off < 64; off <<= 1) {
        unsigned t = __shfl_up(xs, off, 64);
        if (lane >= off) xs += t;
    }
    if (lane == 63) wt4[wid] = xs;
    __syncthreads();
    if (tid == 0) {
        unsigned run = 0;
        for (int w = 0; w < 4; ++w) { wo4[w] = run; run += wt4[w]; }
        tot_s = run;
    }
    __syncthreads();
    unsigned excl = wo4[wid] + xs - v;
    if (tid == gs) { eb_s[0] = excl; eb_s[1] = myc; }
    if (gs == 0 && tid == 0) row_ptr[N_NODES] = tot_s;
    __syncthreads();
    unsigned ebase = eb_s[0], cnt = eb_s[1];
    int node_lo = gs * SUB_NODES;
    int nn = (gs < NSUB - 1) ? SUB_NODES : (N_NODES - (NSUB - 1) * SUB_NODES);
    for (int i = tid; i < nn; i += 256) hist[i] = 1u;
    __syncthreads();
    const unsigned* seg = sub_buf + (size_t)gs * SUB_CAP;
    for (unsigned i = tid; i < cnt; i += 256)
        atomicAdd(&hist[__builtin_nontemporal_load(seg + i) >> 16], 1u);
    __syncthreads();
    unsigned v2 = (tid < nn) ? hist[tid] : 0u;
    unsigned xs2 = v2;
#pragma unroll
    for (int off = 1; off < 64; off <<= 1) {
        unsigned t = __shfl_up(xs2, off, 64);
        if (lane >= off) xs2 += t;
    }
    __syncthreads();
    if (lane == 63) wt4[wid] = xs2;
    __syncthreads();
    if (tid == 0) {
        unsigned run = 0;
        for (int w = 0; w < 4; ++w) { wo4[w] = run; run += wt4[w]; }
    }
    __syncthreads();
    if (tid < nn) {
        unsigned ex2 = wo4[wid] + xs2 - v2;
        unsigned rp = ebase + ex2;
        int n = node_lo + tid;
        row_ptr[n] = rp;
        epk[rp] = pke(n, lrelu(asrc1[n] + adst1[n]));   // self-loop first slot
        hist[tid] = ex2 + 1u;
    }
    __syncthreads();
    // scatter + layer-1 edge logit packed with src
    for (unsigned i = tid; i < cnt; i += 256) {
        unsigned pay = __builtin_nontemporal_load(seg + i);
        unsigned dl = pay >> 16;
        int src = (int)(pay & 0xffffu);
        unsigned p = atomicAdd(&hist[dl], 1u);
        epk[ebase + p] = pke(src, lrelu(asrc1[src] + adst1[node_lo + (int)dl]));
    }
}

// ---- layer-2 edge logits (epk.el overwrite) + As2 reduce (extra block) ----
__global__ __launch_bounds__(256) void wfill2(
    const unsigned* __restrict__ row_ptr,
    const float* __restrict__ asrc2, const float* __restrict__ adst2,
    unsigned long long* __restrict__ epk,
    const float* __restrict__ blkmax2, float* __restrict__ As2)
{
    int lane = threadIdx.x & 63, w = threadIdx.x >> 6;
    if (blockIdx.x == AGG_B) {             // As2 reduction block
        __shared__ float sm[4];
        int tid = threadIdx.x;
        float m = -INFINITY;
        for (int i = tid; i < AGG_B; i += 256) m = fmaxf(m, blkmax2[i]);
#pragma unroll
        for (int off = 32; off; off >>= 1) m = fmaxf(m, __shfl_xor(m, off, 64));
        if (lane == 0) sm[w] = m;
        __syncthreads();
        if (tid == 0)
            As2[0] = fmaxf(fmaxf(sm[0], sm[1]), fmaxf(sm[2], sm[3]));
        return;
    }
    int d = blockIdx.x * 4 + w;
    int s0 = (int)row_ptr[d], s1 = (int)row_ptr[d + 1];
    float ad = adst2[d];
    for (int i = s0 + lane; i < s1; i += 64) {
        unsigned long long q = epk[i];
        int src = (int)(unsigned)(q & 0xffffffffu);
        epk[i] = pke(src, lrelu(asrc2[src] + ad));
    }
}

// ---- agg core: 8 lanes/edge, U=4 burst (32 edges, 4 rows in flight/lane) ----
__device__ __forceinline__ float agg8e(
    const __half* __restrict__ hmat,      // [N][64] fp16 (128B rows)
    const unsigned long long* __restrict__ epk,
    int s0, int s1, float C, int lane, float acc[8])
{
    int slot = lane >> 3;
    int fb = (lane & 7) << 3;
    float sden = 0.f;
#pragma unroll
    for (int j = 0; j < 8; ++j) acc[j] = 0.f;
    for (int base = s0; base < s1; base += 32) {
        int e0 = base + slot, e1 = e0 + 8, e2 = e0 + 16, e3 = e0 + 24;
        unsigned long long q0 = (e0 < s1) ? __builtin_nontemporal_load(epk + e0) : 0ull;
        unsigned long long q1 = (e1 < s1) ? __builtin_nontemporal_load(epk + e1) : 0ull;
        unsigned long long q2 = (e2 < s1) ? __builtin_nontemporal_load(epk + e2) : 0ull;
        unsigned long long q3 = (e3 < s1) ? __builtin_nontemporal_load(epk + e3) : 0ull;
        int i0 = (int)(unsigned)q0, i1 = (int)(unsigned)q1;
        int i2 = (int)(unsigned)q2, i3 = (int)(unsigned)q3;
        float w0 = (e0 < s1) ? __expf(__int_as_float((int)(q0 >> 32)) - C) : 0.f;
        float w1 = (e1 < s1) ? __expf(__int_as_float((int)(q1 >> 32)) - C) : 0.f;
        float w2 = (e2 < s1) ? __expf(__int_as_float((int)(q2 >> 32)) - C) : 0.f;
        float w3 = (e3 < s1) ? __expf(__int_as_float((int)(q3 >> 32)) - C) : 0.f;
        sden += (w0 + w1) + (w2 + w3);
        float4 hv0 = *(const float4*)(hmat + (size_t)i0 * 64 + fb);
        float4 hv1 = *(const float4*)(hmat + (size_t)i1 * 64 + fb);
        float4 hv2 = *(const float4*)(hmat + (size_t)i2 * 64 + fb);
        float4 hv3 = *(const float4*)(hmat + (size_t)i3 * 64 + fb);
        float2 a, b, c, dd;
#define ACC8(HV, W) \
        a = __half22float2(__builtin_bit_cast(__half2, HV.x)); \
        b = __half22float2(__builtin_bit_cast(__half2, HV.y)); \
        c = __half22float2(__builtin_bit_cast(__half2, HV.z)); \
        dd = __half22float2(__builtin_bit_cast(__half2, HV.w)); \
        acc[0] = fmaf(W, a.x, acc[0]);  acc[1] = fmaf(W, a.y, acc[1]); \
        acc[2] = fmaf(W, b.x, acc[2]);  acc[3] = fmaf(W, b.y, acc[3]); \
        acc[4] = fmaf(W, c.x, acc[4]);  acc[5] = fmaf(W, c.y, acc[5]); \
        acc[6] = fmaf(W, dd.x, acc[6]); acc[7] = fmaf(W, dd.y, acc[7]);
        ACC8(hv0, w0)
        ACC8(hv1, w1)
        ACC8(hv2, w2)
        ACC8(hv3, w3)
#undef ACC8
    }
#pragma unroll
    for (int j = 0; j < 8; ++j) {
        acc[j] += __shfl_xor(acc[j], 8, 64);
        acc[j] += __shfl_xor(acc[j], 16, 64);
        acc[j] += __shfl_xor(acc[j], 32, 64);
    }
#pragma unroll
    for (int off = 32; off; off >>= 1) sden += __shfl_xor(sden, off, 64);
    return sden * 0.125f;
}

// ---- fused: GAT layer1 aggregate (+relu) + layer2 linear + alpha dots ----
__global__ __launch_bounds__(256) void agg1(
    const __half* __restrict__ hlin1,
    const float* __restrict__ adst,
    const unsigned* __restrict__ row_ptr,
    const unsigned long long* __restrict__ epk,
    const float* __restrict__ As1, const float* __restrict__ c1b,
    const unsigned* __restrict__ c2w_pk,
    const float* __restrict__ a2s, const float* __restrict__ a2d,
    __half* __restrict__ hlin2, float* __restrict__ asrc2, float* __restrict__ adst2,
    float* __restrict__ blkmax)
{
    __shared__ float vbuf[4][64];
    __shared__ float wred[4];
    int lane = threadIdx.x & 63, w = threadIdx.x >> 6;
    int d = blockIdx.x * 4 + w;
    int s0 = (int)row_ptr[d], s1 = (int)row_ptr[d + 1];
    float C = lrelu(As1[0] + adst[d]);
    float acc[8];
    float den = agg8e(hlin1, epk, s0, s1, C, lane, acc);
    if ((lane >> 3) == 0) {               // slot-0 lanes hold all 64 features
        int fb = (lane & 7) << 3;
#pragma unroll
        for (int j = 0; j < 8; ++j) vbuf[w][fb + j] = acc[j];
    }
    __syncthreads();
    float inv = 1.f / (den + 1e-30f);
    int l2 = (2 * lane) & 63;
    float va = fmaxf(vbuf[w][l2] * inv + c1b[l2], 0.f);
    float vb = fmaxf(vbuf[w][l2 + 1] * inv + c1b[l2 + 1], 0.f);
    unsigned vpk = pkh2(va, vb);
    float hl = 0.f;
#pragma unroll 8
    for (int kk = 0; kk < 32; ++kk)
        hl = fdot2u((unsigned)rli((int)vpk, kk), c2w_pk[kk * 64 + lane], hl);
    hlin2[(size_t)d * 64 + lane] = __float2half(hl);
    float ps = hl * a2s[lane], pd = hl * a2d[lane];
#pragma unroll
    for (int off = 32; off; off >>= 1) {
        ps += __shfl_xor(ps, off, 64);
        pd += __shfl_xor(pd, off, 64);
    }
    if (lane == 0) { asrc2[d] = ps; adst2[d] = pd; wred[w] = ps; }
    __syncthreads();
    if (threadIdx.x == 0)
        blkmax[blockIdx.x] = fmaxf(fmaxf(wred[0], wred[1]), fmaxf(wred[2], wred[3]));
}

// ---- fused: GAT layer2 aggregate + bias + pool (block-level pre-reduce) ----
__global__ __launch_bounds__(256) void agg2_pool(
    const __half* __restrict__ hlin2,
    const float* __restrict__ adst2,
    const unsigned* __restrict__ row_ptr,
    const unsigned long long* __restrict__ epk,
    const float* __restrict__ As2, const float* __restrict__ c2b,
    const int* __restrict__ batch, unsigned* __restrict__ g_enc)
{
    __shared__ float vbuf[4][64];
    __shared__ int sbat[4];
    int lane = threadIdx.x & 63, w = threadIdx.x >> 6;
    int d = blockIdx.x * 4 + w;
    int s0 = (int)row_ptr[d], s1 = (int)row_ptr[d + 1];
    float C = lrelu(As2[0] + adst2[d]);
    float acc[8];
    float den = agg8e(hlin2, epk, s0, s1, C, lane, acc);
    if ((lane >> 3) == 0) {
        int fb = (lane & 7) << 3;
#pragma unroll
        for (int j = 0; j < 8; ++j) vbuf[w][fb + j] = acc[j];
    }
    __syncthreads();
    float v = vbuf[w][lane] / (den + 1e-30f) + c2b[lane];   // no relu
    vbuf[w][lane] = v;                     // own slot: race-free write-back
    if (lane == 0) sbat[w] = batch[d];
    __syncthreads();
    int b0 = sbat[0];
    bool same = (sbat[1] == b0) & (sbat[2] == b0) & (sbat[3] == b0);
    if (same) {
        // common case (batch sorted): 64 atomics per block instead of 256
        if (w == 0) {
            float m = fmaxf(fmaxf(vbuf[0][lane], vbuf[1][lane]),
                            fmaxf(vbuf[2][lane], vbuf[3][lane]));
            atomicMax(&g_enc[b0 * 64 + lane], fenc(m));
        }
    } else {
        atomicMax(&g_enc[sbat[w] * 64 + lane], fenc(v));
    }
}

// ---- readout MLP: wave per graph ----
__global__ __launch_bounds__(256) void readout(
    const unsigned* __restrict__ g_enc,
    const float* __restrict__ fc1w, const float* __restrict__ fc1b,
    const float* __restrict__ fc2w, const float* __restrict__ fc2b,
    float* __restrict__ out)
{
    int lane = threadIdx.x & 63;
    int gi = blockIdx.x * 4 + (threadIdx.x >> 6);
    float gv = fdec(g_enc[gi * 64 + lane]);
    float a = fc1b[lane];
#pragma unroll 8
    for (int k = 0; k < 64; ++k)
        a = fmaf(rlf(gv, k), fc1w[k * 64 + lane], a);
    a = fmaxf(a, 0.f) * fc2w[lane];
#pragma unroll
    for (int off = 32; off; off >>= 1) a += __shfl_xor(a, off, 64);
    if (lane == 0) out[gi] = a + fc2b[0];
}

extern "C" void kernel_launch(void* const* d_in, const int* in_sizes, int n_in,
                              void* d_out, int out_size, void* d_ws, size_t ws_size,
                              hipStream_t stream)
{
    const float* x      = (const float*)d_in[0];
    const int*   ei     = (const int*)d_in[1];
    // d_in[2] edge_attr: dead value in reference, never read
    const int*   batch  = (const int*)d_in[3];
    const float* n_w1   = (const float*)d_in[4];
    const float* n_b1   = (const float*)d_in[5];
    const float* n_w2   = (const float*)d_in[6];
    const float* n_b2   = (const float*)d_in[7];
    // d_in[8..11] edge MLP weights: dead
    const float* c1_w    = (const float*)d_in[12];
    const float* c1_asrc = (const float*)d_in[13];
    const float* c1_adst = (const float*)d_in[14];
    const float* c1_b    = (const float*)d_in[15];
    const float* c2_w    = (const float*)d_in[16];
    const float* c2_asrc = (const float*)d_in[17];
    const float* c2_adst = (const float*)d_in[18];
    const float* c2_b    = (const float*)d_in[19];
    const float* fc1_w   = (const float*)d_in[20];
    const float* fc1_b   = (const float*)d_in[21];
    const float* fc2_w   = (const float*)d_in[22];
    const float* fc2_b   = (const float*)d_in[23];
    float* out = (float*)d_out;

    // workspace carve (256B aligned)
    char* ws = (char*)d_ws;
    size_t off = 0;
    auto alloc = [&](size_t bytes) -> void* {
        off = (off + 255) & ~(size_t)255;
        void* p = ws + off;
        off += bytes;
        return p;
    };
    unsigned* sub_tail = (unsigned*)alloc(sizeof(unsigned) * NSUB);
    unsigned* sub_buf  = (unsigned*)alloc(sizeof(unsigned) * (size_t)NSUB * SUB_CAP);
    unsigned* row_ptr  = (unsigned*)alloc(sizeof(unsigned) * (N_NODES + 1));
    unsigned long long* epk =
        (unsigned long long*)alloc(sizeof(unsigned long long) * E_TOT);
    __half*   hlin1    = (__half*)alloc(sizeof(__half) * (size_t)N_NODES * 64);
    __half*   hlin2    = (__half*)alloc(sizeof(__half) * (size_t)N_NODES * 64);
    float*    asrc1    = (float*)alloc(sizeof(float) * N_NODES);
    float*    adst1    = (float*)alloc(sizeof(float) * N_NODES);
    float*    asrc2    = (float*)alloc(sizeof(float) * N_NODES);
    float*    adst2    = (float*)alloc(sizeof(float) * N_NODES);
    unsigned* g_enc    = (unsigned*)alloc(sizeof(unsigned) * N_GRAPHS * HIDDEN);
    unsigned* nw1_pk   = (unsigned*)alloc(sizeof(unsigned) * 64 * 64);
    unsigned* w2c1_pk  = (unsigned*)alloc(sizeof(unsigned) * 32 * 64);
    unsigned* c2w_pk   = (unsigned*)alloc(sizeof(unsigned) * 32 * 64);
    float*    b2c1     = (float*)alloc(sizeof(float) * 64);
    float*    blkmax1  = (float*)alloc(sizeof(float) * EMB_B);
    float*    blkmax2  = (float*)alloc(sizeof(float) * AGG_B);
    float*    As1      = (float*)alloc(sizeof(float) * 2);
    float*    As2      = (float*)alloc(sizeof(float) * 2);

    fold_w<<<1, 256, 0, stream>>>(n_w1, n_w2, n_b2, c1_w, c2_w,
                                  nw1_pk, w2c1_pk, c2w_pk, b2c1, g_enc, sub_tail);

    // bucket (640 blocks, overlaps embed) + embed (3125 blocks)
    embed_bucket<<<BUCKET_B + EMB_B, 256, 0, stream>>>(
        x, nw1_pk, n_b1, w2c1_pk, b2c1, c1_asrc, c1_adst,
        hlin1, asrc1, adst1, blkmax1,
        ei, sub_tail, sub_buf);

    // CSR build -> packed (src, el1) records + As1 reduce
    csr_as1<<<NSUB + 1, 256, 0, stream>>>(
        sub_buf, sub_tail, asrc1, adst1, row_ptr, epk, blkmax1, As1);

    agg1<<<AGG_B, 256, 0, stream>>>(
        hlin1, adst1, row_ptr, epk, As1,
        c1_b, c2w_pk, c2_asrc, c2_adst, hlin2, asrc2, adst2, blkmax2);

    // layer-2 edge logits (epk overwrite) + As2 reduce
    wfill2<<<AGG_B + 1, 256, 0, stream>>>(
        row_ptr, asrc2, adst2, epk, blkmax2, As2);

    agg2_pool<<<AGG_B, 256, 0, stream>>>(
        hlin2, adst2, row_ptr, epk, As2, c2_b, batch, g_enc);
    readout<<<N_GRAPHS / 4, 256, 0, stream>>>(g_enc, fc1_w, fc1_b, fc2_w, fc2_b, out);
}

// Round 23
// 223.144 us; speedup vs baseline: 1.1689x; 1.0084x over previous
//
#include <hip/hip_runtime.h>
#include <hip/hip_fp16.h>
#include <math.h>

#define N_NODES   50000
#define N_EDGES   1600000
#define E_TOT     (N_EDGES + N_NODES)
#define N_FEAT    128
#define HIDDEN    64
#define N_GRAPHS  128
#define NEG_SLOPE 0.2f
#define NSUB      256                      // sub-buckets over dst space
#define SUB_NODES 196                      // nodes per sub
#define SUB_CAP   8192                     // per-sub global capacity (mean 6250)
#define BUCKET_B  640
#define BCHUNK    2500                     // N_EDGES / BUCKET_B
#define SB_CAP2   17                       // LDS cap/sub (19.5KB -> 8 blocks/CU)
#define EMB_B     ((N_NODES + 15) / 16)    // 3125 embed blocks (4 nodes/wave)
#define AGG_B     (N_NODES / 4)            // agg blocks (1 dst/wave)

// ---- monotone float<->uint encoding for atomicMax on floats ----
__device__ __forceinline__ unsigned fenc(float f) {
    unsigned u = __float_as_uint(f);
    return (u & 0x80000000u) ? ~u : (u | 0x80000000u);
}
__device__ __forceinline__ float fdec(unsigned k) {
    unsigned u = (k & 0x80000000u) ? (k & 0x7FFFFFFFu) : ~k;
    return __uint_as_float(u);
}
__device__ __forceinline__ float lrelu(float e) {
    return (e >= 0.f) ? e : NEG_SLOPE * e;
}
__device__ __forceinline__ int rli(int v, int l) {
    return __builtin_amdgcn_readlane(v, l);
}
__device__ __forceinline__ float rlf(float v, int l) {
    return __int_as_float(__builtin_amdgcn_readlane(__float_as_int(v), l));
}
// ---- fp16-pair pack + v_dot2_f32_f16 (fp16 mul, fp32 accumulate) ----
typedef _Float16 h2v __attribute__((ext_vector_type(2)));
__device__ __forceinline__ unsigned pkh2(float a, float b) {
    h2v v; v.x = (_Float16)a; v.y = (_Float16)b;
    return __builtin_bit_cast(unsigned, v);
}
__device__ __forceinline__ float fdot2u(unsigned a, unsigned b, float c) {
    return __builtin_amdgcn_fdot2(__builtin_bit_cast(h2v, a),
                                  __builtin_bit_cast(h2v, b), c, false);
}
// ---- packed edge record: low32 = src, high32 = el bits ----
__device__ __forceinline__ unsigned long long pke(int src, float el) {
    return ((unsigned long long)(unsigned)__float_as_int(el) << 32) |
           (unsigned long long)(unsigned)src;
}

// ---- fold: W2C1=w2@c1w; pack nw1, w2c1, c2w; init g_enc + sub_tail ----
__global__ __launch_bounds__(256) void fold_w(
    const float* __restrict__ nw1,
    const float* __restrict__ w2, const float* __restrict__ b2,
    const float* __restrict__ c1w, const float* __restrict__ c2w,
    unsigned* __restrict__ nw1_pk, unsigned* __restrict__ w2c1_pk,
    unsigned* __restrict__ c2w_pk,
    float* __restrict__ b2c1, unsigned* __restrict__ g_enc,
    unsigned* __restrict__ sub_tail)
{
    __shared__ float c1s[4096];
    __shared__ float w2c1s[4096];
    int tid = threadIdx.x;
    for (int i = tid; i < 4096; i += 256) c1s[i] = c1w[i];
    for (int i = tid; i < N_GRAPHS * HIDDEN; i += 256) g_enc[i] = fenc(-INFINITY);
    sub_tail[tid] = 0u;
    __syncthreads();
    int j = tid & 63, i0 = tid >> 6;
    for (int ii = 0; ii < 16; ++ii) {
        int i = i0 * 16 + ii;
        float a = 0.f;
#pragma unroll 8
        for (int k = 0; k < 64; ++k) a = fmaf(w2[i * 64 + k], c1s[k * 64 + j], a);
        w2c1s[i * 64 + j] = a;
    }
    if (tid < 64) {
        float a = 0.f;
#pragma unroll 8
        for (int k = 0; k < 64; ++k) a = fmaf(b2[k], c1s[k * 64 + tid], a);
        b2c1[tid] = a;
    }
    __syncthreads();
    for (int idx = tid; idx < 64 * 64; idx += 256) {
        int kk = idx >> 6, jj = idx & 63;
        nw1_pk[idx] = pkh2(nw1[(2 * kk) * 64 + jj], nw1[(2 * kk + 1) * 64 + jj]);
    }
    for (int idx = tid; idx < 32 * 64; idx += 256) {
        int kk = idx >> 6, jj = idx & 63;
        w2c1_pk[idx] = pkh2(w2c1s[(2 * kk) * 64 + jj], w2c1s[(2 * kk + 1) * 64 + jj]);
        c2w_pk[idx]  = pkh2(c2w[(2 * kk) * 64 + jj],  c2w[(2 * kk + 1) * 64 + jj]);
    }
}

// ---- FUSED: bucket blocks [0,BUCKET_B) + embed blocks [BUCKET_B, +EMB_B) ----
__global__ __launch_bounds__(256) void embed_bucket(
    const float* __restrict__ x,
    const unsigned* __restrict__ nw1_pk, const float* __restrict__ n_b1,
    const unsigned* __restrict__ w2c1_pk, const float* __restrict__ b2c1,
    const float* __restrict__ a1s, const float* __restrict__ a1d,
    __half* __restrict__ hlin,
    float* __restrict__ asrc, float* __restrict__ adst,
    float* __restrict__ blkmax,
    const int* __restrict__ ei,
    unsigned* __restrict__ sub_tail, unsigned* __restrict__ sub_buf)
{
    __shared__ unsigned st[NSUB][SB_CAP2];    // 17.4 KB, odd stride: conflict-free
    __shared__ unsigned scnt[NSUB];
    __shared__ unsigned sbase[NSUB];
    __shared__ float wred[4];
    int tid = threadIdx.x;
    int lane = tid & 63, wid = tid >> 6;

    if (blockIdx.x < BUCKET_B) {
        // ---------- bucket path ----------
        scnt[tid] = 0u;
        __syncthreads();
        int beg = blockIdx.x * BCHUNK;
        int end = min(beg + BCHUNK, N_EDGES);
        for (int base = beg; base < end; base += 256) {
            int e = base + tid;
            if (e < end) {
                unsigned src = (unsigned)__builtin_nontemporal_load(ei + e);
                unsigned dst = (unsigned)__builtin_nontemporal_load(ei + N_EDGES + e);
                unsigned sub = dst / SUB_NODES;
                unsigned pay = ((dst - sub * SUB_NODES) << 16) | src;
                unsigned p = atomicAdd(&scnt[sub], 1u);
                if (p < SB_CAP2) st[sub][p] = pay;
                else {                           // ~1% overflow: direct write
                    unsigned gp = atomicAdd(&sub_tail[sub], 1u);
                    if (gp < SUB_CAP)
                        __builtin_nontemporal_store(pay, sub_buf + (size_t)sub * SUB_CAP + gp);
                }
            }
        }
        __syncthreads();
        unsigned c = min(scnt[tid], (unsigned)SB_CAP2);
        scnt[tid] = c;
        sbase[tid] = atomicAdd(&sub_tail[tid], c);
        __syncthreads();
        // wave-coalesced flush: wave handles subs wid, wid+4, ...; lanes 0..c-1
        for (int o = wid; o < NSUB; o += 4) {
            unsigned c_o = scnt[o];
            if ((unsigned)lane < c_o) {
                unsigned pos = sbase[o] + lane;
                if (pos < SUB_CAP)
                    __builtin_nontemporal_store(st[o][lane],
                        sub_buf + (size_t)o * SUB_CAP + pos);
            }
        }
    } else {
        // ---------- embed path: MLP + folded linear via packed dot2 ----------
        int eb = blockIdx.x - BUCKET_B;
        int n0 = eb * 16 + wid * 4;          // 4 nodes per wave
        if (n0 < N_NODES) {
            unsigned xpk[4];
#pragma unroll
            for (int nn = 0; nn < 4; ++nn) {
                float2 v = ((const float2*)(x + (size_t)(n0 + nn) * N_FEAT))[lane];
                xpk[nn] = pkh2(v.x, v.y);
            }
            float acc[4];
            float b1v = n_b1[lane];
#pragma unroll
            for (int nn = 0; nn < 4; ++nn) acc[nn] = b1v;
#pragma unroll 4
            for (int kk = 0; kk < 64; ++kk) {
                unsigned wp = nw1_pk[kk * 64 + lane];
#pragma unroll
                for (int nn = 0; nn < 4; ++nn)
                    acc[nn] = fdot2u((unsigned)rli((int)xpk[nn], kk), wp, acc[nn]);
            }
#pragma unroll
            for (int nn = 0; nn < 4; ++nn) acc[nn] = fmaxf(acc[nn], 0.f);
            unsigned hpk[4];
#pragma unroll
            for (int nn = 0; nn < 4; ++nn) {
                float ha = __shfl(acc[nn], (2 * lane) & 63, 64);
                float hb = __shfl(acc[nn], (2 * lane + 1) & 63, 64);
                hpk[nn] = pkh2(ha, hb);
            }
            float hl[4];
            float bcv = b2c1[lane];
#pragma unroll
            for (int nn = 0; nn < 4; ++nn) hl[nn] = bcv;
#pragma unroll 4
            for (int kk = 0; kk < 32; ++kk) {
                unsigned wp = w2c1_pk[kk * 64 + lane];
#pragma unroll
                for (int nn = 0; nn < 4; ++nn)
                    hl[nn] = fdot2u((unsigned)rli((int)hpk[nn], kk), wp, hl[nn]);
            }
            float s1v = a1s[lane], d1v = a1d[lane];
            float wmax = -INFINITY;
#pragma unroll
            for (int nn = 0; nn < 4; ++nn) {
                int n = n0 + nn;
                hlin[(size_t)n * 64 + lane] = __float2half(hl[nn]);
                float ps = hl[nn] * s1v, pd = hl[nn] * d1v;
#pragma unroll
                for (int off = 32; off; off >>= 1) {
                    ps += __shfl_xor(ps, off, 64);
                    pd += __shfl_xor(pd, off, 64);
                }
                if (lane == 0) { asrc[n] = ps; adst[n] = pd; wmax = fmaxf(wmax, ps); }
            }
            if (lane == 0) wred[wid] = wmax;
        } else if (lane == 0) wred[wid] = -INFINITY;
        __syncthreads();
        if (tid == 0)
            blkmax[eb] = fmaxf(fmaxf(wred[0], wred[1]), fmaxf(wred[2], wred[3]));
    }
}

// ---- CSR build (256 per-sub blocks, zero global atomics) -> epk + As1 ----
__global__ __launch_bounds__(256) void csr_as1(
    const unsigned* __restrict__ sub_buf, const unsigned* __restrict__ sub_tail,
    const float* __restrict__ asrc1, const float* __restrict__ adst1,
    unsigned* __restrict__ row_ptr, unsigned long long* __restrict__ epk,
    const float* __restrict__ blkmax1, float* __restrict__ As1)
{
    __shared__ unsigned hist[SUB_NODES];
    __shared__ unsigned wt4[4], wo4[4];
    __shared__ unsigned eb_s[2];
    __shared__ unsigned tot_s;
    int tid = threadIdx.x, lane = tid & 63, wid = tid >> 6;

    if (blockIdx.x == NSUB) {              // As1 reduction block
        float m = -INFINITY;
        for (int i = tid; i < EMB_B; i += 256) m = fmaxf(m, blkmax1[i]);
#pragma unroll
        for (int off = 32; off; off >>= 1) m = fmaxf(m, __shfl_xor(m, off, 64));
        float* sm = (float*)wt4;
        if (lane == 0) sm[wid] = m;
        __syncthreads();
        if (tid == 0)
            As1[0] = fmaxf(fmaxf(sm[0], sm[1]), fmaxf(sm[2], sm[3]));
        return;
    }
    int gs = blockIdx.x;                   // 0..255
    unsigned myc = min(sub_tail[tid], (unsigned)SUB_CAP);
    unsigned nn_t = (tid < NSUB - 1) ? SUB_NODES : (N_NODES - (NSUB - 1) * SUB_NODES);
    unsigned v = myc + nn_t;
    unsigned xs = v;
#pragma unroll
    for (int off = 1; off < 64; off <<= 1) {
        unsigned t = __shfl_up(xs, off, 64);
        if (lane >= off) xs += t;
    }
    if (lane == 63) wt4[wid] = xs;
    __syncthreads();
    if (tid == 0) {
        unsigned run = 0;
        for (int w = 0; w < 4; ++w) { wo4[w] = run; run += wt4[w]; }
        tot_s = run;
    }
    __syncthreads();
    unsigned excl = wo4[wid] + xs - v;
    if (tid == gs) { eb_s[0] = excl; eb_s[1] = myc; }
    if (gs == 0 && tid == 0) row_ptr[N_NODES] = tot_s;
    __syncthreads();
    unsigned ebase = eb_s[0], cnt = eb_s[1];
    int node_lo = gs * SUB_NODES;
    int nn = (gs < NSUB - 1) ? SUB_NODES : (N_NODES - (NSUB - 1) * SUB_NODES);
    for (int i = tid; i < nn; i += 256) hist[i] = 1u;
    __syncthreads();
    const unsigned* seg = sub_buf + (size_t)gs * SUB_CAP;
    for (unsigned i = tid; i < cnt; i += 256)
        atomicAdd(&hist[__builtin_nontemporal_load(seg + i) >> 16], 1u);
    __syncthreads();
    unsigned v2 = (tid < nn) ? hist[tid] : 0u;
    unsigned xs2 = v2;
#pragma unroll
    for (int off = 1; off < 64; off <<= 1) {
        unsigned t = __shfl_up(xs2, off, 64);
        if (lane >= off) xs2 += t;
    }
    __syncthreads();
    if (lane == 63) wt4[wid] = xs2;
    __syncthreads();
    if (tid == 0) {
        unsigned run = 0;
        for (int w = 0; w < 4; ++w) { wo4[w] = run; run += wt4[w]; }
    }
    __syncthreads();
    if (tid < nn) {
        unsigned ex2 = wo4[wid] + xs2 - v2;
        unsigned rp = ebase + ex2;
        int n = node_lo + tid;
        row_ptr[n] = rp;
        epk[rp] = pke(n, lrelu(asrc1[n] + adst1[n]));   // self-loop first slot
        hist[tid] = ex2 + 1u;
    }
    __syncthreads();
    // scatter + layer-1 edge logit packed with src
    for (unsigned i = tid; i < cnt; i += 256) {
        unsigned pay = __builtin_nontemporal_load(seg + i);
        unsigned dl = pay >> 16;
        int src = (int)(pay & 0xffffu);
        unsigned p = atomicAdd(&hist[dl], 1u);
        epk[ebase + p] = pke(src, lrelu(asrc1[src] + adst1[node_lo + (int)dl]));
    }
}

// ---- 1-block max-reduce ----
__global__ __launch_bounds__(1024) void reduce_max(
    const float* __restrict__ in, int n, float* __restrict__ As)
{
    __shared__ float wm[16];
    int tid = threadIdx.x, lane = tid & 63, wid = tid >> 6;
    float m = -INFINITY;
    for (int i = tid; i < n; i += 1024) m = fmaxf(m, in[i]);
#pragma unroll
    for (int off = 32; off; off >>= 1) m = fmaxf(m, __shfl_xor(m, off, 64));
    if (lane == 0) wm[wid] = m;
    __syncthreads();
    if (tid == 0) {
        float r = -INFINITY;
        for (int w = 0; w < 16; ++w) r = fmaxf(r, wm[w]);
        As[0] = r;
    }
}

// ---- agg core (packed el): 8 lanes/edge, U=4 burst ----
__device__ __forceinline__ float agg8e(
    const __half* __restrict__ hmat,      // [N][64] fp16 (128B rows)
    const unsigned long long* __restrict__ epk,
    int s0, int s1, float C, int lane, float acc[8])
{
    int slot = lane >> 3;
    int fb = (lane & 7) << 3;
    float sden = 0.f;
#pragma unroll
    for (int j = 0; j < 8; ++j) acc[j] = 0.f;
    for (int base = s0; base < s1; base += 32) {
        int e0 = base + slot, e1 = e0 + 8, e2 = e0 + 16, e3 = e0 + 24;
        unsigned long long q0 = (e0 < s1) ? __builtin_nontemporal_load(epk + e0) : 0ull;
        unsigned long long q1 = (e1 < s1) ? __builtin_nontemporal_load(epk + e1) : 0ull;
        unsigned long long q2 = (e2 < s1) ? __builtin_nontemporal_load(epk + e2) : 0ull;
        unsigned long long q3 = (e3 < s1) ? __builtin_nontemporal_load(epk + e3) : 0ull;
        int i0 = (int)(unsigned)q0, i1 = (int)(unsigned)q1;
        int i2 = (int)(unsigned)q2, i3 = (int)(unsigned)q3;
        float w0 = (e0 < s1) ? __expf(__int_as_float((int)(q0 >> 32)) - C) : 0.f;
        float w1 = (e1 < s1) ? __expf(__int_as_float((int)(q1 >> 32)) - C) : 0.f;
        float w2 = (e2 < s1) ? __expf(__int_as_float((int)(q2 >> 32)) - C) : 0.f;
        float w3 = (e3 < s1) ? __expf(__int_as_float((int)(q3 >> 32)) - C) : 0.f;
        sden += (w0 + w1) + (w2 + w3);
        float4 hv0 = *(const float4*)(hmat + (size_t)i0 * 64 + fb);
        float4 hv1 = *(const float4*)(hmat + (size_t)i1 * 64 + fb);
        float4 hv2 = *(const float4*)(hmat + (size_t)i2 * 64 + fb);
        float4 hv3 = *(const float4*)(hmat + (size_t)i3 * 64 + fb);
        float2 a, b, c, dd;
#define ACC8(HV, W) \
        a = __half22float2(__builtin_bit_cast(__half2, HV.x)); \
        b = __half22float2(__builtin_bit_cast(__half2, HV.y)); \
        c = __half22float2(__builtin_bit_cast(__half2, HV.z)); \
        dd = __half22float2(__builtin_bit_cast(__half2, HV.w)); \
        acc[0] = fmaf(W, a.x, acc[0]);  acc[1] = fmaf(W, a.y, acc[1]); \
        acc[2] = fmaf(W, b.x, acc[2]);  acc[3] = fmaf(W, b.y, acc[3]); \
        acc[4] = fmaf(W, c.x, acc[4]);  acc[5] = fmaf(W, c.y, acc[5]); \
        acc[6] = fmaf(W, dd.x, acc[6]); acc[7] = fmaf(W, dd.y, acc[7]);
        ACC8(hv0, w0)
        ACC8(hv1, w1)
        ACC8(hv2, w2)
        ACC8(hv3, w3)
#undef ACC8
    }
#pragma unroll
    for (int j = 0; j < 8; ++j) {
        acc[j] += __shfl_xor(acc[j], 8, 64);
        acc[j] += __shfl_xor(acc[j], 16, 64);
        acc[j] += __shfl_xor(acc[j], 32, 64);
    }
#pragma unroll
    for (int off = 32; off; off >>= 1) sden += __shfl_xor(sden, off, 64);
    return sden * 0.125f;
}

// ---- agg core (inline logit): src from epk low word, asrc L2-resident ----
__device__ __forceinline__ float agg8i(
    const __half* __restrict__ hmat,
    const unsigned long long* __restrict__ epk,
    const float* __restrict__ asrc,
    int s0, int s1, float ad, float C, int lane, float acc[8])
{
    int slot = lane >> 3;
    int fb = (lane & 7) << 3;
    float sden = 0.f;
#pragma unroll
    for (int j = 0; j < 8; ++j) acc[j] = 0.f;
    for (int base = s0; base < s1; base += 32) {
        int e0 = base + slot, e1 = e0 + 8, e2 = e0 + 16, e3 = e0 + 24;
        unsigned long long q0 = (e0 < s1) ? __builtin_nontemporal_load(epk + e0) : 0ull;
        unsigned long long q1 = (e1 < s1) ? __builtin_nontemporal_load(epk + e1) : 0ull;
        unsigned long long q2 = (e2 < s1) ? __builtin_nontemporal_load(epk + e2) : 0ull;
        unsigned long long q3 = (e3 < s1) ? __builtin_nontemporal_load(epk + e3) : 0ull;
        int i0 = (int)(unsigned)q0, i1 = (int)(unsigned)q1;
        int i2 = (int)(unsigned)q2, i3 = (int)(unsigned)q3;
        // issue row loads first (dep: idx only); logit gathers+exp overlap them
        float4 hv0 = *(const float4*)(hmat + (size_t)i0 * 64 + fb);
        float4 hv1 = *(const float4*)(hmat + (size_t)i1 * 64 + fb);
        float4 hv2 = *(const float4*)(hmat + (size_t)i2 * 64 + fb);
        float4 hv3 = *(const float4*)(hmat + (size_t)i3 * 64 + fb);
        float w0 = (e0 < s1) ? __expf(lrelu(asrc[i0] + ad) - C) : 0.f;
        float w1 = (e1 < s1) ? __expf(lrelu(asrc[i1] + ad) - C) : 0.f;
        float w2 = (e2 < s1) ? __expf(lrelu(asrc[i2] + ad) - C) : 0.f;
        float w3 = (e3 < s1) ? __expf(lrelu(asrc[i3] + ad) - C) : 0.f;
        sden += (w0 + w1) + (w2 + w3);
        float2 a, b, c, dd;
#define ACC8(HV, W) \
        a = __half22float2(__builtin_bit_cast(__half2, HV.x)); \
        b = __half22float2(__builtin_bit_cast(__half2, HV.y)); \
        c = __half22float2(__builtin_bit_cast(__half2, HV.z)); \
        dd = __half22float2(__builtin_bit_cast(__half2, HV.w)); \
        acc[0] = fmaf(W, a.x, acc[0]);  acc[1] = fmaf(W, a.y, acc[1]); \
        acc[2] = fmaf(W, b.x, acc[2]);  acc[3] = fmaf(W, b.y, acc[3]); \
        acc[4] = fmaf(W, c.x, acc[4]);  acc[5] = fmaf(W, c.y, acc[5]); \
        acc[6] = fmaf(W, dd.x, acc[6]); acc[7] = fmaf(W, dd.y, acc[7]);
        ACC8(hv0, w0)
        ACC8(hv1, w1)
        ACC8(hv2, w2)
        ACC8(hv3, w3)
#undef ACC8
    }
#pragma unroll
    for (int j = 0; j < 8; ++j) {
        acc[j] += __shfl_xor(acc[j], 8, 64);
        acc[j] += __shfl_xor(acc[j], 16, 64);
        acc[j] += __shfl_xor(acc[j], 32, 64);
    }
#pragma unroll
    for (int off = 32; off; off >>= 1) sden += __shfl_xor(sden, off, 64);
    return sden * 0.125f;
}

// ---- fused: GAT layer1 aggregate (+relu) + layer2 linear + alpha dots ----
__global__ __launch_bounds__(256) void agg1(
    const __half* __restrict__ hlin1,
    const float* __restrict__ adst,
    const unsigned* __restrict__ row_ptr,
    const unsigned long long* __restrict__ epk,
    const float* __restrict__ As1, const float* __restrict__ c1b,
    const unsigned* __restrict__ c2w_pk,
    const float* __restrict__ a2s, const float* __restrict__ a2d,
    __half* __restrict__ hlin2, float* __restrict__ asrc2, float* __restrict__ adst2,
    float* __restrict__ blkmax)
{
    __shared__ float vbuf[4][64];
    __shared__ float wred[4];
    int lane = threadIdx.x & 63, w = threadIdx.x >> 6;
    int d = blockIdx.x * 4 + w;
    int s0 = (int)row_ptr[d], s1 = (int)row_ptr[d + 1];
    float C = lrelu(As1[0] + adst[d]);
    float acc[8];
    float den = agg8e(hlin1, epk, s0, s1, C, lane, acc);
    if ((lane >> 3) == 0) {               // slot-0 lanes hold all 64 features
        int fb = (lane & 7) << 3;
#pragma unroll
        for (int j = 0; j < 8; ++j) vbuf[w][fb + j] = acc[j];
    }
    __syncthreads();
    float inv = 1.f / (den + 1e-30f);
    int l2 = (2 * lane) & 63;
    float va = fmaxf(vbuf[w][l2] * inv + c1b[l2], 0.f);
    float vb = fmaxf(vbuf[w][l2 + 1] * inv + c1b[l2 + 1], 0.f);
    unsigned vpk = pkh2(va, vb);
    float hl = 0.f;
#pragma unroll 8
    for (int kk = 0; kk < 32; ++kk)
        hl = fdot2u((unsigned)rli((int)vpk, kk), c2w_pk[kk * 64 + lane], hl);
    hlin2[(size_t)d * 64 + lane] = __float2half(hl);
    float ps = hl * a2s[lane], pd = hl * a2d[lane];
#pragma unroll
    for (int off = 32; off; off >>= 1) {
        ps += __shfl_xor(ps, off, 64);
        pd += __shfl_xor(pd, off, 64);
    }
    if (lane == 0) { asrc2[d] = ps; adst2[d] = pd; wred[w] = ps; }
    __syncthreads();
    if (threadIdx.x == 0)
        blkmax[blockIdx.x] = fmaxf(fmaxf(wred[0], wred[1]), fmaxf(wred[2], wred[3]));
}

// ---- fused: GAT layer2 aggregate (inline logits) + bias + pooled atomics ----
__global__ __launch_bounds__(256) void agg2_pool(
    const __half* __restrict__ hlin2,
    const float* __restrict__ asrc2, const float* __restrict__ adst2,
    const unsigned* __restrict__ row_ptr,
    const unsigned long long* __restrict__ epk,
    const float* __restrict__ As2, const float* __restrict__ c2b,
    const int* __restrict__ batch, unsigned* __restrict__ g_enc)
{
    __shared__ float vbuf[4][64];
    __shared__ int sbat[4];
    int lane = threadIdx.x & 63, w = threadIdx.x >> 6;
    int d = blockIdx.x * 4 + w;
    int s0 = (int)row_ptr[d], s1 = (int)row_ptr[d + 1];
    float ad = adst2[d];
    float C = lrelu(As2[0] + ad);
    float acc[8];
    float den = agg8i(hlin2, epk, asrc2, s0, s1, ad, C, lane, acc);
    if ((lane >> 3) == 0) {
        int fb = (lane & 7) << 3;
#pragma unroll
        for (int j = 0; j < 8; ++j) vbuf[w][fb + j] = acc[j];
    }
    __syncthreads();
    float v = vbuf[w][lane] / (den + 1e-30f) + c2b[lane];   // no relu
    vbuf[w][lane] = v;                     // own slot: race-free write-back
    if (lane == 0) sbat[w] = batch[d];
    __syncthreads();
    int b0 = sbat[0];
    bool same = (sbat[1] == b0) & (sbat[2] == b0) & (sbat[3] == b0);
    if (same) {
        // common case (batch sorted): 64 atomics per block instead of 256
        if (w == 0) {
            float m = fmaxf(fmaxf(vbuf[0][lane], vbuf[1][lane]),
                            fmaxf(vbuf[2][lane], vbuf[3][lane]));
            atomicMax(&g_enc[b0 * 64 + lane], fenc(m));
        }
    } else {
        atomicMax(&g_enc[sbat[w] * 64 + lane], fenc(v));
    }
}

// ---- readout MLP: wave per graph ----
__global__ __launch_bounds__(256) void readout(
    const unsigned* __restrict__ g_enc,
    const float* __restrict__ fc1w, const float* __restrict__ fc1b,
    const float* __restrict__ fc2w, const float* __restrict__ fc2b,
    float* __restrict__ out)
{
    int lane = threadIdx.x & 63;
    int gi = blockIdx.x * 4 + (threadIdx.x >> 6);
    float gv = fdec(g_enc[gi * 64 + lane]);
    float a = fc1b[lane];
#pragma unroll 8
    for (int k = 0; k < 64; ++k)
        a = fmaf(rlf(gv, k), fc1w[k * 64 + lane], a);
    a = fmaxf(a, 0.f) * fc2w[lane];
#pragma unroll
    for (int off = 32; off; off >>= 1) a += __shfl_xor(a, off, 64);
    if (lane == 0) out[gi] = a + fc2b[0];
}

extern "C" void kernel_launch(void* const* d_in, const int* in_sizes, int n_in,
                              void* d_out, int out_size, void* d_ws, size_t ws_size,
                              hipStream_t stream)
{
    const float* x      = (const float*)d_in[0];
    const int*   ei     = (const int*)d_in[1];
    // d_in[2] edge_attr: dead value in reference, never read
    const int*   batch  = (const int*)d_in[3];
    const float* n_w1   = (const float*)d_in[4];
    const float* n_b1   = (const float*)d_in[5];
    const float* n_w2   = (const float*)d_in[6];
    const float* n_b2   = (const float*)d_in[7];
    // d_in[8..11] edge MLP weights: dead
    const float* c1_w    = (const float*)d_in[12];
    const float* c1_asrc = (const float*)d_in[13];
    const float* c1_adst = (const float*)d_in[14];
    const float* c1_b    = (const float*)d_in[15];
    const float* c2_w    = (const float*)d_in[16];
    const float* c2_asrc = (const float*)d_in[17];
    const float* c2_adst = (const float*)d_in[18];
    const float* c2_b    = (const float*)d_in[19];
    const float* fc1_w   = (const float*)d_in[20];
    const float* fc1_b   = (const float*)d_in[21];
    const float* fc2_w   = (const float*)d_in[22];
    const float* fc2_b   = (const float*)d_in[23];
    float* out = (float*)d_out;

    // workspace carve (256B aligned)
    char* ws = (char*)d_ws;
    size_t off = 0;
    auto alloc = [&](size_t bytes) -> void* {
        off = (off + 255) & ~(size_t)255;
        void* p = ws + off;
        off += bytes;
        return p;
    };
    unsigned* sub_tail = (unsigned*)alloc(sizeof(unsigned) * NSUB);
    unsigned* sub_buf  = (unsigned*)alloc(sizeof(unsigned) * (size_t)NSUB * SUB_CAP);
    unsigned* row_ptr  = (unsigned*)alloc(sizeof(unsigned) * (N_NODES + 1));
    unsigned long long* epk =
        (unsigned long long*)alloc(sizeof(unsigned long long) * E_TOT);
    __half*   hlin1    = (__half*)alloc(sizeof(__half) * (size_t)N_NODES * 64);
    __half*   hlin2    = (__half*)alloc(sizeof(__half) * (size_t)N_NODES * 64);
    float*    asrc1    = (float*)alloc(sizeof(float) * N_NODES);
    float*    adst1    = (float*)alloc(sizeof(float) * N_NODES);
    float*    asrc2    = (float*)alloc(sizeof(float) * N_NODES);
    float*    adst2    = (float*)alloc(sizeof(float) * N_NODES);
    unsigned* g_enc    = (unsigned*)alloc(sizeof(unsigned) * N_GRAPHS * HIDDEN);
    unsigned* nw1_pk   = (unsigned*)alloc(sizeof(unsigned) * 64 * 64);
    unsigned* w2c1_pk  = (unsigned*)alloc(sizeof(unsigned) * 32 * 64);
    unsigned* c2w_pk   = (unsigned*)alloc(sizeof(unsigned) * 32 * 64);
    float*    b2c1     = (float*)alloc(sizeof(float) * 64);
    float*    blkmax1  = (float*)alloc(sizeof(float) * EMB_B);
    float*    blkmax2  = (float*)alloc(sizeof(float) * AGG_B);
    float*    As1      = (float*)alloc(sizeof(float) * 2);
    float*    As2      = (float*)alloc(sizeof(float) * 2);

    fold_w<<<1, 256, 0, stream>>>(n_w1, n_w2, n_b2, c1_w, c2_w,
                                  nw1_pk, w2c1_pk, c2w_pk, b2c1, g_enc, sub_tail);

    // bucket (640 blocks, overlaps embed) + embed (3125 blocks)
    embed_bucket<<<BUCKET_B + EMB_B, 256, 0, stream>>>(
        x, nw1_pk, n_b1, w2c1_pk, b2c1, c1_asrc, c1_adst,
        hlin1, asrc1, adst1, blkmax1,
        ei, sub_tail, sub_buf);

    // CSR build -> packed (src, el1) records + As1 reduce
    csr_as1<<<NSUB + 1, 256, 0, stream>>>(
        sub_buf, sub_tail, asrc1, adst1, row_ptr, epk, blkmax1, As1);

    agg1<<<AGG_B, 256, 0, stream>>>(
        hlin1, adst1, row_ptr, epk, As1,
        c1_b, c2w_pk, c2_asrc, c2_adst, hlin2, asrc2, adst2, blkmax2);

    // As2 reduce (replaces the 13us wfill2 edge pass)
    reduce_max<<<1, 1024, 0, stream>>>(blkmax2, AGG_B, As2);

    // layer-2 agg with inline logits (asrc2 is 200KB, L2-resident)
    agg2_pool<<<AGG_B, 256, 0, stream>>>(
        hlin2, asrc2, adst2, row_ptr, epk, As2, c2_b, batch, g_enc);
    readout<<<N_GRAPHS / 4, 256, 0, stream>>>(g_enc, fc1_w, fc1_b, fc2_w, fc2_b, out);
}

// Round 24
// 214.404 us; speedup vs baseline: 1.2166x; 1.0408x over previous
//
#include <hip/hip_runtime.h>
#include <hip/hip_fp16.h>
#include <math.h>

#define N_NODES   50000
#define N_EDGES   1600000
#define E_TOT     (N_EDGES + N_NODES)
#define N_FEAT    128
#define HIDDEN    64
#define N_GRAPHS  128
#define NEG_SLOPE 0.2f
#define NSUB      256                      // sub-buckets over dst space
#define SUB_NODES 196                      // nodes per sub
#define SUB_CAP   8192                     // per-sub global capacity (mean 6250)
#define BUCKET_B  640
#define BCHUNK    2500                     // N_EDGES / BUCKET_B
#define SB_CAP2   17                       // LDS cap/sub (19.5KB -> 8 blocks/CU)
#define EMB_B     ((N_NODES + 15) / 16)    // 3125 embed blocks (4 nodes/wave)
#define AGG_B     (N_NODES / 4)            // agg blocks (1 dst/wave)

// ---- monotone float<->uint encoding for atomicMax on floats ----
__device__ __forceinline__ unsigned fenc(float f) {
    unsigned u = __float_as_uint(f);
    return (u & 0x80000000u) ? ~u : (u | 0x80000000u);
}
__device__ __forceinline__ float fdec(unsigned k) {
    unsigned u = (k & 0x80000000u) ? (k & 0x7FFFFFFFu) : ~k;
    return __uint_as_float(u);
}
__device__ __forceinline__ float lrelu(float e) {
    return (e >= 0.f) ? e : NEG_SLOPE * e;
}
__device__ __forceinline__ int rli(int v, int l) {
    return __builtin_amdgcn_readlane(v, l);
}
__device__ __forceinline__ float rlf(float v, int l) {
    return __int_as_float(__builtin_amdgcn_readlane(__float_as_int(v), l));
}
// ---- fp16-pair pack + v_dot2_f32_f16 (fp16 mul, fp32 accumulate) ----
typedef _Float16 h2v __attribute__((ext_vector_type(2)));
__device__ __forceinline__ unsigned pkh2(float a, float b) {
    h2v v; v.x = (_Float16)a; v.y = (_Float16)b;
    return __builtin_bit_cast(unsigned, v);
}
__device__ __forceinline__ float fdot2u(unsigned a, unsigned b, float c) {
    return __builtin_amdgcn_fdot2(__builtin_bit_cast(h2v, a),
                                  __builtin_bit_cast(h2v, b), c, false);
}
// ---- packed edge record: low32 = src, high32 = el bits ----
__device__ __forceinline__ unsigned long long pke(int src, float el) {
    return ((unsigned long long)(unsigned)__float_as_int(el) << 32) |
           (unsigned long long)(unsigned)src;
}

// ---- fold: W2C1=w2@c1w; pack nw1, w2c1, c2w; init g_enc + sub_tail ----
__global__ __launch_bounds__(256) void fold_w(
    const float* __restrict__ nw1,
    const float* __restrict__ w2, const float* __restrict__ b2,
    const float* __restrict__ c1w, const float* __restrict__ c2w,
    unsigned* __restrict__ nw1_pk, unsigned* __restrict__ w2c1_pk,
    unsigned* __restrict__ c2w_pk,
    float* __restrict__ b2c1, unsigned* __restrict__ g_enc,
    unsigned* __restrict__ sub_tail)
{
    __shared__ float c1s[4096];
    __shared__ float w2c1s[4096];
    int tid = threadIdx.x;
    for (int i = tid; i < 4096; i += 256) c1s[i] = c1w[i];
    for (int i = tid; i < N_GRAPHS * HIDDEN; i += 256) g_enc[i] = fenc(-INFINITY);
    sub_tail[tid] = 0u;
    __syncthreads();
    int j = tid & 63, i0 = tid >> 6;
    for (int ii = 0; ii < 16; ++ii) {
        int i = i0 * 16 + ii;
        float a = 0.f;
#pragma unroll 8
        for (int k = 0; k < 64; ++k) a = fmaf(w2[i * 64 + k], c1s[k * 64 + j], a);
        w2c1s[i * 64 + j] = a;
    }
    if (tid < 64) {
        float a = 0.f;
#pragma unroll 8
        for (int k = 0; k < 64; ++k) a = fmaf(b2[k], c1s[k * 64 + tid], a);
        b2c1[tid] = a;
    }
    __syncthreads();
    for (int idx = tid; idx < 64 * 64; idx += 256) {
        int kk = idx >> 6, jj = idx & 63;
        nw1_pk[idx] = pkh2(nw1[(2 * kk) * 64 + jj], nw1[(2 * kk + 1) * 64 + jj]);
    }
    for (int idx = tid; idx < 32 * 64; idx += 256) {
        int kk = idx >> 6, jj = idx & 63;
        w2c1_pk[idx] = pkh2(w2c1s[(2 * kk) * 64 + jj], w2c1s[(2 * kk + 1) * 64 + jj]);
        c2w_pk[idx]  = pkh2(c2w[(2 * kk) * 64 + jj],  c2w[(2 * kk + 1) * 64 + jj]);
    }
}

// ---- FUSED: bucket blocks [0,BUCKET_B) + embed blocks [BUCKET_B, +EMB_B) ----
__global__ __launch_bounds__(256) void embed_bucket(
    const float* __restrict__ x,
    const unsigned* __restrict__ nw1_pk, const float* __restrict__ n_b1,
    const unsigned* __restrict__ w2c1_pk, const float* __restrict__ b2c1,
    const float* __restrict__ a1s, const float* __restrict__ a1d,
    __half* __restrict__ hlin,
    float* __restrict__ asrc, float* __restrict__ adst,
    float* __restrict__ blkmax,
    const int* __restrict__ ei,
    unsigned* __restrict__ sub_tail, unsigned* __restrict__ sub_buf)
{
    __shared__ unsigned st[NSUB][SB_CAP2];    // 17.4 KB, odd stride: conflict-free
    __shared__ unsigned scnt[NSUB];
    __shared__ unsigned sbase[NSUB];
    __shared__ float wred[4];
    int tid = threadIdx.x;
    int lane = tid & 63, wid = tid >> 6;

    if (blockIdx.x < BUCKET_B) {
        // ---------- bucket path ----------
        scnt[tid] = 0u;
        __syncthreads();
        int beg = blockIdx.x * BCHUNK;
        int end = min(beg + BCHUNK, N_EDGES);
        for (int base = beg; base < end; base += 256) {
            int e = base + tid;
            if (e < end) {
                unsigned src = (unsigned)__builtin_nontemporal_load(ei + e);
                unsigned dst = (unsigned)__builtin_nontemporal_load(ei + N_EDGES + e);
                unsigned sub = dst / SUB_NODES;
                unsigned pay = ((dst - sub * SUB_NODES) << 16) | src;
                unsigned p = atomicAdd(&scnt[sub], 1u);
                if (p < SB_CAP2) st[sub][p] = pay;
                else {                           // ~1% overflow: direct write
                    unsigned gp = atomicAdd(&sub_tail[sub], 1u);
                    if (gp < SUB_CAP)
                        __builtin_nontemporal_store(pay, sub_buf + (size_t)sub * SUB_CAP + gp);
                }
            }
        }
        __syncthreads();
        unsigned c = min(scnt[tid], (unsigned)SB_CAP2);
        scnt[tid] = c;
        sbase[tid] = atomicAdd(&sub_tail[tid], c);
        __syncthreads();
        // wave-coalesced flush: wave handles subs wid, wid+4, ...; lanes 0..c-1
        for (int o = wid; o < NSUB; o += 4) {
            unsigned c_o = scnt[o];
            if ((unsigned)lane < c_o) {
                unsigned pos = sbase[o] + lane;
                if (pos < SUB_CAP)
                    __builtin_nontemporal_store(st[o][lane],
                        sub_buf + (size_t)o * SUB_CAP + pos);
            }
        }
    } else {
        // ---------- embed path: MLP + folded linear via packed dot2 ----------
        int eb = blockIdx.x - BUCKET_B;
        int n0 = eb * 16 + wid * 4;          // 4 nodes per wave
        if (n0 < N_NODES) {
            unsigned xpk[4];
#pragma unroll
            for (int nn = 0; nn < 4; ++nn) {
                float2 v = ((const float2*)(x + (size_t)(n0 + nn) * N_FEAT))[lane];
                xpk[nn] = pkh2(v.x, v.y);
            }
            float acc[4];
            float b1v = n_b1[lane];
#pragma unroll
            for (int nn = 0; nn < 4; ++nn) acc[nn] = b1v;
#pragma unroll 4
            for (int kk = 0; kk < 64; ++kk) {
                unsigned wp = nw1_pk[kk * 64 + lane];
#pragma unroll
                for (int nn = 0; nn < 4; ++nn)
                    acc[nn] = fdot2u((unsigned)rli((int)xpk[nn], kk), wp, acc[nn]);
            }
#pragma unroll
            for (int nn = 0; nn < 4; ++nn) acc[nn] = fmaxf(acc[nn], 0.f);
            unsigned hpk[4];
#pragma unroll
            for (int nn = 0; nn < 4; ++nn) {
                float ha = __shfl(acc[nn], (2 * lane) & 63, 64);
                float hb = __shfl(acc[nn], (2 * lane + 1) & 63, 64);
                hpk[nn] = pkh2(ha, hb);
            }
            float hl[4];
            float bcv = b2c1[lane];
#pragma unroll
            for (int nn = 0; nn < 4; ++nn) hl[nn] = bcv;
#pragma unroll 4
            for (int kk = 0; kk < 32; ++kk) {
                unsigned wp = w2c1_pk[kk * 64 + lane];
#pragma unroll
                for (int nn = 0; nn < 4; ++nn)
                    hl[nn] = fdot2u((unsigned)rli((int)hpk[nn], kk), wp, hl[nn]);
            }
            float s1v = a1s[lane], d1v = a1d[lane];
            float wmax = -INFINITY;
#pragma unroll
            for (int nn = 0; nn < 4; ++nn) {
                int n = n0 + nn;
                hlin[(size_t)n * 64 + lane] = __float2half(hl[nn]);
                float ps = hl[nn] * s1v, pd = hl[nn] * d1v;
#pragma unroll
                for (int off = 32; off; off >>= 1) {
                    ps += __shfl_xor(ps, off, 64);
                    pd += __shfl_xor(pd, off, 64);
                }
                if (lane == 0) { asrc[n] = ps; adst[n] = pd; wmax = fmaxf(wmax, ps); }
            }
            if (lane == 0) wred[wid] = wmax;
        } else if (lane == 0) wred[wid] = -INFINITY;
        __syncthreads();
        if (tid == 0)
            blkmax[eb] = fmaxf(fmaxf(wred[0], wred[1]), fmaxf(wred[2], wred[3]));
    }
}

// ---- CSR build: 1024 threads/block (16 waves/CU vs 4 -> hides LDS-atomic
// and scatter latency); zero global atomics -> epk + As1 ----
__global__ __launch_bounds__(1024) void csr_as1(
    const unsigned* __restrict__ sub_buf, const unsigned* __restrict__ sub_tail,
    const float* __restrict__ asrc1, const float* __restrict__ adst1,
    unsigned* __restrict__ row_ptr, unsigned long long* __restrict__ epk,
    const float* __restrict__ blkmax1, float* __restrict__ As1)
{
    __shared__ unsigned hist[SUB_NODES];
    __shared__ unsigned wt4[4], wo4[4];
    __shared__ unsigned eb_s[2];
    __shared__ unsigned tot_s;
    __shared__ float wm[16];
    int tid = threadIdx.x, lane = tid & 63, wid = tid >> 6;

    if (blockIdx.x == NSUB) {              // As1 reduction block
        float m = -INFINITY;
        for (int i = tid; i < EMB_B; i += 1024) m = fmaxf(m, blkmax1[i]);
#pragma unroll
        for (int off = 32; off; off >>= 1) m = fmaxf(m, __shfl_xor(m, off, 64));
        if (lane == 0) wm[wid] = m;
        __syncthreads();
        if (tid == 0) {
            float r = -INFINITY;
            for (int w = 0; w < 16; ++w) r = fmaxf(r, wm[w]);
            As1[0] = r;
        }
        return;
    }
    int gs = blockIdx.x;                   // 0..255
    // 256-wide exclusive scan over (cnt + nnodes); threads >=256 inert
    unsigned myc = 0u, v = 0u;
    if (tid < NSUB) {
        myc = min(sub_tail[tid], (unsigned)SUB_CAP);
        unsigned nn_t = (tid < NSUB - 1) ? SUB_NODES
                                         : (N_NODES - (NSUB - 1) * SUB_NODES);
        v = myc + nn_t;
    }
    unsigned xs = v;
#pragma unroll
    for (int off = 1; off < 64; off <<= 1) {
        unsigned t = __shfl_up(xs, off, 64);
        if (lane >= off) xs += t;
    }
    if (lane == 63 && wid < 4) wt4[wid] = xs;
    __syncthreads();
    if (tid == 0) {
        unsigned run = 0;
        for (int w = 0; w < 4; ++w) { wo4[w] = run; run += wt4[w]; }
        tot_s = run;
    }
    __syncthreads();
    if (tid == gs) { eb_s[0] = wo4[wid] + xs - v; eb_s[1] = myc; }
    if (gs == 0 && tid == 0) row_ptr[N_NODES] = tot_s;
    __syncthreads();
    unsigned ebase = eb_s[0], cnt = eb_s[1];
    int node_lo = gs * SUB_NODES;
    int nn = (gs < NSUB - 1) ? SUB_NODES : (N_NODES - (NSUB - 1) * SUB_NODES);
    for (int i = tid; i < nn; i += 1024) hist[i] = 1u;
    __syncthreads();
    const unsigned* seg = sub_buf + (size_t)gs * SUB_CAP;
    for (unsigned i = tid; i < cnt; i += 1024)
        atomicAdd(&hist[__builtin_nontemporal_load(seg + i) >> 16], 1u);
    __syncthreads();
    // scan hist (nn <= 256): first 4 waves carry it, others inert
    unsigned v2 = (tid < nn) ? hist[tid] : 0u;
    unsigned xs2 = v2;
#pragma unroll
    for (int off = 1; off < 64; off <<= 1) {
        unsigned t = __shfl_up(xs2, off, 64);
        if (lane >= off) xs2 += t;
    }
    __syncthreads();
    if (lane == 63 && wid < 4) wt4[wid] = xs2;
    __syncthreads();
    if (tid == 0) {
        unsigned run = 0;
        for (int w = 0; w < 4; ++w) { wo4[w] = run; run += wt4[w]; }
    }
    __syncthreads();
    if (tid < nn) {
        unsigned ex2 = wo4[wid] + xs2 - v2;
        unsigned rp = ebase + ex2;
        int n = node_lo + tid;
        row_ptr[n] = rp;
        epk[rp] = pke(n, lrelu(asrc1[n] + adst1[n]));   // self-loop first slot
        hist[tid] = ex2 + 1u;
    }
    __syncthreads();
    // scatter + layer-1 edge logit packed with src
    for (unsigned i = tid; i < cnt; i += 1024) {
        unsigned pay = __builtin_nontemporal_load(seg + i);
        unsigned dl = pay >> 16;
        int src = (int)(pay & 0xffffu);
        unsigned p = atomicAdd(&hist[dl], 1u);
        epk[ebase + p] = pke(src, lrelu(asrc1[src] + adst1[node_lo + (int)dl]));
    }
}

// ---- 1-block max-reduce ----
__global__ __launch_bounds__(1024) void reduce_max(
    const float* __restrict__ in, int n, float* __restrict__ As)
{
    __shared__ float wm[16];
    int tid = threadIdx.x, lane = tid & 63, wid = tid >> 6;
    float m = -INFINITY;
    for (int i = tid; i < n; i += 1024) m = fmaxf(m, in[i]);
#pragma unroll
    for (int off = 32; off; off >>= 1) m = fmaxf(m, __shfl_xor(m, off, 64));
    if (lane == 0) wm[wid] = m;
    __syncthreads();
    if (tid == 0) {
        float r = -INFINITY;
        for (int w = 0; w < 16; ++w) r = fmaxf(r, wm[w]);
        As[0] = r;
    }
}

// ---- agg core (packed el): 8 lanes/edge, U=4 burst ----
__device__ __forceinline__ float agg8e(
    const __half* __restrict__ hmat,      // [N][64] fp16 (128B rows)
    const unsigned long long* __restrict__ epk,
    int s0, int s1, float C, int lane, float acc[8])
{
    int slot = lane >> 3;
    int fb = (lane & 7) << 3;
    float sden = 0.f;
#pragma unroll
    for (int j = 0; j < 8; ++j) acc[j] = 0.f;
    for (int base = s0; base < s1; base += 32) {
        int e0 = base + slot, e1 = e0 + 8, e2 = e0 + 16, e3 = e0 + 24;
        unsigned long long q0 = (e0 < s1) ? __builtin_nontemporal_load(epk + e0) : 0ull;
        unsigned long long q1 = (e1 < s1) ? __builtin_nontemporal_load(epk + e1) : 0ull;
        unsigned long long q2 = (e2 < s1) ? __builtin_nontemporal_load(epk + e2) : 0ull;
        unsigned long long q3 = (e3 < s1) ? __builtin_nontemporal_load(epk + e3) : 0ull;
        int i0 = (int)(unsigned)q0, i1 = (int)(unsigned)q1;
        int i2 = (int)(unsigned)q2, i3 = (int)(unsigned)q3;
        float w0 = (e0 < s1) ? __expf(__int_as_float((int)(q0 >> 32)) - C) : 0.f;
        float w1 = (e1 < s1) ? __expf(__int_as_float((int)(q1 >> 32)) - C) : 0.f;
        float w2 = (e2 < s1) ? __expf(__int_as_float((int)(q2 >> 32)) - C) : 0.f;
        float w3 = (e3 < s1) ? __expf(__int_as_float((int)(q3 >> 32)) - C) : 0.f;
        sden += (w0 + w1) + (w2 + w3);
        float4 hv0 = *(const float4*)(hmat + (size_t)i0 * 64 + fb);
        float4 hv1 = *(const float4*)(hmat + (size_t)i1 * 64 + fb);
        float4 hv2 = *(const float4*)(hmat + (size_t)i2 * 64 + fb);
        float4 hv3 = *(const float4*)(hmat + (size_t)i3 * 64 + fb);
        float2 a, b, c, dd;
#define ACC8(HV, W) \
        a = __half22float2(__builtin_bit_cast(__half2, HV.x)); \
        b = __half22float2(__builtin_bit_cast(__half2, HV.y)); \
        c = __half22float2(__builtin_bit_cast(__half2, HV.z)); \
        dd = __half22float2(__builtin_bit_cast(__half2, HV.w)); \
        acc[0] = fmaf(W, a.x, acc[0]);  acc[1] = fmaf(W, a.y, acc[1]); \
        acc[2] = fmaf(W, b.x, acc[2]);  acc[3] = fmaf(W, b.y, acc[3]); \
        acc[4] = fmaf(W, c.x, acc[4]);  acc[5] = fmaf(W, c.y, acc[5]); \
        acc[6] = fmaf(W, dd.x, acc[6]); acc[7] = fmaf(W, dd.y, acc[7]);
        ACC8(hv0, w0)
        ACC8(hv1, w1)
        ACC8(hv2, w2)
        ACC8(hv3, w3)
#undef ACC8
    }
#pragma unroll
    for (int j = 0; j < 8; ++j) {
        acc[j] += __shfl_xor(acc[j], 8, 64);
        acc[j] += __shfl_xor(acc[j], 16, 64);
        acc[j] += __shfl_xor(acc[j], 32, 64);
    }
#pragma unroll
    for (int off = 32; off; off >>= 1) sden += __shfl_xor(sden, off, 64);
    return sden * 0.125f;
}

// ---- agg core (inline logit): src from epk low word, asrc L2-resident ----
__device__ __forceinline__ float agg8i(
    const __half* __restrict__ hmat,
    const unsigned long long* __restrict__ epk,
    const float* __restrict__ asrc,
    int s0, int s1, float ad, float C, int lane, float acc[8])
{
    int slot = lane >> 3;
    int fb = (lane & 7) << 3;
    float sden = 0.f;
#pragma unroll
    for (int j = 0; j < 8; ++j) acc[j] = 0.f;
    for (int base = s0; base < s1; base += 32) {
        int e0 = base + slot, e1 = e0 + 8, e2 = e0 + 16, e3 = e0 + 24;
        unsigned long long q0 = (e0 < s1) ? __builtin_nontemporal_load(epk + e0) : 0ull;
        unsigned long long q1 = (e1 < s1) ? __builtin_nontemporal_load(epk + e1) : 0ull;
        unsigned long long q2 = (e2 < s1) ? __builtin_nontemporal_load(epk + e2) : 0ull;
        unsigned long long q3 = (e3 < s1) ? __builtin_nontemporal_load(epk + e3) : 0ull;
        int i0 = (int)(unsigned)q0, i1 = (int)(unsigned)q1;
        int i2 = (int)(unsigned)q2, i3 = (int)(unsigned)q3;
        float4 hv0 = *(const float4*)(hmat + (size_t)i0 * 64 + fb);
        float4 hv1 = *(const float4*)(hmat + (size_t)i1 * 64 + fb);
        float4 hv2 = *(const float4*)(hmat + (size_t)i2 * 64 + fb);
        float4 hv3 = *(const float4*)(hmat + (size_t)i3 * 64 + fb);
        float w0 = (e0 < s1) ? __expf(lrelu(asrc[i0] + ad) - C) : 0.f;
        float w1 = (e1 < s1) ? __expf(lrelu(asrc[i1] + ad) - C) : 0.f;
        float w2 = (e2 < s1) ? __expf(lrelu(asrc[i2] + ad) - C) : 0.f;
        float w3 = (e3 < s1) ? __expf(lrelu(asrc[i3] + ad) - C) : 0.f;
        sden += (w0 + w1) + (w2 + w3);
        float2 a, b, c, dd;
#define ACC8(HV, W) \
        a = __half22float2(__builtin_bit_cast(__half2, HV.x)); \
        b = __half22float2(__builtin_bit_cast(__half2, HV.y)); \
        c = __half22float2(__builtin_bit_cast(__half2, HV.z)); \
        dd = __half22float2(__builtin_bit_cast(__half2, HV.w)); \
        acc[0] = fmaf(W, a.x, acc[0]);  acc[1] = fmaf(W, a.y, acc[1]); \
        acc[2] = fmaf(W, b.x, acc[2]);  acc[3] = fmaf(W, b.y, acc[3]); \
        acc[4] = fmaf(W, c.x, acc[4]);  acc[5] = fmaf(W, c.y, acc[5]); \
        acc[6] = fmaf(W, dd.x, acc[6]); acc[7] = fmaf(W, dd.y, acc[7]);
        ACC8(hv0, w0)
        ACC8(hv1, w1)
        ACC8(hv2, w2)
        ACC8(hv3, w3)
#undef ACC8
    }
#pragma unroll
    for (int j = 0; j < 8; ++j) {
        acc[j] += __shfl_xor(acc[j], 8, 64);
        acc[j] += __shfl_xor(acc[j], 16, 64);
        acc[j] += __shfl_xor(acc[j], 32, 64);
    }
#pragma unroll
    for (int off = 32; off; off >>= 1) sden += __shfl_xor(sden, off, 64);
    return sden * 0.125f;
}

// ---- fused: GAT layer1 aggregate (+relu) + layer2 linear + alpha dots ----
__global__ __launch_bounds__(256) void agg1(
    const __half* __restrict__ hlin1,
    const float* __restrict__ adst,
    const unsigned* __restrict__ row_ptr,
    const unsigned long long* __restrict__ epk,
    const float* __restrict__ As1, const float* __restrict__ c1b,
    const unsigned* __restrict__ c2w_pk,
    const float* __restrict__ a2s, const float* __restrict__ a2d,
    __half* __restrict__ hlin2, float* __restrict__ asrc2, float* __restrict__ adst2,
    float* __restrict__ blkmax)
{
    __shared__ float vbuf[4][64];
    __shared__ float wred[4];
    int lane = threadIdx.x & 63, w = threadIdx.x >> 6;
    int d = blockIdx.x * 4 + w;
    int s0 = (int)row_ptr[d], s1 = (int)row_ptr[d + 1];
    float C = lrelu(As1[0] + adst[d]);
    float acc[8];
    float den = agg8e(hlin1, epk, s0, s1, C, lane, acc);
    if ((lane >> 3) == 0) {               // slot-0 lanes hold all 64 features
        int fb = (lane & 7) << 3;
#pragma unroll
        for (int j = 0; j < 8; ++j) vbuf[w][fb + j] = acc[j];
    }
    __syncthreads();
    float inv = 1.f / (den + 1e-30f);
    int l2 = (2 * lane) & 63;
    float va = fmaxf(vbuf[w][l2] * inv + c1b[l2], 0.f);
    float vb = fmaxf(vbuf[w][l2 + 1] * inv + c1b[l2 + 1], 0.f);
    unsigned vpk = pkh2(va, vb);
    float hl = 0.f;
#pragma unroll 8
    for (int kk = 0; kk < 32; ++kk)
        hl = fdot2u((unsigned)rli((int)vpk, kk), c2w_pk[kk * 64 + lane], hl);
    hlin2[(size_t)d * 64 + lane] = __float2half(hl);
    float ps = hl * a2s[lane], pd = hl * a2d[lane];
#pragma unroll
    for (int off = 32; off; off >>= 1) {
        ps += __shfl_xor(ps, off, 64);
        pd += __shfl_xor(pd, off, 64);
    }
    if (lane == 0) { asrc2[d] = ps; adst2[d] = pd; wred[w] = ps; }
    __syncthreads();
    if (threadIdx.x == 0)
        blkmax[blockIdx.x] = fmaxf(fmaxf(wred[0], wred[1]), fmaxf(wred[2], wred[3]));
}

// ---- fused: GAT layer2 aggregate (inline logits) + bias + pooled atomics ----
__global__ __launch_bounds__(256) void agg2_pool(
    const __half* __restrict__ hlin2,
    const float* __restrict__ asrc2, const float* __restrict__ adst2,
    const unsigned* __restrict__ row_ptr,
    const unsigned long long* __restrict__ epk,
    const float* __restrict__ As2, const float* __restrict__ c2b,
    const int* __restrict__ batch, unsigned* __restrict__ g_enc)
{
    __shared__ float vbuf[4][64];
    __shared__ int sbat[4];
    int lane = threadIdx.x & 63, w = threadIdx.x >> 6;
    int d = blockIdx.x * 4 + w;
    int s0 = (int)row_ptr[d], s1 = (int)row_ptr[d + 1];
    float ad = adst2[d];
    float C = lrelu(As2[0] + ad);
    float acc[8];
    float den = agg8i(hlin2, epk, asrc2, s0, s1, ad, C, lane, acc);
    if ((lane >> 3) == 0) {
        int fb = (lane & 7) << 3;
#pragma unroll
        for (int j = 0; j < 8; ++j) vbuf[w][fb + j] = acc[j];
    }
    __syncthreads();
    float v = vbuf[w][lane] / (den + 1e-30f) + c2b[lane];   // no relu
    vbuf[w][lane] = v;                     // own slot: race-free write-back
    if (lane == 0) sbat[w] = batch[d];
    __syncthreads();
    int b0 = sbat[0];
    bool same = (sbat[1] == b0) & (sbat[2] == b0) & (sbat[3] == b0);
    if (same) {
        // common case (batch sorted): 64 atomics per block instead of 256
        if (w == 0) {
            float m = fmaxf(fmaxf(vbuf[0][lane], vbuf[1][lane]),
                            fmaxf(vbuf[2][lane], vbuf[3][lane]));
            atomicMax(&g_enc[b0 * 64 + lane], fenc(m));
        }
    } else {
        atomicMax(&g_enc[sbat[w] * 64 + lane], fenc(v));
    }
}

// ---- readout MLP: wave per graph ----
__global__ __launch_bounds__(256) void readout(
    const unsigned* __restrict__ g_enc,
    const float* __restrict__ fc1w, const float* __restrict__ fc1b,
    const float* __restrict__ fc2w, const float* __restrict__ fc2b,
    float* __restrict__ out)
{
    int lane = threadIdx.x & 63;
    int gi = blockIdx.x * 4 + (threadIdx.x >> 6);
    float gv = fdec(g_enc[gi * 64 + lane]);
    float a = fc1b[lane];
#pragma unroll 8
    for (int k = 0; k < 64; ++k)
        a = fmaf(rlf(gv, k), fc1w[k * 64 + lane], a);
    a = fmaxf(a, 0.f) * fc2w[lane];
#pragma unroll
    for (int off = 32; off; off >>= 1) a += __shfl_xor(a, off, 64);
    if (lane == 0) out[gi] = a + fc2b[0];
}

extern "C" void kernel_launch(void* const* d_in, const int* in_sizes, int n_in,
                              void* d_out, int out_size, void* d_ws, size_t ws_size,
                              hipStream_t stream)
{
    const float* x      = (const float*)d_in[0];
    const int*   ei     = (const int*)d_in[1];
    // d_in[2] edge_attr: dead value in reference, never read
    const int*   batch  = (const int*)d_in[3];
    const float* n_w1   = (const float*)d_in[4];
    const float* n_b1   = (const float*)d_in[5];
    const float* n_w2   = (const float*)d_in[6];
    const float* n_b2   = (const float*)d_in[7];
    // d_in[8..11] edge MLP weights: dead
    const float* c1_w    = (const float*)d_in[12];
    const float* c1_asrc = (const float*)d_in[13];
    const float* c1_adst = (const float*)d_in[14];
    const float* c1_b    = (const float*)d_in[15];
    const float* c2_w    = (const float*)d_in[16];
    const float* c2_asrc = (const float*)d_in[17];
    const float* c2_adst = (const float*)d_in[18];
    const float* c2_b    = (const float*)d_in[19];
    const float* fc1_w   = (const float*)d_in[20];
    const float* fc1_b   = (const float*)d_in[21];
    const float* fc2_w   = (const float*)d_in[22];
    const float* fc2_b   = (const float*)d_in[23];
    float* out = (float*)d_out;

    // workspace carve (256B aligned)
    char* ws = (char*)d_ws;
    size_t off = 0;
    auto alloc = [&](size_t bytes) -> void* {
        off = (off + 255) & ~(size_t)255;
        void* p = ws + off;
        off += bytes;
        return p;
    };
    unsigned* sub_tail = (unsigned*)alloc(sizeof(unsigned) * NSUB);
    unsigned* sub_buf  = (unsigned*)alloc(sizeof(unsigned) * (size_t)NSUB * SUB_CAP);
    unsigned* row_ptr  = (unsigned*)alloc(sizeof(unsigned) * (N_NODES + 1));
    unsigned long long* epk =
        (unsigned long long*)alloc(sizeof(unsigned long long) * E_TOT);
    __half*   hlin1    = (__half*)alloc(sizeof(__half) * (size_t)N_NODES * 64);
    __half*   hlin2    = (__half*)alloc(sizeof(__half) * (size_t)N_NODES * 64);
    float*    asrc1    = (float*)alloc(sizeof(float) * N_NODES);
    float*    adst1    = (float*)alloc(sizeof(float) * N_NODES);
    float*    asrc2    = (float*)alloc(sizeof(float) * N_NODES);
    float*    adst2    = (float*)alloc(sizeof(float) * N_NODES);
    unsigned* g_enc    = (unsigned*)alloc(sizeof(unsigned) * N_GRAPHS * HIDDEN);
    unsigned* nw1_pk   = (unsigned*)alloc(sizeof(unsigned) * 64 * 64);
    unsigned* w2c1_pk  = (unsigned*)alloc(sizeof(unsigned) * 32 * 64);
    unsigned* c2w_pk   = (unsigned*)alloc(sizeof(unsigned) * 32 * 64);
    float*    b2c1     = (float*)alloc(sizeof(float) * 64);
    float*    blkmax1  = (float*)alloc(sizeof(float) * EMB_B);
    float*    blkmax2  = (float*)alloc(sizeof(float) * AGG_B);
    float*    As1      = (float*)alloc(sizeof(float) * 2);
    float*    As2      = (float*)alloc(sizeof(float) * 2);

    fold_w<<<1, 256, 0, stream>>>(n_w1, n_w2, n_b2, c1_w, c2_w,
                                  nw1_pk, w2c1_pk, c2w_pk, b2c1, g_enc, sub_tail);

    // bucket (640 blocks, overlaps embed) + embed (3125 blocks)
    embed_bucket<<<BUCKET_B + EMB_B, 256, 0, stream>>>(
        x, nw1_pk, n_b1, w2c1_pk, b2c1, c1_asrc, c1_adst,
        hlin1, asrc1, adst1, blkmax1,
        ei, sub_tail, sub_buf);

    // CSR build -> packed (src, el1) records + As1 reduce (1024 thr/block)
    csr_as1<<<NSUB + 1, 1024, 0, stream>>>(
        sub_buf, sub_tail, asrc1, adst1, row_ptr, epk, blkmax1, As1);

    agg1<<<AGG_B, 256, 0, stream>>>(
        hlin1, adst1, row_ptr, epk, As1,
        c1_b, c2w_pk, c2_asrc, c2_adst, hlin2, asrc2, adst2, blkmax2);

    // As2 reduce
    reduce_max<<<1, 1024, 0, stream>>>(blkmax2, AGG_B, As2);

    // layer-2 agg with inline logits (asrc2 is 200KB, L2-resident)
    agg2_pool<<<AGG_B, 256, 0, stream>>>(
        hlin2, asrc2, adst2, row_ptr, epk, As2, c2_b, batch, g_enc);
    readout<<<N_GRAPHS / 4, 256, 0, stream>>>(g_enc, fc1_w, fc1_b, fc2_w, fc2_b, out);
}

// Round 25
// 213.652 us; speedup vs baseline: 1.2208x; 1.0035x over previous
//
#include <hip/hip_runtime.h>
#include <hip/hip_fp16.h>
#include <math.h>

#define N_NODES   50000
#define N_EDGES   1600000
#define E_TOT     (N_EDGES + N_NODES)
#define N_FEAT    128
#define HIDDEN    64
#define N_GRAPHS  128
#define NEG_SLOPE 0.2f
#define NSUB      256                      // sub-buckets over dst space
#define SUB_NODES 196                      // nodes per sub
#define SUB_CAP   8192                     // per-sub global capacity (mean 6250)
#define BUCKET_B  640
#define BCHUNK    2500                     // N_EDGES / BUCKET_B
#define SB_CAP2   17                       // LDS cap/sub (19.5KB -> 8 blocks/CU)
#define EMB_B     ((N_NODES + 15) / 16)    // 3125 embed blocks (4 nodes/wave)
#define AGG_B     (N_NODES / 4)            // agg blocks (1 dst/wave)

// ---- monotone float<->uint encoding for atomicMax on floats ----
__device__ __forceinline__ unsigned fenc(float f) {
    unsigned u = __float_as_uint(f);
    return (u & 0x80000000u) ? ~u : (u | 0x80000000u);
}
__device__ __forceinline__ float fdec(unsigned k) {
    unsigned u = (k & 0x80000000u) ? (k & 0x7FFFFFFFu) : ~k;
    return __uint_as_float(u);
}
__device__ __forceinline__ float lrelu(float e) {
    return (e >= 0.f) ? e : NEG_SLOPE * e;
}
__device__ __forceinline__ int rli(int v, int l) {
    return __builtin_amdgcn_readlane(v, l);
}
__device__ __forceinline__ float rlf(float v, int l) {
    return __int_as_float(__builtin_amdgcn_readlane(__float_as_int(v), l));
}
// ---- fp16-pair pack + v_dot2_f32_f16 (fp16 mul, fp32 accumulate) ----
typedef _Float16 h2v __attribute__((ext_vector_type(2)));
__device__ __forceinline__ unsigned pkh2(float a, float b) {
    h2v v; v.x = (_Float16)a; v.y = (_Float16)b;
    return __builtin_bit_cast(unsigned, v);
}
__device__ __forceinline__ float fdot2u(unsigned a, unsigned b, float c) {
    return __builtin_amdgcn_fdot2(__builtin_bit_cast(h2v, a),
                                  __builtin_bit_cast(h2v, b), c, false);
}
// ---- packed edge record: low32 = src, high32 = el bits ----
__device__ __forceinline__ unsigned long long pke(int src, float el) {
    return ((unsigned long long)(unsigned)__float_as_int(el) << 32) |
           (unsigned long long)(unsigned)src;
}

// ---- fold: W2C1=w2@c1w; pack nw1, w2c1, c2w; init g_enc + sub_tail ----
__global__ __launch_bounds__(256) void fold_w(
    const float* __restrict__ nw1,
    const float* __restrict__ w2, const float* __restrict__ b2,
    const float* __restrict__ c1w, const float* __restrict__ c2w,
    unsigned* __restrict__ nw1_pk, unsigned* __restrict__ w2c1_pk,
    unsigned* __restrict__ c2w_pk,
    float* __restrict__ b2c1, unsigned* __restrict__ g_enc,
    unsigned* __restrict__ sub_tail)
{
    __shared__ float c1s[4096];
    __shared__ float w2c1s[4096];
    int tid = threadIdx.x;
    for (int i = tid; i < 4096; i += 256) c1s[i] = c1w[i];
    for (int i = tid; i < N_GRAPHS * HIDDEN; i += 256) g_enc[i] = fenc(-INFINITY);
    sub_tail[tid] = 0u;
    __syncthreads();
    int j = tid & 63, i0 = tid >> 6;
    for (int ii = 0; ii < 16; ++ii) {
        int i = i0 * 16 + ii;
        float a = 0.f;
#pragma unroll 8
        for (int k = 0; k < 64; ++k) a = fmaf(w2[i * 64 + k], c1s[k * 64 + j], a);
        w2c1s[i * 64 + j] = a;
    }
    if (tid < 64) {
        float a = 0.f;
#pragma unroll 8
        for (int k = 0; k < 64; ++k) a = fmaf(b2[k], c1s[k * 64 + tid], a);
        b2c1[tid] = a;
    }
    __syncthreads();
    for (int idx = tid; idx < 64 * 64; idx += 256) {
        int kk = idx >> 6, jj = idx & 63;
        nw1_pk[idx] = pkh2(nw1[(2 * kk) * 64 + jj], nw1[(2 * kk + 1) * 64 + jj]);
    }
    for (int idx = tid; idx < 32 * 64; idx += 256) {
        int kk = idx >> 6, jj = idx & 63;
        w2c1_pk[idx] = pkh2(w2c1s[(2 * kk) * 64 + jj], w2c1s[(2 * kk + 1) * 64 + jj]);
        c2w_pk[idx]  = pkh2(c2w[(2 * kk) * 64 + jj],  c2w[(2 * kk + 1) * 64 + jj]);
    }
}

// ---- FUSED: bucket blocks [0,BUCKET_B) + embed blocks [BUCKET_B, +EMB_B) ----
__global__ __launch_bounds__(256) void embed_bucket(
    const float* __restrict__ x,
    const unsigned* __restrict__ nw1_pk, const float* __restrict__ n_b1,
    const unsigned* __restrict__ w2c1_pk, const float* __restrict__ b2c1,
    const float* __restrict__ a1s, const float* __restrict__ a1d,
    __half* __restrict__ hlin,
    float* __restrict__ asrc, float* __restrict__ adst,
    float* __restrict__ blkmax,
    const int* __restrict__ ei,
    unsigned* __restrict__ sub_tail, unsigned* __restrict__ sub_buf)
{
    __shared__ unsigned st[NSUB][SB_CAP2];    // 17.4 KB, odd stride: conflict-free
    __shared__ unsigned scnt[NSUB];
    __shared__ unsigned sbase[NSUB];
    __shared__ float wred[4];
    int tid = threadIdx.x;
    int lane = tid & 63, wid = tid >> 6;

    if (blockIdx.x < BUCKET_B) {
        // ---------- bucket path ----------
        scnt[tid] = 0u;
        __syncthreads();
        int beg = blockIdx.x * BCHUNK;
        int end = min(beg + BCHUNK, N_EDGES);
        for (int base = beg; base < end; base += 256) {
            int e = base + tid;
            if (e < end) {
                unsigned src = (unsigned)__builtin_nontemporal_load(ei + e);
                unsigned dst = (unsigned)__builtin_nontemporal_load(ei + N_EDGES + e);
                unsigned sub = dst / SUB_NODES;
                unsigned pay = ((dst - sub * SUB_NODES) << 16) | src;
                unsigned p = atomicAdd(&scnt[sub], 1u);
                if (p < SB_CAP2) st[sub][p] = pay;
                else {                           // ~1% overflow: direct write
                    unsigned gp = atomicAdd(&sub_tail[sub], 1u);
                    if (gp < SUB_CAP)
                        __builtin_nontemporal_store(pay, sub_buf + (size_t)sub * SUB_CAP + gp);
                }
            }
        }
        __syncthreads();
        unsigned c = min(scnt[tid], (unsigned)SB_CAP2);
        scnt[tid] = c;
        sbase[tid] = atomicAdd(&sub_tail[tid], c);
        __syncthreads();
        // wave-coalesced flush: wave handles subs wid, wid+4, ...; lanes 0..c-1
        for (int o = wid; o < NSUB; o += 4) {
            unsigned c_o = scnt[o];
            if ((unsigned)lane < c_o) {
                unsigned pos = sbase[o] + lane;
                if (pos < SUB_CAP)
                    __builtin_nontemporal_store(st[o][lane],
                        sub_buf + (size_t)o * SUB_CAP + pos);
            }
        }
    } else {
        // ---------- embed path: MLP + folded linear via packed dot2 ----------
        int eb = blockIdx.x - BUCKET_B;
        int n0 = eb * 16 + wid * 4;          // 4 nodes per wave
        if (n0 < N_NODES) {
            unsigned xpk[4];
#pragma unroll
            for (int nn = 0; nn < 4; ++nn) {
                float2 v = ((const float2*)(x + (size_t)(n0 + nn) * N_FEAT))[lane];
                xpk[nn] = pkh2(v.x, v.y);
            }
            float acc[4];
            float b1v = n_b1[lane];
#pragma unroll
            for (int nn = 0; nn < 4; ++nn) acc[nn] = b1v;
#pragma unroll 4
            for (int kk = 0; kk < 64; ++kk) {
                unsigned wp = nw1_pk[kk * 64 + lane];
#pragma unroll
                for (int nn = 0; nn < 4; ++nn)
                    acc[nn] = fdot2u((unsigned)rli((int)xpk[nn], kk), wp, acc[nn]);
            }
#pragma unroll
            for (int nn = 0; nn < 4; ++nn) acc[nn] = fmaxf(acc[nn], 0.f);
            unsigned hpk[4];
#pragma unroll
            for (int nn = 0; nn < 4; ++nn) {
                float ha = __shfl(acc[nn], (2 * lane) & 63, 64);
                float hb = __shfl(acc[nn], (2 * lane + 1) & 63, 64);
                hpk[nn] = pkh2(ha, hb);
            }
            float hl[4];
            float bcv = b2c1[lane];
#pragma unroll
            for (int nn = 0; nn < 4; ++nn) hl[nn] = bcv;
#pragma unroll 4
            for (int kk = 0; kk < 32; ++kk) {
                unsigned wp = w2c1_pk[kk * 64 + lane];
#pragma unroll
                for (int nn = 0; nn < 4; ++nn)
                    hl[nn] = fdot2u((unsigned)rli((int)hpk[nn], kk), wp, hl[nn]);
            }
            float s1v = a1s[lane], d1v = a1d[lane];
            float wmax = -INFINITY;
#pragma unroll
            for (int nn = 0; nn < 4; ++nn) {
                int n = n0 + nn;
                hlin[(size_t)n * 64 + lane] = __float2half(hl[nn]);
                float ps = hl[nn] * s1v, pd = hl[nn] * d1v;
#pragma unroll
                for (int off = 32; off; off >>= 1) {
                    ps += __shfl_xor(ps, off, 64);
                    pd += __shfl_xor(pd, off, 64);
                }
                if (lane == 0) { asrc[n] = ps; adst[n] = pd; wmax = fmaxf(wmax, ps); }
            }
            if (lane == 0) wred[wid] = wmax;
        } else if (lane == 0) wred[wid] = -INFINITY;
        __syncthreads();
        if (tid == 0)
            blkmax[eb] = fmaxf(fmaxf(wred[0], wred[1]), fmaxf(wred[2], wred[3]));
    }
}

// ---- CSR build: 1024 threads/block; zero global atomics -> epk + As1 ----
__global__ __launch_bounds__(1024) void csr_as1(
    const unsigned* __restrict__ sub_buf, const unsigned* __restrict__ sub_tail,
    const float* __restrict__ asrc1, const float* __restrict__ adst1,
    unsigned* __restrict__ row_ptr, unsigned long long* __restrict__ epk,
    const float* __restrict__ blkmax1, float* __restrict__ As1)
{
    __shared__ unsigned hist[SUB_NODES];
    __shared__ unsigned wt4[4], wo4[4];
    __shared__ unsigned eb_s[2];
    __shared__ unsigned tot_s;
    __shared__ float wm[16];
    int tid = threadIdx.x, lane = tid & 63, wid = tid >> 6;

    if (blockIdx.x == NSUB) {              // As1 reduction block
        float m = -INFINITY;
        for (int i = tid; i < EMB_B; i += 1024) m = fmaxf(m, blkmax1[i]);
#pragma unroll
        for (int off = 32; off; off >>= 1) m = fmaxf(m, __shfl_xor(m, off, 64));
        if (lane == 0) wm[wid] = m;
        __syncthreads();
        if (tid == 0) {
            float r = -INFINITY;
            for (int w = 0; w < 16; ++w) r = fmaxf(r, wm[w]);
            As1[0] = r;
        }
        return;
    }
    int gs = blockIdx.x;                   // 0..255
    unsigned myc = 0u, v = 0u;
    if (tid < NSUB) {
        myc = min(sub_tail[tid], (unsigned)SUB_CAP);
        unsigned nn_t = (tid < NSUB - 1) ? SUB_NODES
                                         : (N_NODES - (NSUB - 1) * SUB_NODES);
        v = myc + nn_t;
    }
    unsigned xs = v;
#pragma unroll
    for (int off = 1; off < 64; off <<= 1) {
        unsigned t = __shfl_up(xs, off, 64);
        if (lane >= off) xs += t;
    }
    if (lane == 63 && wid < 4) wt4[wid] = xs;
    __syncthreads();
    if (tid == 0) {
        unsigned run = 0;
        for (int w = 0; w < 4; ++w) { wo4[w] = run; run += wt4[w]; }
        tot_s = run;
    }
    __syncthreads();
    if (tid == gs) { eb_s[0] = wo4[wid] + xs - v; eb_s[1] = myc; }
    if (gs == 0 && tid == 0) row_ptr[N_NODES] = tot_s;
    __syncthreads();
    unsigned ebase = eb_s[0], cnt = eb_s[1];
    int node_lo = gs * SUB_NODES;
    int nn = (gs < NSUB - 1) ? SUB_NODES : (N_NODES - (NSUB - 1) * SUB_NODES);
    for (int i = tid; i < nn; i += 1024) hist[i] = 1u;
    __syncthreads();
    const unsigned* seg = sub_buf + (size_t)gs * SUB_CAP;
    for (unsigned i = tid; i < cnt; i += 1024)
        atomicAdd(&hist[__builtin_nontemporal_load(seg + i) >> 16], 1u);
    __syncthreads();
    unsigned v2 = (tid < nn) ? hist[tid] : 0u;
    unsigned xs2 = v2;
#pragma unroll
    for (int off = 1; off < 64; off <<= 1) {
        unsigned t = __shfl_up(xs2, off, 64);
        if (lane >= off) xs2 += t;
    }
    __syncthreads();
    if (lane == 63 && wid < 4) wt4[wid] = xs2;
    __syncthreads();
    if (tid == 0) {
        unsigned run = 0;
        for (int w = 0; w < 4; ++w) { wo4[w] = run; run += wt4[w]; }
    }
    __syncthreads();
    if (tid < nn) {
        unsigned ex2 = wo4[wid] + xs2 - v2;
        unsigned rp = ebase + ex2;
        int n = node_lo + tid;
        row_ptr[n] = rp;
        epk[rp] = pke(n, lrelu(asrc1[n] + adst1[n]));   // self-loop first slot
        hist[tid] = ex2 + 1u;
    }
    __syncthreads();
    for (unsigned i = tid; i < cnt; i += 1024) {
        unsigned pay = __builtin_nontemporal_load(seg + i);
        unsigned dl = pay >> 16;
        int src = (int)(pay & 0xffffu);
        unsigned p = atomicAdd(&hist[dl], 1u);
        epk[ebase + p] = pke(src, lrelu(asrc1[src] + adst1[node_lo + (int)dl]));
    }
}

// ---- 1-block max-reduce ----
__global__ __launch_bounds__(1024) void reduce_max(
    const float* __restrict__ in, int n, float* __restrict__ As)
{
    __shared__ float wm[16];
    int tid = threadIdx.x, lane = tid & 63, wid = tid >> 6;
    float m = -INFINITY;
    for (int i = tid; i < n; i += 1024) m = fmaxf(m, in[i]);
#pragma unroll
    for (int off = 32; off; off >>= 1) m = fmaxf(m, __shfl_xor(m, off, 64));
    if (lane == 0) wm[wid] = m;
    __syncthreads();
    if (tid == 0) {
        float r = -INFINITY;
        for (int w = 0; w < 16; ++w) r = fmaxf(r, wm[w]);
        As[0] = r;
    }
}

// ---- agg core (packed el): 8 lanes/edge, U=6 burst (48 edges/round) ----
// deg = Poisson(32)+1 -> 99.5% of rows complete in ONE memory round.
__device__ __forceinline__ float agg8e(
    const __half* __restrict__ hmat,      // [N][64] fp16 (128B rows)
    const unsigned long long* __restrict__ epk,
    int s0, int s1, float C, int lane, float acc[8])
{
    int slot = lane >> 3;
    int fb = (lane & 7) << 3;
    float sden = 0.f;
#pragma unroll
    for (int j = 0; j < 8; ++j) acc[j] = 0.f;
    for (int base = s0; base < s1; base += 48) {
        int e0 = base + slot,  e1 = e0 + 8,  e2 = e0 + 16;
        int e3 = e0 + 24,      e4 = e0 + 32, e5 = e0 + 40;
        unsigned long long q0 = (e0 < s1) ? __builtin_nontemporal_load(epk + e0) : 0ull;
        unsigned long long q1 = (e1 < s1) ? __builtin_nontemporal_load(epk + e1) : 0ull;
        unsigned long long q2 = (e2 < s1) ? __builtin_nontemporal_load(epk + e2) : 0ull;
        unsigned long long q3 = (e3 < s1) ? __builtin_nontemporal_load(epk + e3) : 0ull;
        unsigned long long q4 = (e4 < s1) ? __builtin_nontemporal_load(epk + e4) : 0ull;
        unsigned long long q5 = (e5 < s1) ? __builtin_nontemporal_load(epk + e5) : 0ull;
        int i0 = (int)(unsigned)q0, i1 = (int)(unsigned)q1;
        int i2 = (int)(unsigned)q2, i3 = (int)(unsigned)q3;
        int i4 = (int)(unsigned)q4, i5 = (int)(unsigned)q5;
        // 6 independent 16B row loads (dep: idx only; issue before exp chain)
        float4 hv0 = *(const float4*)(hmat + (size_t)i0 * 64 + fb);
        float4 hv1 = *(const float4*)(hmat + (size_t)i1 * 64 + fb);
        float4 hv2 = *(const float4*)(hmat + (size_t)i2 * 64 + fb);
        float4 hv3 = *(const float4*)(hmat + (size_t)i3 * 64 + fb);
        float4 hv4 = *(const float4*)(hmat + (size_t)i4 * 64 + fb);
        float4 hv5 = *(const float4*)(hmat + (size_t)i5 * 64 + fb);
        float w0 = (e0 < s1) ? __expf(__int_as_float((int)(q0 >> 32)) - C) : 0.f;
        float w1 = (e1 < s1) ? __expf(__int_as_float((int)(q1 >> 32)) - C) : 0.f;
        float w2 = (e2 < s1) ? __expf(__int_as_float((int)(q2 >> 32)) - C) : 0.f;
        float w3 = (e3 < s1) ? __expf(__int_as_float((int)(q3 >> 32)) - C) : 0.f;
        float w4 = (e4 < s1) ? __expf(__int_as_float((int)(q4 >> 32)) - C) : 0.f;
        float w5 = (e5 < s1) ? __expf(__int_as_float((int)(q5 >> 32)) - C) : 0.f;
        sden += ((w0 + w1) + (w2 + w3)) + (w4 + w5);
        float2 a, b, c, dd;
#define ACC8(HV, W) \
        a = __half22float2(__builtin_bit_cast(__half2, HV.x)); \
        b = __half22float2(__builtin_bit_cast(__half2, HV.y)); \
        c = __half22float2(__builtin_bit_cast(__half2, HV.z)); \
        dd = __half22float2(__builtin_bit_cast(__half2, HV.w)); \
        acc[0] = fmaf(W, a.x, acc[0]);  acc[1] = fmaf(W, a.y, acc[1]); \
        acc[2] = fmaf(W, b.x, acc[2]);  acc[3] = fmaf(W, b.y, acc[3]); \
        acc[4] = fmaf(W, c.x, acc[4]);  acc[5] = fmaf(W, c.y, acc[5]); \
        acc[6] = fmaf(W, dd.x, acc[6]); acc[7] = fmaf(W, dd.y, acc[7]);
        ACC8(hv0, w0)
        ACC8(hv1, w1)
        ACC8(hv2, w2)
        ACC8(hv3, w3)
        ACC8(hv4, w4)
        ACC8(hv5, w5)
#undef ACC8
    }
#pragma unroll
    for (int j = 0; j < 8; ++j) {
        acc[j] += __shfl_xor(acc[j], 8, 64);
        acc[j] += __shfl_xor(acc[j], 16, 64);
        acc[j] += __shfl_xor(acc[j], 32, 64);
    }
#pragma unroll
    for (int off = 32; off; off >>= 1) sden += __shfl_xor(sden, off, 64);
    return sden * 0.125f;
}

// ---- agg core (inline logit): src from epk low word, asrc L2-resident ----
__device__ __forceinline__ float agg8i(
    const __half* __restrict__ hmat,
    const unsigned long long* __restrict__ epk,
    const float* __restrict__ asrc,
    int s0, int s1, float ad, float C, int lane, float acc[8])
{
    int slot = lane >> 3;
    int fb = (lane & 7) << 3;
    float sden = 0.f;
#pragma unroll
    for (int j = 0; j < 8; ++j) acc[j] = 0.f;
    for (int base = s0; base < s1; base += 48) {
        int e0 = base + slot,  e1 = e0 + 8,  e2 = e0 + 16;
        int e3 = e0 + 24,      e4 = e0 + 32, e5 = e0 + 40;
        unsigned long long q0 = (e0 < s1) ? __builtin_nontemporal_load(epk + e0) : 0ull;
        unsigned long long q1 = (e1 < s1) ? __builtin_nontemporal_load(epk + e1) : 0ull;
        unsigned long long q2 = (e2 < s1) ? __builtin_nontemporal_load(epk + e2) : 0ull;
        unsigned long long q3 = (e3 < s1) ? __builtin_nontemporal_load(epk + e3) : 0ull;
        unsigned long long q4 = (e4 < s1) ? __builtin_nontemporal_load(epk + e4) : 0ull;
        unsigned long long q5 = (e5 < s1) ? __builtin_nontemporal_load(epk + e5) : 0ull;
        int i0 = (int)(unsigned)q0, i1 = (int)(unsigned)q1;
        int i2 = (int)(unsigned)q2, i3 = (int)(unsigned)q3;
        int i4 = (int)(unsigned)q4, i5 = (int)(unsigned)q5;
        float4 hv0 = *(const float4*)(hmat + (size_t)i0 * 64 + fb);
        float4 hv1 = *(const float4*)(hmat + (size_t)i1 * 64 + fb);
        float4 hv2 = *(const float4*)(hmat + (size_t)i2 * 64 + fb);
        float4 hv3 = *(const float4*)(hmat + (size_t)i3 * 64 + fb);
        float4 hv4 = *(const float4*)(hmat + (size_t)i4 * 64 + fb);
        float4 hv5 = *(const float4*)(hmat + (size_t)i5 * 64 + fb);
        float w0 = (e0 < s1) ? __expf(lrelu(asrc[i0] + ad) - C) : 0.f;
        float w1 = (e1 < s1) ? __expf(lrelu(asrc[i1] + ad) - C) : 0.f;
        float w2 = (e2 < s1) ? __expf(lrelu(asrc[i2] + ad) - C) : 0.f;
        float w3 = (e3 < s1) ? __expf(lrelu(asrc[i3] + ad) - C) : 0.f;
        float w4 = (e4 < s1) ? __expf(lrelu(asrc[i4] + ad) - C) : 0.f;
        float w5 = (e5 < s1) ? __expf(lrelu(asrc[i5] + ad) - C) : 0.f;
        sden += ((w0 + w1) + (w2 + w3)) + (w4 + w5);
        float2 a, b, c, dd;
#define ACC8(HV, W) \
        a = __half22float2(__builtin_bit_cast(__half2, HV.x)); \
        b = __half22float2(__builtin_bit_cast(__half2, HV.y)); \
        c = __half22float2(__builtin_bit_cast(__half2, HV.z)); \
        dd = __half22float2(__builtin_bit_cast(__half2, HV.w)); \
        acc[0] = fmaf(W, a.x, acc[0]);  acc[1] = fmaf(W, a.y, acc[1]); \
        acc[2] = fmaf(W, b.x, acc[2]);  acc[3] = fmaf(W, b.y, acc[3]); \
        acc[4] = fmaf(W, c.x, acc[4]);  acc[5] = fmaf(W, c.y, acc[5]); \
        acc[6] = fmaf(W, dd.x, acc[6]); acc[7] = fmaf(W, dd.y, acc[7]);
        ACC8(hv0, w0)
        ACC8(hv1, w1)
        ACC8(hv2, w2)
        ACC8(hv3, w3)
        ACC8(hv4, w4)
        ACC8(hv5, w5)
#undef ACC8
    }
#pragma unroll
    for (int j = 0; j < 8; ++j) {
        acc[j] += __shfl_xor(acc[j], 8, 64);
        acc[j] += __shfl_xor(acc[j], 16, 64);
        acc[j] += __shfl_xor(acc[j], 32, 64);
    }
#pragma unroll
    for (int off = 32; off; off >>= 1) sden += __shfl_xor(sden, off, 64);
    return sden * 0.125f;
}

// ---- fused: GAT layer1 aggregate (+relu) + layer2 linear + alpha dots ----
__global__ __launch_bounds__(256) void agg1(
    const __half* __restrict__ hlin1,
    const float* __restrict__ adst,
    const unsigned* __restrict__ row_ptr,
    const unsigned long long* __restrict__ epk,
    const float* __restrict__ As1, const float* __restrict__ c1b,
    const unsigned* __restrict__ c2w_pk,
    const float* __restrict__ a2s, const float* __restrict__ a2d,
    __half* __restrict__ hlin2, float* __restrict__ asrc2, float* __restrict__ adst2,
    float* __restrict__ blkmax)
{
    __shared__ float vbuf[4][64];
    __shared__ float wred[4];
    int lane = threadIdx.x & 63, w = threadIdx.x >> 6;
    int d = blockIdx.x * 4 + w;
    int s0 = (int)row_ptr[d], s1 = (int)row_ptr[d + 1];
    float C = lrelu(As1[0] + adst[d]);
    float acc[8];
    float den = agg8e(hlin1, epk, s0, s1, C, lane, acc);
    if ((lane >> 3) == 0) {               // slot-0 lanes hold all 64 features
        int fb = (lane & 7) << 3;
#pragma unroll
        for (int j = 0; j < 8; ++j) vbuf[w][fb + j] = acc[j];
    }
    __syncthreads();
    float inv = 1.f / (den + 1e-30f);
    int l2 = (2 * lane) & 63;
    float va = fmaxf(vbuf[w][l2] * inv + c1b[l2], 0.f);
    float vb = fmaxf(vbuf[w][l2 + 1] * inv + c1b[l2 + 1], 0.f);
    unsigned vpk = pkh2(va, vb);
    float hl = 0.f;
#pragma unroll 8
    for (int kk = 0; kk < 32; ++kk)
        hl = fdot2u((unsigned)rli((int)vpk, kk), c2w_pk[kk * 64 + lane], hl);
    hlin2[(size_t)d * 64 + lane] = __float2half(hl);
    float ps = hl * a2s[lane], pd = hl * a2d[lane];
#pragma unroll
    for (int off = 32; off; off >>= 1) {
        ps += __shfl_xor(ps, off, 64);
        pd += __shfl_xor(pd, off, 64);
    }
    if (lane == 0) { asrc2[d] = ps; adst2[d] = pd; wred[w] = ps; }
    __syncthreads();
    if (threadIdx.x == 0)
        blkmax[blockIdx.x] = fmaxf(fmaxf(wred[0], wred[1]), fmaxf(wred[2], wred[3]));
}

// ---- fused: GAT layer2 aggregate (inline logits) + bias + pooled atomics ----
__global__ __launch_bounds__(256) void agg2_pool(
    const __half* __restrict__ hlin2,
    const float* __restrict__ asrc2, const float* __restrict__ adst2,
    const unsigned* __restrict__ row_ptr,
    const unsigned long long* __restrict__ epk,
    const float* __restrict__ As2, const float* __restrict__ c2b,
    const int* __restrict__ batch, unsigned* __restrict__ g_enc)
{
    __shared__ float vbuf[4][64];
    __shared__ int sbat[4];
    int lane = threadIdx.x & 63, w = threadIdx.x >> 6;
    int d = blockIdx.x * 4 + w;
    int s0 = (int)row_ptr[d], s1 = (int)row_ptr[d + 1];
    float ad = adst2[d];
    float C = lrelu(As2[0] + ad);
    float acc[8];
    float den = agg8i(hlin2, epk, asrc2, s0, s1, ad, C, lane, acc);
    if ((lane >> 3) == 0) {
        int fb = (lane & 7) << 3;
#pragma unroll
        for (int j = 0; j < 8; ++j) vbuf[w][fb + j] = acc[j];
    }
    __syncthreads();
    float v = vbuf[w][lane] / (den + 1e-30f) + c2b[lane];   // no relu
    vbuf[w][lane] = v;                     // own slot: race-free write-back
    if (lane == 0) sbat[w] = batch[d];
    __syncthreads();
    int b0 = sbat[0];
    bool same = (sbat[1] == b0) & (sbat[2] == b0) & (sbat[3] == b0);
    if (same) {
        // common case (batch sorted): 64 atomics per block instead of 256
        if (w == 0) {
            float m = fmaxf(fmaxf(vbuf[0][lane], vbuf[1][lane]),
                            fmaxf(vbuf[2][lane], vbuf[3][lane]));
            atomicMax(&g_enc[b0 * 64 + lane], fenc(m));
        }
    } else {
        atomicMax(&g_enc[sbat[w] * 64 + lane], fenc(v));
    }
}

// ---- readout MLP: wave per graph ----
__global__ __launch_bounds__(256) void readout(
    const unsigned* __restrict__ g_enc,
    const float* __restrict__ fc1w, const float* __restrict__ fc1b,
    const float* __restrict__ fc2w, const float* __restrict__ fc2b,
    float* __restrict__ out)
{
    int lane = threadIdx.x & 63;
    int gi = blockIdx.x * 4 + (threadIdx.x >> 6);
    float gv = fdec(g_enc[gi * 64 + lane]);
    float a = fc1b[lane];
#pragma unroll 8
    for (int k = 0; k < 64; ++k)
        a = fmaf(rlf(gv, k), fc1w[k * 64 + lane], a);
    a = fmaxf(a, 0.f) * fc2w[lane];
#pragma unroll
    for (int off = 32; off; off >>= 1) a += __shfl_xor(a, off, 64);
    if (lane == 0) out[gi] = a + fc2b[0];
}

extern "C" void kernel_launch(void* const* d_in, const int* in_sizes, int n_in,
                              void* d_out, int out_size, void* d_ws, size_t ws_size,
                              hipStream_t stream)
{
    const float* x      = (const float*)d_in[0];
    const int*   ei     = (const int*)d_in[1];
    // d_in[2] edge_attr: dead value in reference, never read
    const int*   batch  = (const int*)d_in[3];
    const float* n_w1   = (const float*)d_in[4];
    const float* n_b1   = (const float*)d_in[5];
    const float* n_w2   = (const float*)d_in[6];
    const float* n_b2   = (const float*)d_in[7];
    // d_in[8..11] edge MLP weights: dead
    const float* c1_w    = (const float*)d_in[12];
    const float* c1_asrc = (const float*)d_in[13];
    const float* c1_adst = (const float*)d_in[14];
    const float* c1_b    = (const float*)d_in[15];
    const float* c2_w    = (const float*)d_in[16];
    const float* c2_asrc = (const float*)d_in[17];
    const float* c2_adst = (const float*)d_in[18];
    const float* c2_b    = (const float*)d_in[19];
    const float* fc1_w   = (const float*)d_in[20];
    const float* fc1_b   = (const float*)d_in[21];
    const float* fc2_w   = (const float*)d_in[22];
    const float* fc2_b   = (const float*)d_in[23];
    float* out = (float*)d_out;

    // workspace carve (256B aligned)
    char* ws = (char*)d_ws;
    size_t off = 0;
    auto alloc = [&](size_t bytes) -> void* {
        off = (off + 255) & ~(size_t)255;
        void* p = ws + off;
        off += bytes;
        return p;
    };
    unsigned* sub_tail = (unsigned*)alloc(sizeof(unsigned) * NSUB);
    unsigned* sub_buf  = (unsigned*)alloc(sizeof(unsigned) * (size_t)NSUB * SUB_CAP);
    unsigned* row_ptr  = (unsigned*)alloc(sizeof(unsigned) * (N_NODES + 1));
    unsigned long long* epk =
        (unsigned long long*)alloc(sizeof(unsigned long long) * E_TOT);
    __half*   hlin1    = (__half*)alloc(sizeof(__half) * (size_t)N_NODES * 64);
    __half*   hlin2    = (__half*)alloc(sizeof(__half) * (size_t)N_NODES * 64);
    float*    asrc1    = (float*)alloc(sizeof(float) * N_NODES);
    float*    adst1    = (float*)alloc(sizeof(float) * N_NODES);
    float*    asrc2    = (float*)alloc(sizeof(float) * N_NODES);
    float*    adst2    = (float*)alloc(sizeof(float) * N_NODES);
    unsigned* g_enc    = (unsigned*)alloc(sizeof(unsigned) * N_GRAPHS * HIDDEN);
    unsigned* nw1_pk   = (unsigned*)alloc(sizeof(unsigned) * 64 * 64);
    unsigned* w2c1_pk  = (unsigned*)alloc(sizeof(unsigned) * 32 * 64);
    unsigned* c2w_pk   = (unsigned*)alloc(sizeof(unsigned) * 32 * 64);
    float*    b2c1     = (float*)alloc(sizeof(float) * 64);
    float*    blkmax1  = (float*)alloc(sizeof(float) * EMB_B);
    float*    blkmax2  = (float*)alloc(sizeof(float) * AGG_B);
    float*    As1      = (float*)alloc(sizeof(float) * 2);
    float*    As2      = (float*)alloc(sizeof(float) * 2);

    fold_w<<<1, 256, 0, stream>>>(n_w1, n_w2, n_b2, c1_w, c2_w,
                                  nw1_pk, w2c1_pk, c2w_pk, b2c1, g_enc, sub_tail);

    // bucket (640 blocks, overlaps embed) + embed (3125 blocks)
    embed_bucket<<<BUCKET_B + EMB_B, 256, 0, stream>>>(
        x, nw1_pk, n_b1, w2c1_pk, b2c1, c1_asrc, c1_adst,
        hlin1, asrc1, adst1, blkmax1,
        ei, sub_tail, sub_buf);

    // CSR build -> packed (src, el1) records + As1 reduce (1024 thr/block)
    csr_as1<<<NSUB + 1, 1024, 0, stream>>>(
        sub_buf, sub_tail, asrc1, adst1, row_ptr, epk, blkmax1, As1);

    agg1<<<AGG_B, 256, 0, stream>>>(
        hlin1, adst1, row_ptr, epk, As1,
        c1_b, c2w_pk, c2_asrc, c2_adst, hlin2, asrc2, adst2, blkmax2);

    // As2 reduce
    reduce_max<<<1, 1024, 0, stream>>>(blkmax2, AGG_B, As2);

    // layer-2 agg with inline logits (asrc2 is 200KB, L2-resident)
    agg2_pool<<<AGG_B, 256, 0, stream>>>(
        hlin2, asrc2, adst2, row_ptr, epk, As2, c2_b, batch, g_enc);
    readout<<<N_GRAPHS / 4, 256, 0, stream>>>(g_enc, fc1_w, fc1_b, fc2_w, fc2_b, out);
}

// Round 26
// 213.325 us; speedup vs baseline: 1.2227x; 1.0015x over previous
//
#include <hip/hip_runtime.h>
#include <hip/hip_fp16.h>
#include <math.h>

#define N_NODES   50000
#define N_EDGES   1600000
#define E_TOT     (N_EDGES + N_NODES)
#define N_FEAT    128
#define HIDDEN    64
#define N_GRAPHS  128
#define NEG_SLOPE 0.2f
#define NSUB      256                      // sub-buckets over dst space
#define SUB_NODES 196                      // nodes per sub
#define SUB_CAP   8192                     // per-sub global capacity (mean 6250)
#define BUCKET_B  640
#define BCHUNK    2500                     // N_EDGES / BUCKET_B
#define SB_CAP2   17                       // LDS cap/sub (19.5KB -> 8 blocks/CU)
#define EMB_B     ((N_NODES + 15) / 16)    // 3125 embed blocks (4 nodes/wave)
#define AGG_B     (N_NODES / 4)            // agg blocks (1 dst/wave)

// ---- monotone float<->uint encoding for atomicMax on floats ----
__device__ __forceinline__ unsigned fenc(float f) {
    unsigned u = __float_as_uint(f);
    return (u & 0x80000000u) ? ~u : (u | 0x80000000u);
}
__device__ __forceinline__ float fdec(unsigned k) {
    unsigned u = (k & 0x80000000u) ? (k & 0x7FFFFFFFu) : ~k;
    return __uint_as_float(u);
}
__device__ __forceinline__ float lrelu(float e) {
    return (e >= 0.f) ? e : NEG_SLOPE * e;
}
__device__ __forceinline__ int rli(int v, int l) {
    return __builtin_amdgcn_readlane(v, l);
}
__device__ __forceinline__ float rlf(float v, int l) {
    return __int_as_float(__builtin_amdgcn_readlane(__float_as_int(v), l));
}
// ---- fp16-pair pack + v_dot2_f32_f16 (fp16 mul, fp32 accumulate) ----
typedef _Float16 h2v __attribute__((ext_vector_type(2)));
__device__ __forceinline__ unsigned pkh2(float a, float b) {
    h2v v; v.x = (_Float16)a; v.y = (_Float16)b;
    return __builtin_bit_cast(unsigned, v);
}
__device__ __forceinline__ float fdot2u(unsigned a, unsigned b, float c) {
    return __builtin_amdgcn_fdot2(__builtin_bit_cast(h2v, a),
                                  __builtin_bit_cast(h2v, b), c, false);
}
// ---- packed edge record: low32 = src, high32 = el bits ----
__device__ __forceinline__ unsigned long long pke(int src, float el) {
    return ((unsigned long long)(unsigned)__float_as_int(el) << 32) |
           (unsigned long long)(unsigned)src;
}

// ---- fold: W2C1=w2@c1w; pack nw1, w2c1, c2w; init g_enc + sub_tail ----
__global__ __launch_bounds__(256) void fold_w(
    const float* __restrict__ nw1,
    const float* __restrict__ w2, const float* __restrict__ b2,
    const float* __restrict__ c1w, const float* __restrict__ c2w,
    unsigned* __restrict__ nw1_pk, unsigned* __restrict__ w2c1_pk,
    unsigned* __restrict__ c2w_pk,
    float* __restrict__ b2c1, unsigned* __restrict__ g_enc,
    unsigned* __restrict__ sub_tail)
{
    __shared__ float c1s[4096];
    __shared__ float w2c1s[4096];
    int tid = threadIdx.x;
    for (int i = tid; i < 4096; i += 256) c1s[i] = c1w[i];
    for (int i = tid; i < N_GRAPHS * HIDDEN; i += 256) g_enc[i] = fenc(-INFINITY);
    sub_tail[tid] = 0u;
    __syncthreads();
    int j = tid & 63, i0 = tid >> 6;
    for (int ii = 0; ii < 16; ++ii) {
        int i = i0 * 16 + ii;
        float a = 0.f;
#pragma unroll 8
        for (int k = 0; k < 64; ++k) a = fmaf(w2[i * 64 + k], c1s[k * 64 + j], a);
        w2c1s[i * 64 + j] = a;
    }
    if (tid < 64) {
        float a = 0.f;
#pragma unroll 8
        for (int k = 0; k < 64; ++k) a = fmaf(b2[k], c1s[k * 64 + tid], a);
        b2c1[tid] = a;
    }
    __syncthreads();
    for (int idx = tid; idx < 64 * 64; idx += 256) {
        int kk = idx >> 6, jj = idx & 63;
        nw1_pk[idx] = pkh2(nw1[(2 * kk) * 64 + jj], nw1[(2 * kk + 1) * 64 + jj]);
    }
    for (int idx = tid; idx < 32 * 64; idx += 256) {
        int kk = idx >> 6, jj = idx & 63;
        w2c1_pk[idx] = pkh2(w2c1s[(2 * kk) * 64 + jj], w2c1s[(2 * kk + 1) * 64 + jj]);
        c2w_pk[idx]  = pkh2(c2w[(2 * kk) * 64 + jj],  c2w[(2 * kk + 1) * 64 + jj]);
    }
}

// ---- FUSED: bucket blocks [0,BUCKET_B) + embed blocks [BUCKET_B, +EMB_B) ----
__global__ __launch_bounds__(256) void embed_bucket(
    const float* __restrict__ x,
    const unsigned* __restrict__ nw1_pk, const float* __restrict__ n_b1,
    const unsigned* __restrict__ w2c1_pk, const float* __restrict__ b2c1,
    const float* __restrict__ a1s, const float* __restrict__ a1d,
    __half* __restrict__ hlin,
    float* __restrict__ asrc, float* __restrict__ adst,
    float* __restrict__ blkmax,
    const int* __restrict__ ei,
    unsigned* __restrict__ sub_tail, unsigned* __restrict__ sub_buf)
{
    __shared__ unsigned st[NSUB][SB_CAP2];    // 17.4 KB, odd stride: conflict-free
    __shared__ unsigned scnt[NSUB];
    __shared__ unsigned sbase[NSUB];
    __shared__ float wred[4];
    int tid = threadIdx.x;
    int lane = tid & 63, wid = tid >> 6;

    if (blockIdx.x < BUCKET_B) {
        // ---------- bucket path ----------
        scnt[tid] = 0u;
        __syncthreads();
        int beg = blockIdx.x * BCHUNK;
        int end = min(beg + BCHUNK, N_EDGES);
        for (int base = beg; base < end; base += 256) {
            int e = base + tid;
            if (e < end) {
                unsigned src = (unsigned)__builtin_nontemporal_load(ei + e);
                unsigned dst = (unsigned)__builtin_nontemporal_load(ei + N_EDGES + e);
                unsigned sub = dst / SUB_NODES;
                unsigned pay = ((dst - sub * SUB_NODES) << 16) | src;
                unsigned p = atomicAdd(&scnt[sub], 1u);
                if (p < SB_CAP2) st[sub][p] = pay;
                else {                           // ~1% overflow: direct write
                    unsigned gp = atomicAdd(&sub_tail[sub], 1u);
                    if (gp < SUB_CAP)
                        __builtin_nontemporal_store(pay, sub_buf + (size_t)sub * SUB_CAP + gp);
                }
            }
        }
        __syncthreads();
        unsigned c = min(scnt[tid], (unsigned)SB_CAP2);
        scnt[tid] = c;
        sbase[tid] = atomicAdd(&sub_tail[tid], c);
        __syncthreads();
        // wave-coalesced flush: wave handles subs wid, wid+4, ...; lanes 0..c-1
        for (int o = wid; o < NSUB; o += 4) {
            unsigned c_o = scnt[o];
            if ((unsigned)lane < c_o) {
                unsigned pos = sbase[o] + lane;
                if (pos < SUB_CAP)
                    __builtin_nontemporal_store(st[o][lane],
                        sub_buf + (size_t)o * SUB_CAP + pos);
            }
        }
    } else {
        // ---------- embed path: MLP + folded linear via packed dot2 ----------
        // dual accumulators per node: 8 independent dot2 chains (depth 32/16)
        int eb = blockIdx.x - BUCKET_B;
        int n0 = eb * 16 + wid * 4;          // 4 nodes per wave
        if (n0 < N_NODES) {
            unsigned xpk[4];
#pragma unroll
            for (int nn = 0; nn < 4; ++nn) {
                float2 v = ((const float2*)(x + (size_t)(n0 + nn) * N_FEAT))[lane];
                xpk[nn] = pkh2(v.x, v.y);
            }
            float accA[4], accB[4];
            float b1v = n_b1[lane];
#pragma unroll
            for (int nn = 0; nn < 4; ++nn) { accA[nn] = b1v; accB[nn] = 0.f; }
#pragma unroll 4
            for (int kk = 0; kk < 64; kk += 2) {
                unsigned wp0 = nw1_pk[kk * 64 + lane];
                unsigned wp1 = nw1_pk[(kk + 1) * 64 + lane];
#pragma unroll
                for (int nn = 0; nn < 4; ++nn) {
                    accA[nn] = fdot2u((unsigned)rli((int)xpk[nn], kk), wp0, accA[nn]);
                    accB[nn] = fdot2u((unsigned)rli((int)xpk[nn], kk + 1), wp1, accB[nn]);
                }
            }
            float acc[4];
#pragma unroll
            for (int nn = 0; nn < 4; ++nn)
                acc[nn] = fmaxf(accA[nn] + accB[nn], 0.f);
            unsigned hpk[4];
#pragma unroll
            for (int nn = 0; nn < 4; ++nn) {
                float ha = __shfl(acc[nn], (2 * lane) & 63, 64);
                float hb = __shfl(acc[nn], (2 * lane + 1) & 63, 64);
                hpk[nn] = pkh2(ha, hb);
            }
            float hlA[4], hlB[4];
            float bcv = b2c1[lane];
#pragma unroll
            for (int nn = 0; nn < 4; ++nn) { hlA[nn] = bcv; hlB[nn] = 0.f; }
#pragma unroll 4
            for (int kk = 0; kk < 32; kk += 2) {
                unsigned wp0 = w2c1_pk[kk * 64 + lane];
                unsigned wp1 = w2c1_pk[(kk + 1) * 64 + lane];
#pragma unroll
                for (int nn = 0; nn < 4; ++nn) {
                    hlA[nn] = fdot2u((unsigned)rli((int)hpk[nn], kk), wp0, hlA[nn]);
                    hlB[nn] = fdot2u((unsigned)rli((int)hpk[nn], kk + 1), wp1, hlB[nn]);
                }
            }
            float hl[4];
#pragma unroll
            for (int nn = 0; nn < 4; ++nn) hl[nn] = hlA[nn] + hlB[nn];
            float s1v = a1s[lane], d1v = a1d[lane];
            float wmax = -INFINITY;
#pragma unroll
            for (int nn = 0; nn < 4; ++nn) {
                int n = n0 + nn;
                hlin[(size_t)n * 64 + lane] = __float2half(hl[nn]);
                float ps = hl[nn] * s1v, pd = hl[nn] * d1v;
#pragma unroll
                for (int off = 32; off; off >>= 1) {
                    ps += __shfl_xor(ps, off, 64);
                    pd += __shfl_xor(pd, off, 64);
                }
                if (lane == 0) { asrc[n] = ps; adst[n] = pd; wmax = fmaxf(wmax, ps); }
            }
            if (lane == 0) wred[wid] = wmax;
        } else if (lane == 0) wred[wid] = -INFINITY;
        __syncthreads();
        if (tid == 0)
            blkmax[eb] = fmaxf(fmaxf(wred[0], wred[1]), fmaxf(wred[2], wred[3]));
    }
}

// ---- CSR build: 1024 threads/block; zero global atomics -> epk + As1 ----
__global__ __launch_bounds__(1024) void csr_as1(
    const unsigned* __restrict__ sub_buf, const unsigned* __restrict__ sub_tail,
    const float* __restrict__ asrc1, const float* __restrict__ adst1,
    unsigned* __restrict__ row_ptr, unsigned long long* __restrict__ epk,
    const float* __restrict__ blkmax1, float* __restrict__ As1)
{
    __shared__ unsigned hist[SUB_NODES];
    __shared__ unsigned wt4[4], wo4[4];
    __shared__ unsigned eb_s[2];
    __shared__ unsigned tot_s;
    __shared__ float wm[16];
    int tid = threadIdx.x, lane = tid & 63, wid = tid >> 6;

    if (blockIdx.x == NSUB) {              // As1 reduction block
        float m = -INFINITY;
        for (int i = tid; i < EMB_B; i += 1024) m = fmaxf(m, blkmax1[i]);
#pragma unroll
        for (int off = 32; off; off >>= 1) m = fmaxf(m, __shfl_xor(m, off, 64));
        if (lane == 0) wm[wid] = m;
        __syncthreads();
        if (tid == 0) {
            float r = -INFINITY;
            for (int w = 0; w < 16; ++w) r = fmaxf(r, wm[w]);
            As1[0] = r;
        }
        return;
    }
    int gs = blockIdx.x;                   // 0..255
    unsigned myc = 0u, v = 0u;
    if (tid < NSUB) {
        myc = min(sub_tail[tid], (unsigned)SUB_CAP);
        unsigned nn_t = (tid < NSUB - 1) ? SUB_NODES
                                         : (N_NODES - (NSUB - 1) * SUB_NODES);
        v = myc + nn_t;
    }
    unsigned xs = v;
#pragma unroll
    for (int off = 1; off < 64; off <<= 1) {
        unsigned t = __shfl_up(xs, off, 64);
        if (lane >= off) xs += t;
    }
    if (lane == 63 && wid < 4) wt4[wid] = xs;
    __syncthreads();
    if (tid == 0) {
        unsigned run = 0;
        for (int w = 0; w < 4; ++w) { wo4[w] = run; run += wt4[w]; }
        tot_s = run;
    }
    __syncthreads();
    if (tid == gs) { eb_s[0] = wo4[wid] + xs - v; eb_s[1] = myc; }
    if (gs == 0 && tid == 0) row_ptr[N_NODES] = tot_s;
    __syncthreads();
    unsigned ebase = eb_s[0], cnt = eb_s[1];
    int node_lo = gs * SUB_NODES;
    int nn = (gs < NSUB - 1) ? SUB_NODES : (N_NODES - (NSUB - 1) * SUB_NODES);
    for (int i = tid; i < nn; i += 1024) hist[i] = 1u;
    __syncthreads();
    const unsigned* seg = sub_buf + (size_t)gs * SUB_CAP;
    for (unsigned i = tid; i < cnt; i += 1024)
        atomicAdd(&hist[__builtin_nontemporal_load(seg + i) >> 16], 1u);
    __syncthreads();
    unsigned v2 = (tid < nn) ? hist[tid] : 0u;
    unsigned xs2 = v2;
#pragma unroll
    for (int off = 1; off < 64; off <<= 1) {
        unsigned t = __shfl_up(xs2, off, 64);
        if (lane >= off) xs2 += t;
    }
    __syncthreads();
    if (lane == 63 && wid < 4) wt4[wid] = xs2;
    __syncthreads();
    if (tid == 0) {
        unsigned run = 0;
        for (int w = 0; w < 4; ++w) { wo4[w] = run; run += wt4[w]; }
    }
    __syncthreads();
    if (tid < nn) {
        unsigned ex2 = wo4[wid] + xs2 - v2;
        unsigned rp = ebase + ex2;
        int n = node_lo + tid;
        row_ptr[n] = rp;
        epk[rp] = pke(n, lrelu(asrc1[n] + adst1[n]));   // self-loop first slot
        hist[tid] = ex2 + 1u;
    }
    __syncthreads();
    for (unsigned i = tid; i < cnt; i += 1024) {
        unsigned pay = __builtin_nontemporal_load(seg + i);
        unsigned dl = pay >> 16;
        int src = (int)(pay & 0xffffu);
        unsigned p = atomicAdd(&hist[dl], 1u);
        epk[ebase + p] = pke(src, lrelu(asrc1[src] + adst1[node_lo + (int)dl]));
    }
}

// ---- 1-block max-reduce ----
__global__ __launch_bounds__(1024) void reduce_max(
    const float* __restrict__ in, int n, float* __restrict__ As)
{
    __shared__ float wm[16];
    int tid = threadIdx.x, lane = tid & 63, wid = tid >> 6;
    float m = -INFINITY;
    for (int i = tid; i < n; i += 1024) m = fmaxf(m, in[i]);
#pragma unroll
    for (int off = 32; off; off >>= 1) m = fmaxf(m, __shfl_xor(m, off, 64));
    if (lane == 0) wm[wid] = m;
    __syncthreads();
    if (tid == 0) {
        float r = -INFINITY;
        for (int w = 0; w < 16; ++w) r = fmaxf(r, wm[w]);
        As[0] = r;
    }
}

// ---- agg core (packed el): 8 lanes/edge, U=6 burst (48 edges/round) ----
__device__ __forceinline__ float agg8e(
    const __half* __restrict__ hmat,      // [N][64] fp16 (128B rows)
    const unsigned long long* __restrict__ epk,
    int s0, int s1, float C, int lane, float acc[8])
{
    int slot = lane >> 3;
    int fb = (lane & 7) << 3;
    float sden = 0.f;
#pragma unroll
    for (int j = 0; j < 8; ++j) acc[j] = 0.f;
    for (int base = s0; base < s1; base += 48) {
        int e0 = base + slot,  e1 = e0 + 8,  e2 = e0 + 16;
        int e3 = e0 + 24,      e4 = e0 + 32, e5 = e0 + 40;
        unsigned long long q0 = (e0 < s1) ? __builtin_nontemporal_load(epk + e0) : 0ull;
        unsigned long long q1 = (e1 < s1) ? __builtin_nontemporal_load(epk + e1) : 0ull;
        unsigned long long q2 = (e2 < s1) ? __builtin_nontemporal_load(epk + e2) : 0ull;
        unsigned long long q3 = (e3 < s1) ? __builtin_nontemporal_load(epk + e3) : 0ull;
        unsigned long long q4 = (e4 < s1) ? __builtin_nontemporal_load(epk + e4) : 0ull;
        unsigned long long q5 = (e5 < s1) ? __builtin_nontemporal_load(epk + e5) : 0ull;
        int i0 = (int)(unsigned)q0, i1 = (int)(unsigned)q1;
        int i2 = (int)(unsigned)q2, i3 = (int)(unsigned)q3;
        int i4 = (int)(unsigned)q4, i5 = (int)(unsigned)q5;
        float4 hv0 = *(const float4*)(hmat + (size_t)i0 * 64 + fb);
        float4 hv1 = *(const float4*)(hmat + (size_t)i1 * 64 + fb);
        float4 hv2 = *(const float4*)(hmat + (size_t)i2 * 64 + fb);
        float4 hv3 = *(const float4*)(hmat + (size_t)i3 * 64 + fb);
        float4 hv4 = *(const float4*)(hmat + (size_t)i4 * 64 + fb);
        float4 hv5 = *(const float4*)(hmat + (size_t)i5 * 64 + fb);
        float w0 = (e0 < s1) ? __expf(__int_as_float((int)(q0 >> 32)) - C) : 0.f;
        float w1 = (e1 < s1) ? __expf(__int_as_float((int)(q1 >> 32)) - C) : 0.f;
        float w2 = (e2 < s1) ? __expf(__int_as_float((int)(q2 >> 32)) - C) : 0.f;
        float w3 = (e3 < s1) ? __expf(__int_as_float((int)(q3 >> 32)) - C) : 0.f;
        float w4 = (e4 < s1) ? __expf(__int_as_float((int)(q4 >> 32)) - C) : 0.f;
        float w5 = (e5 < s1) ? __expf(__int_as_float((int)(q5 >> 32)) - C) : 0.f;
        sden += ((w0 + w1) + (w2 + w3)) + (w4 + w5);
        float2 a, b, c, dd;
#define ACC8(HV, W) \
        a = __half22float2(__builtin_bit_cast(__half2, HV.x)); \
        b = __half22float2(__builtin_bit_cast(__half2, HV.y)); \
        c = __half22float2(__builtin_bit_cast(__half2, HV.z)); \
        dd = __half22float2(__builtin_bit_cast(__half2, HV.w)); \
        acc[0] = fmaf(W, a.x, acc[0]);  acc[1] = fmaf(W, a.y, acc[1]); \
        acc[2] = fmaf(W, b.x, acc[2]);  acc[3] = fmaf(W, b.y, acc[3]); \
        acc[4] = fmaf(W, c.x, acc[4]);  acc[5] = fmaf(W, c.y, acc[5]); \
        acc[6] = fmaf(W, dd.x, acc[6]); acc[7] = fmaf(W, dd.y, acc[7]);
        ACC8(hv0, w0)
        ACC8(hv1, w1)
        ACC8(hv2, w2)
        ACC8(hv3, w3)
        ACC8(hv4, w4)
        ACC8(hv5, w5)
#undef ACC8
    }
#pragma unroll
    for (int j = 0; j < 8; ++j) {
        acc[j] += __shfl_xor(acc[j], 8, 64);
        acc[j] += __shfl_xor(acc[j], 16, 64);
        acc[j] += __shfl_xor(acc[j], 32, 64);
    }
#pragma unroll
    for (int off = 32; off; off >>= 1) sden += __shfl_xor(sden, off, 64);
    return sden * 0.125f;
}

// ---- agg core (inline logit): src from epk low word, asrc L2-resident ----
__device__ __forceinline__ float agg8i(
    const __half* __restrict__ hmat,
    const unsigned long long* __restrict__ epk,
    const float* __restrict__ asrc,
    int s0, int s1, float ad, float C, int lane, float acc[8])
{
    int slot = lane >> 3;
    int fb = (lane & 7) << 3;
    float sden = 0.f;
#pragma unroll
    for (int j = 0; j < 8; ++j) acc[j] = 0.f;
    for (int base = s0; base < s1; base += 48) {
        int e0 = base + slot,  e1 = e0 + 8,  e2 = e0 + 16;
        int e3 = e0 + 24,      e4 = e0 + 32, e5 = e0 + 40;
        unsigned long long q0 = (e0 < s1) ? __builtin_nontemporal_load(epk + e0) : 0ull;
        unsigned long long q1 = (e1 < s1) ? __builtin_nontemporal_load(epk + e1) : 0ull;
        unsigned long long q2 = (e2 < s1) ? __builtin_nontemporal_load(epk + e2) : 0ull;
        unsigned long long q3 = (e3 < s1) ? __builtin_nontemporal_load(epk + e3) : 0ull;
        unsigned long long q4 = (e4 < s1) ? __builtin_nontemporal_load(epk + e4) : 0ull;
        unsigned long long q5 = (e5 < s1) ? __builtin_nontemporal_load(epk + e5) : 0ull;
        int i0 = (int)(unsigned)q0, i1 = (int)(unsigned)q1;
        int i2 = (int)(unsigned)q2, i3 = (int)(unsigned)q3;
        int i4 = (int)(unsigned)q4, i5 = (int)(unsigned)q5;
        float4 hv0 = *(const float4*)(hmat + (size_t)i0 * 64 + fb);
        float4 hv1 = *(const float4*)(hmat + (size_t)i1 * 64 + fb);
        float4 hv2 = *(const float4*)(hmat + (size_t)i2 * 64 + fb);
        float4 hv3 = *(const float4*)(hmat + (size_t)i3 * 64 + fb);
        float4 hv4 = *(const float4*)(hmat + (size_t)i4 * 64 + fb);
        float4 hv5 = *(const float4*)(hmat + (size_t)i5 * 64 + fb);
        float w0 = (e0 < s1) ? __expf(lrelu(asrc[i0] + ad) - C) : 0.f;
        float w1 = (e1 < s1) ? __expf(lrelu(asrc[i1] + ad) - C) : 0.f;
        float w2 = (e2 < s1) ? __expf(lrelu(asrc[i2] + ad) - C) : 0.f;
        float w3 = (e3 < s1) ? __expf(lrelu(asrc[i3] + ad) - C) : 0.f;
        float w4 = (e4 < s1) ? __expf(lrelu(asrc[i4] + ad) - C) : 0.f;
        float w5 = (e5 < s1) ? __expf(lrelu(asrc[i5] + ad) - C) : 0.f;
        sden += ((w0 + w1) + (w2 + w3)) + (w4 + w5);
        float2 a, b, c, dd;
#define ACC8(HV, W) \
        a = __half22float2(__builtin_bit_cast(__half2, HV.x)); \
        b = __half22float2(__builtin_bit_cast(__half2, HV.y)); \
        c = __half22float2(__builtin_bit_cast(__half2, HV.z)); \
        dd = __half22float2(__builtin_bit_cast(__half2, HV.w)); \
        acc[0] = fmaf(W, a.x, acc[0]);  acc[1] = fmaf(W, a.y, acc[1]); \
        acc[2] = fmaf(W, b.x, acc[2]);  acc[3] = fmaf(W, b.y, acc[3]); \
        acc[4] = fmaf(W, c.x, acc[4]);  acc[5] = fmaf(W, c.y, acc[5]); \
        acc[6] = fmaf(W, dd.x, acc[6]); acc[7] = fmaf(W, dd.y, acc[7]);
        ACC8(hv0, w0)
        ACC8(hv1, w1)
        ACC8(hv2, w2)
        ACC8(hv3, w3)
        ACC8(hv4, w4)
        ACC8(hv5, w5)
#undef ACC8
    }
#pragma unroll
    for (int j = 0; j < 8; ++j) {
        acc[j] += __shfl_xor(acc[j], 8, 64);
        acc[j] += __shfl_xor(acc[j], 16, 64);
        acc[j] += __shfl_xor(acc[j], 32, 64);
    }
#pragma unroll
    for (int off = 32; off; off >>= 1) sden += __shfl_xor(sden, off, 64);
    return sden * 0.125f;
}

// ---- fused: GAT layer1 aggregate (+relu) + layer2 linear + alpha dots ----
__global__ __launch_bounds__(256) void agg1(
    const __half* __restrict__ hlin1,
    const float* __restrict__ adst,
    const unsigned* __restrict__ row_ptr,
    const unsigned long long* __restrict__ epk,
    const float* __restrict__ As1, const float* __restrict__ c1b,
    const unsigned* __restrict__ c2w_pk,
    const float* __restrict__ a2s, const float* __restrict__ a2d,
    __half* __restrict__ hlin2, float* __restrict__ asrc2, float* __restrict__ adst2,
    float* __restrict__ blkmax)
{
    __shared__ float vbuf[4][64];
    __shared__ float wred[4];
    int lane = threadIdx.x & 63, w = threadIdx.x >> 6;
    int d = blockIdx.x * 4 + w;
    int s0 = (int)row_ptr[d], s1 = (int)row_ptr[d + 1];
    float C = lrelu(As1[0] + adst[d]);
    float acc[8];
    float den = agg8e(hlin1, epk, s0, s1, C, lane, acc);
    if ((lane >> 3) == 0) {               // slot-0 lanes hold all 64 features
        int fb = (lane & 7) << 3;
#pragma unroll
        for (int j = 0; j < 8; ++j) vbuf[w][fb + j] = acc[j];
    }
    __syncthreads();
    float inv = 1.f / (den + 1e-30f);
    int l2 = (2 * lane) & 63;
    float va = fmaxf(vbuf[w][l2] * inv + c1b[l2], 0.f);
    float vb = fmaxf(vbuf[w][l2 + 1] * inv + c1b[l2 + 1], 0.f);
    unsigned vpk = pkh2(va, vb);
    float hl = 0.f;
#pragma unroll 8
    for (int kk = 0; kk < 32; ++kk)
        hl = fdot2u((unsigned)rli((int)vpk, kk), c2w_pk[kk * 64 + lane], hl);
    hlin2[(size_t)d * 64 + lane] = __float2half(hl);
    float ps = hl * a2s[lane], pd = hl * a2d[lane];
#pragma unroll
    for (int off = 32; off; off >>= 1) {
        ps += __shfl_xor(ps, off, 64);
        pd += __shfl_xor(pd, off, 64);
    }
    if (lane == 0) { asrc2[d] = ps; adst2[d] = pd; wred[w] = ps; }
    __syncthreads();
    if (threadIdx.x == 0)
        blkmax[blockIdx.x] = fmaxf(fmaxf(wred[0], wred[1]), fmaxf(wred[2], wred[3]));
}

// ---- fused: GAT layer2 aggregate (inline logits) + bias + pooled atomics ----
__global__ __launch_bounds__(256) void agg2_pool(
    const __half* __restrict__ hlin2,
    const float* __restrict__ asrc2, const float* __restrict__ adst2,
    const unsigned* __restrict__ row_ptr,
    const unsigned long long* __restrict__ epk,
    const float* __restrict__ As2, const float* __restrict__ c2b,
    const int* __restrict__ batch, unsigned* __restrict__ g_enc)
{
    __shared__ float vbuf[4][64];
    __shared__ int sbat[4];
    int lane = threadIdx.x & 63, w = threadIdx.x >> 6;
    int d = blockIdx.x * 4 + w;
    int s0 = (int)row_ptr[d], s1 = (int)row_ptr[d + 1];
    float ad = adst2[d];
    float C = lrelu(As2[0] + ad);
    float acc[8];
    float den = agg8i(hlin2, epk, asrc2, s0, s1, ad, C, lane, acc);
    if ((lane >> 3) == 0) {
        int fb = (lane & 7) << 3;
#pragma unroll
        for (int j = 0; j < 8; ++j) vbuf[w][fb + j] = acc[j];
    }
    __syncthreads();
    float v = vbuf[w][lane] / (den + 1e-30f) + c2b[lane];   // no relu
    vbuf[w][lane] = v;                     // own slot: race-free write-back
    if (lane == 0) sbat[w] = batch[d];
    __syncthreads();
    int b0 = sbat[0];
    bool same = (sbat[1] == b0) & (sbat[2] == b0) & (sbat[3] == b0);
    if (same) {
        // common case (batch sorted): 64 atomics per block instead of 256
        if (w == 0) {
            float m = fmaxf(fmaxf(vbuf[0][lane], vbuf[1][lane]),
                            fmaxf(vbuf[2][lane], vbuf[3][lane]));
            atomicMax(&g_enc[b0 * 64 + lane], fenc(m));
        }
    } else {
        atomicMax(&g_enc[sbat[w] * 64 + lane], fenc(v));
    }
}

// ---- readout MLP: wave per graph ----
__global__ __launch_bounds__(256) void readout(
    const unsigned* __restrict__ g_enc,
    const float* __restrict__ fc1w, const float* __restrict__ fc1b,
    const float* __restrict__ fc2w, const float* __restrict__ fc2b,
    float* __restrict__ out)
{
    int lane = threadIdx.x & 63;
    int gi = blockIdx.x * 4 + (threadIdx.x >> 6);
    float gv = fdec(g_enc[gi * 64 + lane]);
    float a = fc1b[lane];
#pragma unroll 8
    for (int k = 0; k < 64; ++k)
        a = fmaf(rlf(gv, k), fc1w[k * 64 + lane], a);
    a = fmaxf(a, 0.f) * fc2w[lane];
#pragma unroll
    for (int off = 32; off; off >>= 1) a += __shfl_xor(a, off, 64);
    if (lane == 0) out[gi] = a + fc2b[0];
}

extern "C" void kernel_launch(void* const* d_in, const int* in_sizes, int n_in,
                              void* d_out, int out_size, void* d_ws, size_t ws_size,
                              hipStream_t stream)
{
    const float* x      = (const float*)d_in[0];
    const int*   ei     = (const int*)d_in[1];
    // d_in[2] edge_attr: dead value in reference, never read
    const int*   batch  = (const int*)d_in[3];
    const float* n_w1   = (const float*)d_in[4];
    const float* n_b1   = (const float*)d_in[5];
    const float* n_w2   = (const float*)d_in[6];
    const float* n_b2   = (const float*)d_in[7];
    // d_in[8..11] edge MLP weights: dead
    const float* c1_w    = (const float*)d_in[12];
    const float* c1_asrc = (const float*)d_in[13];
    const float* c1_adst = (const float*)d_in[14];
    const float* c1_b    = (const float*)d_in[15];
    const float* c2_w    = (const float*)d_in[16];
    const float* c2_asrc = (const float*)d_in[17];
    const float* c2_adst = (const float*)d_in[18];
    const float* c2_b    = (const float*)d_in[19];
    const float* fc1_w   = (const float*)d_in[20];
    const float* fc1_b   = (const float*)d_in[21];
    const float* fc2_w   = (const float*)d_in[22];
    const float* fc2_b   = (const float*)d_in[23];
    float* out = (float*)d_out;

    // workspace carve (256B aligned)
    char* ws = (char*)d_ws;
    size_t off = 0;
    auto alloc = [&](size_t bytes) -> void* {
        off = (off + 255) & ~(size_t)255;
        void* p = ws + off;
        off += bytes;
        return p;
    };
    unsigned* sub_tail = (unsigned*)alloc(sizeof(unsigned) * NSUB);
    unsigned* sub_buf  = (unsigned*)alloc(sizeof(unsigned) * (size_t)NSUB * SUB_CAP);
    unsigned* row_ptr  = (unsigned*)alloc(sizeof(unsigned) * (N_NODES + 1));
    unsigned long long* epk =
        (unsigned long long*)alloc(sizeof(unsigned long long) * E_TOT);
    __half*   hlin1    = (__half*)alloc(sizeof(__half) * (size_t)N_NODES * 64);
    __half*   hlin2    = (__half*)alloc(sizeof(__half) * (size_t)N_NODES * 64);
    float*    asrc1    = (float*)alloc(sizeof(float) * N_NODES);
    float*    adst1    = (float*)alloc(sizeof(float) * N_NODES);
    float*    asrc2    = (float*)alloc(sizeof(float) * N_NODES);
    float*    adst2    = (float*)alloc(sizeof(float) * N_NODES);
    unsigned* g_enc    = (unsigned*)alloc(sizeof(unsigned) * N_GRAPHS * HIDDEN);
    unsigned* nw1_pk   = (unsigned*)alloc(sizeof(unsigned) * 64 * 64);
    unsigned* w2c1_pk  = (unsigned*)alloc(sizeof(unsigned) * 32 * 64);
    unsigned* c2w_pk   = (unsigned*)alloc(sizeof(unsigned) * 32 * 64);
    float*    b2c1     = (float*)alloc(sizeof(float) * 64);
    float*    blkmax1  = (float*)alloc(sizeof(float) * EMB_B);
    float*    blkmax2  = (float*)alloc(sizeof(float) * AGG_B);
    float*    As1      = (float*)alloc(sizeof(float) * 2);
    float*    As2      = (float*)alloc(sizeof(float) * 2);

    fold_w<<<1, 256, 0, stream>>>(n_w1, n_w2, n_b2, c1_w, c2_w,
                                  nw1_pk, w2c1_pk, c2w_pk, b2c1, g_enc, sub_tail);

    // bucket (640 blocks, overlaps embed) + embed (3125 blocks)
    embed_bucket<<<BUCKET_B + EMB_B, 256, 0, stream>>>(
        x, nw1_pk, n_b1, w2c1_pk, b2c1, c1_asrc, c1_adst,
        hlin1, asrc1, adst1, blkmax1,
        ei, sub_tail, sub_buf);

    // CSR build -> packed (src, el1) records + As1 reduce (1024 thr/block)
    csr_as1<<<NSUB + 1, 1024, 0, stream>>>(
        sub_buf, sub_tail, asrc1, adst1, row_ptr, epk, blkmax1, As1);

    agg1<<<AGG_B, 256, 0, stream>>>(
        hlin1, adst1, row_ptr, epk, As1,
        c1_b, c2w_pk, c2_asrc, c2_adst, hlin2, asrc2, adst2, blkmax2);

    // As2 reduce
    reduce_max<<<1, 1024, 0, stream>>>(blkmax2, AGG_B, As2);

    // layer-2 agg with inline logits (asrc2 is 200KB, L2-resident)
    agg2_pool<<<AGG_B, 256, 0, stream>>>(
        hlin2, asrc2, adst2, row_ptr, epk, As2, c2_b, batch, g_enc);
    readout<<<N_GRAPHS / 4, 256, 0, stream>>>(g_enc, fc1_w, fc1_b, fc2_w, fc2_b, out);
}